// Round 5
// baseline (1317.688 us; speedup 1.0000x reference)
//
#include <hip/hip_runtime.h>
#include <hip/hip_bf16.h>
#include <math.h>

// Problem constants
#define BB 4
#define NH 8
#define NN 8192
#define DD 64
#define MM 256
#define LG 32
#define DIM 512
#define K3 1536
#define KER 33

typedef __hip_bfloat16 bf16;
typedef __attribute__((ext_vector_type(8))) short bf16x8;
typedef __attribute__((ext_vector_type(4))) float f32x4;

__device__ __forceinline__ float b2f(bf16 x) { return __bfloat162float(x); }
__device__ __forceinline__ bf16 f2b(float x) { return __float2bfloat16(x); }
__device__ __forceinline__ short f2bs(float x) { bf16 h = __float2bfloat16(x); return *reinterpret_cast<short*>(&h); }
__device__ __forceinline__ float bsf(short s) { return __uint_as_float(((unsigned int)(unsigned short)s) << 16); }
// bf16-pair unpack from a uint32 (lo short = first element)
__device__ __forceinline__ float blo(unsigned int u) { return __uint_as_float(u << 16); }
__device__ __forceinline__ float bhi(unsigned int u) { return __uint_as_float(u & 0xffff0000u); }

// async global->LDS, 16B per lane (dest must be linear: base + lane*16)
__device__ __forceinline__ void g2lds16(const void* g, void* l) {
    __builtin_amdgcn_global_load_lds(
        (const __attribute__((address_space(1))) unsigned int*)g,
        (__attribute__((address_space(3))) unsigned int*)l, 16, 0, 0);
}

// diagnostic fallback: zero the output
__global__ void zero_out(float* __restrict__ o) {
    o[(size_t)blockIdx.x * 256 + threadIdx.x] = 0.f;
}

// ---------------------------------------------------------------------------
// split fp32 -> bf16 hi + bf16 lo (residual), 8 elems/thread, 16B stores
__global__ void split_x(const float* __restrict__ x, short* __restrict__ xh,
                        short* __restrict__ xl) {
    size_t i = ((size_t)blockIdx.x * 256 + threadIdx.x) * 8;
    const float4* xp = (const float4*)(x + i);
    float4 v0 = xp[0], v1 = xp[1];
    float vv[8] = {v0.x, v0.y, v0.z, v0.w, v1.x, v1.y, v1.z, v1.w};
    short hb[8], lb[8];
#pragma unroll
    for (int u = 0; u < 8; u++) {
        bf16 h = f2b(vv[u]);
        hb[u] = *(short*)&h;
        lb[u] = f2bs(vv[u] - b2f(h));
    }
    *(uint4*)(xh + i) = *(uint4*)hb;
    *(uint4*)(xl + i) = *(uint4*)lb;
}

// split + transpose weight: W[k][n] fp32 -> wh/wl [n][K=512] bf16
__global__ void split_wT(const float* __restrict__ W, short* __restrict__ wh,
                         short* __restrict__ wl, int Nn) {
    int idx = blockIdx.x * 256 + threadIdx.x;   // n*512 + k
    int k = idx & 511, n = idx >> 9;
    float v = W[(size_t)k * Nn + n];
    bf16 h = f2b(v);
    wh[idx] = *(short*)&h;
    wl[idx] = f2bs(v - b2f(h));
}

// ---------------------------------------------------------------------------
// qkv projection via MFMA, split-precision (Xh@Wh + Xl@Wh + Xh@Wl).
__global__ __launch_bounds__(256) void gemm_qkv_mfma(
        const short* __restrict__ xh, const short* __restrict__ xl,
        const short* __restrict__ wh, const short* __restrict__ wl,
        bf16* __restrict__ q, bf16* __restrict__ k, bf16* __restrict__ v) {
    __shared__ short Ah[128 * 32];
    __shared__ short Al[128 * 32];
    __shared__ short Bh[128 * 32];
    __shared__ short Bl[128 * 32];
    int orig = blockIdx.x;
    int wg = (orig & 7) * 384 + (orig >> 3);
    int by = wg / 12, bx = wg - by * 12;
    int rowBase = by * 128, colBase = bx * 128;
    int tid = threadIdx.x;
    int rl = tid >> 2;
    int ch = (tid & 3) * 8;
    int wave = tid >> 6, lane = tid & 63;
    int ln = lane & 15, quad = lane >> 4;
    int wr = (wave >> 1) * 64, wc = (wave & 1) * 64;
    f32x4 acc[4][4];
#pragma unroll
    for (int mt = 0; mt < 4; mt++)
#pragma unroll
        for (int nt = 0; nt < 4; nt++) acc[mt][nt] = (f32x4){0.f, 0.f, 0.f, 0.f};

    for (int k0 = 0; k0 < DIM; k0 += 32) {
        __syncthreads();
#pragma unroll
        for (int p = 0; p < 2; p++) {
            int r = p * 64 + rl;
            size_t ga = (size_t)(rowBase + r) * DIM + k0 + ch;
            size_t gb = (size_t)(colBase + r) * DIM + k0 + ch;
            int lo = r * 32 + ch;
            g2lds16(xh + ga, &Ah[lo]);
            g2lds16(xl + ga, &Al[lo]);
            g2lds16(wh + gb, &Bh[lo]);
            g2lds16(wl + gb, &Bl[lo]);
        }
        __syncthreads();
        bf16x8 a_h[4], a_l[4], b_h[4], b_l[4];
#pragma unroll
        for (int mt = 0; mt < 4; mt++) {
            int o = (wr + mt * 16 + ln) * 32 + quad * 8;
            a_h[mt] = *(const bf16x8*)&Ah[o];
            a_l[mt] = *(const bf16x8*)&Al[o];
        }
#pragma unroll
        for (int nt = 0; nt < 4; nt++) {
            int o = (wc + nt * 16 + ln) * 32 + quad * 8;
            b_h[nt] = *(const bf16x8*)&Bh[o];
            b_l[nt] = *(const bf16x8*)&Bl[o];
        }
#pragma unroll
        for (int mt = 0; mt < 4; mt++)
#pragma unroll
            for (int nt = 0; nt < 4; nt++) {
                acc[mt][nt] = __builtin_amdgcn_mfma_f32_16x16x32_bf16(a_h[mt], b_h[nt], acc[mt][nt], 0, 0, 0);
                acc[mt][nt] = __builtin_amdgcn_mfma_f32_16x16x32_bf16(a_l[mt], b_h[nt], acc[mt][nt], 0, 0, 0);
                acc[mt][nt] = __builtin_amdgcn_mfma_f32_16x16x32_bf16(a_h[mt], b_l[nt], acc[mt][nt], 0, 0, 0);
            }
    }
    int part = colBase >> 9;
    bf16* dst = part == 0 ? q : (part == 1 ? k : v);
    float scale = part == 0 ? 0.125f : 1.0f;
#pragma unroll
    for (int mt = 0; mt < 4; mt++)
#pragma unroll
        for (int nt = 0; nt < 4; nt++)
#pragma unroll
            for (int r = 0; r < 4; r++) {
                int row = rowBase + wr + mt * 16 + quad * 4 + r;
                int col = colBase + wc + nt * 16 + ln;
                int h = (col & 511) >> 6, d = col & 63;
                int b_ = row >> 13, n_ = row & 8191;
                size_t di = ((size_t)(b_ * NH + h) * NN + n_) * DD + d;
                dst[di] = f2b(acc[mt][nt][r] * scale);
            }
}

// out projection via MFMA: oh(bf16) @ (Wh+Wl) + bias -> fp32
__global__ __launch_bounds__(256) void gemm_out_mfma(
        const bf16* __restrict__ A, const short* __restrict__ wh,
        const short* __restrict__ wl, const float* __restrict__ bias,
        float* __restrict__ C) {
    __shared__ short As[128 * 32];
    __shared__ short Bh[128 * 32];
    __shared__ short Bl[128 * 32];
    int orig = blockIdx.x;                       // nwg = 1024
    int wg = (orig & 7) * 128 + (orig >> 3);
    int by = wg >> 2, bx = wg & 3;
    int rowBase = by * 128, colBase = bx * 128;
    int tid = threadIdx.x;
    int rl = tid >> 2, ch = (tid & 3) * 8;
    int wave = tid >> 6, lane = tid & 63;
    int ln = lane & 15, quad = lane >> 4;
    int wr = (wave >> 1) * 64, wc = (wave & 1) * 64;
    const short* Ab = (const short*)A;
    f32x4 acc[4][4];
#pragma unroll
    for (int mt = 0; mt < 4; mt++)
#pragma unroll
        for (int nt = 0; nt < 4; nt++) acc[mt][nt] = (f32x4){0.f, 0.f, 0.f, 0.f};

    for (int k0 = 0; k0 < DIM; k0 += 32) {
        __syncthreads();
#pragma unroll
        for (int p = 0; p < 2; p++) {
            int r = p * 64 + rl;
            size_t ga = (size_t)(rowBase + r) * DIM + k0 + ch;
            size_t gb = (size_t)(colBase + r) * DIM + k0 + ch;
            int lo = r * 32 + ch;
            g2lds16(Ab + ga, &As[lo]);
            g2lds16(wh + gb, &Bh[lo]);
            g2lds16(wl + gb, &Bl[lo]);
        }
        __syncthreads();
        bf16x8 a[4], b_h[4], b_l[4];
#pragma unroll
        for (int mt = 0; mt < 4; mt++)
            a[mt] = *(const bf16x8*)&As[(wr + mt * 16 + ln) * 32 + quad * 8];
#pragma unroll
        for (int nt = 0; nt < 4; nt++) {
            int o = (wc + nt * 16 + ln) * 32 + quad * 8;
            b_h[nt] = *(const bf16x8*)&Bh[o];
            b_l[nt] = *(const bf16x8*)&Bl[o];
        }
#pragma unroll
        for (int mt = 0; mt < 4; mt++)
#pragma unroll
            for (int nt = 0; nt < 4; nt++) {
                acc[mt][nt] = __builtin_amdgcn_mfma_f32_16x16x32_bf16(a[mt], b_h[nt], acc[mt][nt], 0, 0, 0);
                acc[mt][nt] = __builtin_amdgcn_mfma_f32_16x16x32_bf16(a[mt], b_l[nt], acc[mt][nt], 0, 0, 0);
            }
    }
#pragma unroll
    for (int mt = 0; mt < 4; mt++)
#pragma unroll
        for (int nt = 0; nt < 4; nt++)
#pragma unroll
            for (int r = 0; r < 4; r++) {
                int row = rowBase + wr + mt * 16 + quad * 4 + r;
                int col = colBase + wc + nt * 16 + ln;
                C[(size_t)row * DIM + col] = acc[mt][nt][r] + bias[col];
            }
}

// ---------------------------------------------------------------------------
// Batched split-precision MFMA GEMM for the pinv chain.
// C(256x256, 32 bats) = scale*(A@B) + alpha*I
// A as hi/lo bf16 [bat][m][k]; B as hi/lo B^T layout [bat][n][k].
// 64x64 tile, 256 threads (4 waves 2x2), grid dim3(4,4,32) = 512 blocks
// -> 2 blocks/CU so staging of one block overlaps MFMA of the other.
// Outputs (flags): 1 = A-layout pairs, 2 = B^T-layout pairs, 4 = fp32.
__global__ __launch_bounds__(256) void bgemm_pair(
        const short* __restrict__ Ah, const short* __restrict__ Al,
        const short* __restrict__ Bh, const short* __restrict__ Bl,
        short* __restrict__ oAh, short* __restrict__ oAl,
        short* __restrict__ oBh, short* __restrict__ oBl,
        float* __restrict__ oF, float scale, float alpha, int flags) {
    __shared__ short sAh[64 * 32];
    __shared__ short sAl[64 * 32];
    __shared__ short sBh[64 * 32];
    __shared__ short sBl[64 * 32];
    int bat = blockIdx.z;
    int rowBase = blockIdx.y * 64;    // 0..192
    int colBase = blockIdx.x * 64;    // 0..192
    const size_t MB = (size_t)bat * (MM * MM);
    int tid = threadIdx.x;
    int rl = tid >> 2, ch = (tid & 3) * 8;   // rl 0..63
    int wave = tid >> 6, lane = tid & 63;
    int ln = lane & 15, quad = lane >> 4;
    int wr = (wave >> 1) * 32, wc = (wave & 1) * 32;
    f32x4 acc[2][2];
#pragma unroll
    for (int mt = 0; mt < 2; mt++)
#pragma unroll
        for (int nt = 0; nt < 2; nt++) acc[mt][nt] = (f32x4){0.f, 0.f, 0.f, 0.f};

    for (int k0 = 0; k0 < MM; k0 += 32) {
        __syncthreads();
        {
            size_t ga = MB + (size_t)(rowBase + rl) * MM + k0 + ch;
            size_t gb = MB + (size_t)(colBase + rl) * MM + k0 + ch;
            int lo = rl * 32 + ch;
            g2lds16(Ah + ga, &sAh[lo]);
            g2lds16(Al + ga, &sAl[lo]);
            g2lds16(Bh + gb, &sBh[lo]);
            g2lds16(Bl + gb, &sBl[lo]);
        }
        __syncthreads();
        bf16x8 a_h[2], a_l[2], b_h[2], b_l[2];
#pragma unroll
        for (int mt = 0; mt < 2; mt++) {
            int o = (wr + mt * 16 + ln) * 32 + quad * 8;
            a_h[mt] = *(const bf16x8*)&sAh[o];
            a_l[mt] = *(const bf16x8*)&sAl[o];
        }
#pragma unroll
        for (int nt = 0; nt < 2; nt++) {
            int o = (wc + nt * 16 + ln) * 32 + quad * 8;
            b_h[nt] = *(const bf16x8*)&sBh[o];
            b_l[nt] = *(const bf16x8*)&sBl[o];
        }
#pragma unroll
        for (int mt = 0; mt < 2; mt++)
#pragma unroll
            for (int nt = 0; nt < 2; nt++) {
                acc[mt][nt] = __builtin_amdgcn_mfma_f32_16x16x32_bf16(a_h[mt], b_h[nt], acc[mt][nt], 0, 0, 0);
                acc[mt][nt] = __builtin_amdgcn_mfma_f32_16x16x32_bf16(a_l[mt], b_h[nt], acc[mt][nt], 0, 0, 0);
                acc[mt][nt] = __builtin_amdgcn_mfma_f32_16x16x32_bf16(a_h[mt], b_l[nt], acc[mt][nt], 0, 0, 0);
            }
    }
#pragma unroll
    for (int mt = 0; mt < 2; mt++)
#pragma unroll
        for (int nt = 0; nt < 2; nt++) {
            short bh4[4], bl4[4];
            int col = colBase + wc + nt * 16 + ln;
            int row0 = rowBase + wr + mt * 16 + quad * 4;
#pragma unroll
            for (int r = 0; r < 4; r++) {
                int row = row0 + r;
                float val = scale * acc[mt][nt][r];
                if (row == col) val += alpha;
                if (flags & 4) oF[MB + (size_t)row * MM + col] = val;
                short vh = f2bs(val);
                short vl = f2bs(val - bsf(vh));
                if (flags & 1) {
                    oAh[MB + (size_t)row * MM + col] = vh;
                    oAl[MB + (size_t)row * MM + col] = vl;
                }
                bh4[r] = vh; bl4[r] = vl;
            }
            if (flags & 2) {
                size_t o = MB + (size_t)col * MM + row0;
                *(uint2*)&oBh[o] = *(uint2*)bh4;
                *(uint2*)&oBl[o] = *(uint2*)bl4;
            }
        }
}

// bufB^T pairs = 7I - bufA^T pairs (elementwise on B^T layout [bat][n][k])
__global__ void eye7_pair(const short* __restrict__ ATh, const short* __restrict__ ATl,
                          short* __restrict__ BTh, short* __restrict__ BTl) {
    size_t base = ((size_t)blockIdx.x * 256 + threadIdx.x) * 8;
    int i0 = (int)(base & 255);         // k index (fastest)
    int j = (int)((base >> 8) & 255);   // n index
    uint4 hv = *(const uint4*)&ATh[base];
    uint4 lv = *(const uint4*)&ATl[base];
    unsigned int hu[4] = {hv.x, hv.y, hv.z, hv.w};
    unsigned int lu[4] = {lv.x, lv.y, lv.z, lv.w};
    short ho[8], lo_[8];
#pragma unroll
    for (int u = 0; u < 8; u++) {
        float a = (u & 1 ? bhi(hu[u >> 1]) : blo(hu[u >> 1])) +
                  (u & 1 ? bhi(lu[u >> 1]) : blo(lu[u >> 1]));
        float v = ((i0 + u) == j ? 7.0f : 0.0f) - a;
        short vh = f2bs(v);
        ho[u] = vh;
        lo_[u] = f2bs(v - bsf(vh));
    }
    *(uint4*)&BTh[base] = *(uint4*)ho;
    *(uint4*)&BTl[base] = *(uint4*)lo_;
}

// z0 = x2^T / (scal0*scal1 + 1e-12) -> A-layout pairs + B^T-layout pairs
__global__ void z_init_pair(const float* __restrict__ x2, const float* __restrict__ scal,
                            short* __restrict__ zAh, short* __restrict__ zAl,
                            short* __restrict__ zBh, short* __restrict__ zBl) {
    size_t base = ((size_t)blockIdx.x * 256 + threadIdx.x) * 8;
    float inv = 1.0f / (scal[0] * scal[1] + 1e-12f);
    int c0 = (int)(base & 255);
    int r = (int)((base >> 8) & 255);
    size_t MB = (base >> 16) << 16;
    // B^T layout: zBT[bat][r][c] = z[c][r] = x2[bat][r][c]*inv  (elementwise)
    const float4* xp = (const float4*)(x2 + base);
    float4 v0 = xp[0], v1 = xp[1];
    float vv[8] = {v0.x, v0.y, v0.z, v0.w, v1.x, v1.y, v1.z, v1.w};
    short ho[8], lo_[8];
#pragma unroll
    for (int u = 0; u < 8; u++) {
        float v = vv[u] * inv;
        short vh = f2bs(v);
        ho[u] = vh; lo_[u] = f2bs(v - bsf(vh));
    }
    *(uint4*)&zBh[base] = *(uint4*)ho;
    *(uint4*)&zBl[base] = *(uint4*)lo_;
    // A layout: zA[bat][r][c] = z[r][c] = x2[bat][c][r]*inv  (strided read)
#pragma unroll
    for (int u = 0; u < 8; u++) {
        float v = x2[MB + (size_t)(c0 + u) * MM + r] * inv;
        short vh = f2bs(v);
        ho[u] = vh; lo_[u] = f2bs(v - bsf(vh));
    }
    *(uint4*)&zAh[base] = *(uint4*)ho;
    *(uint4*)&zAl[base] = *(uint4*)lo_;
}

// t2t = (z @ t1)^T per batch, stored bf16 [bh][d=64][landmark=256]
__global__ void bgemm_t2t(const float* __restrict__ A, const float* __restrict__ B,
                          short* __restrict__ T) {
    __shared__ float As[16][64];
    __shared__ float Bs[16][64];
    int bat = blockIdx.z;
    const float* Ab = A + (size_t)bat * MM * MM;   // z [256,256]
    const float* Bb = B + (size_t)bat * MM * DD;   // t1 [256,64]
    short* Tb = T + (size_t)bat * DD * MM;
    int tid = threadIdx.x;
    int rowBase = blockIdx.y * 64;
    int ty = tid >> 4, tx = tid & 15;
    float acc[4][4] = {};
    for (int k0 = 0; k0 < MM; k0 += 16) {
        for (int idx = tid; idx < 64 * 16; idx += 256) {
            int r = idx >> 4, c = idx & 15;
            As[c][r] = Ab[(size_t)(rowBase + r) * MM + k0 + c];
        }
        for (int idx = tid; idx < 16 * 64; idx += 256) {
            int r = idx >> 6, c = idx & 63;
            Bs[r][c] = Bb[(size_t)(k0 + r) * DD + c];
        }
        __syncthreads();
#pragma unroll
        for (int kk = 0; kk < 16; kk++) {
            float a[4], b[4];
#pragma unroll
            for (int i = 0; i < 4; i++) a[i] = As[kk][ty * 4 + i];
#pragma unroll
            for (int j = 0; j < 4; j++) b[j] = Bs[kk][tx * 4 + j];
#pragma unroll
            for (int i = 0; i < 4; i++)
#pragma unroll
                for (int j = 0; j < 4; j++) acc[i][j] += a[i] * b[j];
        }
        __syncthreads();
    }
#pragma unroll
    for (int i = 0; i < 4; i++) {
        int r = rowBase + ty * 4 + i;     // landmark
#pragma unroll
        for (int j = 0; j < 4; j++) {
            int c = tx * 4 + j;           // d
            Tb[(size_t)c * MM + r] = f2bs(acc[i][j]);
        }
    }
}

// ---------------------------------------------------------------------------
// landmark means: qL/kL[bh,mi,d] = mean over 32 tokens (bf16 in, fp32 out)
__global__ void landmark_means(const bf16* __restrict__ q, const bf16* __restrict__ k,
                               float* __restrict__ qL, float* __restrict__ kL) {
    int idx = blockIdx.x * 256 + threadIdx.x;   // (bh*256 + mi)*64 + d
    int d = idx & 63;
    int mi = (idx >> 6) & 255;
    int bh = idx >> 14;
    const bf16* qp = q + ((size_t)bh * NN + mi * LG) * DD + d;
    const bf16* kp = k + ((size_t)bh * NN + mi * LG) * DD + d;
    float sq = 0.f, sk = 0.f;
#pragma unroll
    for (int j = 0; j < LG; j++) { sq += b2f(qp[(size_t)j * DD]); sk += b2f(kp[(size_t)j * DD]); }
    qL[idx] = sq * (1.f / LG);
    kL[idx] = sk * (1.f / LG);
}

// kL fp32 -> bf16 copy (for attn1 staging)
__global__ void kl_to_bf16(const float* __restrict__ kL, short* __restrict__ kl16) {
    size_t i = ((size_t)blockIdx.x * 256 + threadIdx.x) * 4;
    float4 v = *(const float4*)(kL + i);
    short o[4] = {f2bs(v.x), f2bs(v.y), f2bs(v.z), f2bs(v.w)};
    *(uint2*)&kl16[i] = *(uint2*)o;
}

// attn2 = softmax(qL @ kL^T), one block per row (all fp32)
__global__ void attn2_softmax(const float* __restrict__ qL, const float* __restrict__ kL,
                              float* __restrict__ x2) {
    __shared__ float qs[64];
    __shared__ float red[256];
    int bh = blockIdx.x >> 8, i = blockIdx.x & 255;
    int t = threadIdx.x;
    if (t < 64) qs[t] = qL[((size_t)bh * MM + i) * DD + t];
    __syncthreads();
    const float4* kp = (const float4*)(kL + ((size_t)bh * MM + t) * DD);
    float l = 0.f;
#pragma unroll
    for (int u = 0; u < 16; u++) {
        float4 kv = kp[u];
        l += qs[u*4+0]*kv.x + qs[u*4+1]*kv.y + qs[u*4+2]*kv.z + qs[u*4+3]*kv.w;
    }
    red[t] = l; __syncthreads();
    for (int s = 128; s > 0; s >>= 1) { if (t < s) red[t] = fmaxf(red[t], red[t + s]); __syncthreads(); }
    float mx = red[0]; __syncthreads();
    float e = __expf(l - mx);
    red[t] = e; __syncthreads();
    for (int s = 128; s > 0; s >>= 1) { if (t < s) red[t] += red[t + s]; __syncthreads(); }
    x2[((size_t)bh * MM + i) * MM + t] = e / red[0];
}

__global__ void init_scal(float* scal) {
    if (threadIdx.x == 0) { scal[0] = 0.f; scal[1] = 0.f; }
}

// max over (bh,i) of sum_j |x|  -> scal[0]
__global__ void rsum_max(const float* __restrict__ x2, float* scal) {
    __shared__ float red[256];
    int t = threadIdx.x;
    float v = fabsf(x2[(size_t)blockIdx.x * MM + t]);
    red[t] = v; __syncthreads();
    for (int s = 128; s > 0; s >>= 1) { if (t < s) red[t] += red[t + s]; __syncthreads(); }
    if (t == 0) atomicMax((unsigned int*)&scal[0], __float_as_uint(red[0]));
}

// max over (bh,j) of sum_i |x|  -> scal[1]
__global__ void csum_max(const float* __restrict__ x2, float* scal) {
    __shared__ float red[256];
    int t = threadIdx.x;
    const float* xp = x2 + (size_t)blockIdx.x * MM * MM;
    float s = 0.f;
    for (int i = 0; i < MM; i++) s += fabsf(xp[(size_t)i * MM + t]);
    red[t] = s; __syncthreads();
    for (int st = 128; st > 0; st >>= 1) { if (t < st) red[t] = fmaxf(red[t], red[t + st]); __syncthreads(); }
    if (t == 0) atomicMax((unsigned int*)&scal[1], __float_as_uint(red[0]));
}

// ---------------------------------------------------------------------------
// v transpose: vT[bh][d][n] <- v[bh][n][d].
__global__ void transpose_v(const bf16* __restrict__ v, bf16* __restrict__ vT) {
    int gw = blockIdx.x * 4 + (threadIdx.x >> 6);   // global wave id
    int lane = threadIdx.x & 63;                     // = d
    int bh = gw >> 8;
    int c  = gw & 255;                               // n-chunk (32 tokens)
    const bf16* vb = v + ((size_t)bh * NN + c * 32) * DD + lane;
    unsigned short buf[32];
#pragma unroll
    for (int i = 0; i < 32; i++) buf[i] = *(const unsigned short*)(vb + (size_t)i * DD);
    bf16* dst = vT + ((size_t)bh * DD + lane) * NN + c * 32;
#pragma unroll
    for (int u = 0; u < 4; u++)
        *(uint4*)(dst + u * 8) = *(uint4*)&buf[u * 8];
}

// ---------------------------------------------------------------------------
// MFMA flash attn3v: t1 = softmax(qL @ k^T over n) @ v
// 4 waves / 64 landmark rows per block (halves k/vT HBM re-reads vs 32-row).
#define NJ 128
#define KS2 72
#define VS2 136
#define PS2 136
__global__ __launch_bounds__(256) void attn3v_mfma(
        const float* __restrict__ qL, const bf16* __restrict__ k,
        const bf16* __restrict__ vT, float* __restrict__ t1) {
    __shared__ short ks[NJ * KS2];          // 18432 B  [j][d]
    __shared__ short vs[DD * VS2];          // 17408 B  [d][j]
    __shared__ short ps[4][16 * PS2];       // 17408 B  per-wave P [row][j]
    int bh = blockIdx.y;
    int r0 = blockIdx.x * 64;
    int tid = threadIdx.x;
    int wave = tid >> 6, lane = tid & 63;
    int ln = lane & 15, quad = lane >> 4;
    int m = r0 + wave * 16 + ln;
    const float* qrow = qL + ((size_t)bh * MM + m) * DD;
    bf16x8 a0, a1;
#pragma unroll
    for (int u = 0; u < 8; u++) {
        ((short*)&a0)[u] = f2bs(qrow[quad * 8 + u]);
        ((short*)&a1)[u] = f2bs(qrow[32 + quad * 8 + u]);
    }
    const uint4* kg = (const uint4*)(k + (size_t)bh * NN * DD);
    const uint4* vg = (const uint4*)(vT + (size_t)bh * DD * NN);
    float mrow[4], lrow[4];
    f32x4 o[4];
#pragma unroll
    for (int r = 0; r < 4; r++) { mrow[r] = -1e30f; lrow[r] = 0.f; }
#pragma unroll
    for (int ct = 0; ct < 4; ct++) o[ct] = (f32x4){0.f, 0.f, 0.f, 0.f};
    short* pw = &ps[wave][0];

    for (int j0 = 0; j0 < NN; j0 += NJ) {
        __syncthreads();
        // stage k chunk: 128 rows x 8 uint4 (256 threads, 4 iters)
#pragma unroll
        for (int it = 0; it < 4; it++) {
            int idx = it * 256 + tid;
            int row = idx >> 3, c8 = idx & 7;
            uint4 pk = kg[(size_t)(j0 + row) * 8 + c8];
            *(uint4*)&ks[row * KS2 + c8 * 8] = pk;
        }
        // stage vT chunk: 64 rows x 16 uint4
#pragma unroll
        for (int it = 0; it < 4; it++) {
            int idx = it * 256 + tid;
            int row = idx >> 4, c8 = idx & 15;
            uint4 pv = vg[(size_t)row * (NN / 8) + (j0 / 8) + c8];
            *(uint4*)&vs[row * VS2 + c8 * 8] = pv;
        }
        __syncthreads();
        f32x4 s[8];
#pragma unroll
        for (int ct = 0; ct < 8; ct++) {
            const short* kp = &ks[(ct * 16 + ln) * KS2 + quad * 8];
            bf16x8 b0 = *(const bf16x8*)kp;
            bf16x8 b1 = *(const bf16x8*)(kp + 32);
            f32x4 c = {0.f, 0.f, 0.f, 0.f};
            c = __builtin_amdgcn_mfma_f32_16x16x32_bf16(a0, b0, c, 0, 0, 0);
            c = __builtin_amdgcn_mfma_f32_16x16x32_bf16(a1, b1, c, 0, 0, 0);
            s[ct] = c;
        }
#pragma unroll
        for (int r = 0; r < 4; r++) {
            float v = -1e30f;
#pragma unroll
            for (int ct = 0; ct < 8; ct++) v = fmaxf(v, s[ct][r]);
            v = fmaxf(v, __shfl_xor(v, 1));
            v = fmaxf(v, __shfl_xor(v, 2));
            v = fmaxf(v, __shfl_xor(v, 4));
            v = fmaxf(v, __shfl_xor(v, 8));
            float mn = fmaxf(mrow[r], v);
            float alpha = __expf(mrow[r] - mn);
            mrow[r] = mn;
            float psum = 0.f;
#pragma unroll
            for (int ct = 0; ct < 8; ct++) { float e = __expf(s[ct][r] - mn); s[ct][r] = e; psum += e; }
            lrow[r] = lrow[r] * alpha + psum;
#pragma unroll
            for (int c2 = 0; c2 < 4; c2++) o[c2][r] *= alpha;
        }
#pragma unroll
        for (int ct = 0; ct < 8; ct++)
#pragma unroll
            for (int r = 0; r < 4; r++)
                pw[(quad * 4 + r) * PS2 + ct * 16 + ln] = f2bs(s[ct][r]);
#pragma unroll
        for (int kstep = 0; kstep < 4; kstep++) {
            bf16x8 pa = *(const bf16x8*)&pw[ln * PS2 + kstep * 32 + quad * 8];
#pragma unroll
            for (int ct = 0; ct < 4; ct++) {
                bf16x8 pb = *(const bf16x8*)&vs[(ct * 16 + ln) * VS2 + kstep * 32 + quad * 8];
                o[ct] = __builtin_amdgcn_mfma_f32_16x16x32_bf16(pa, pb, o[ct], 0, 0, 0);
            }
        }
    }
#pragma unroll
    for (int r = 0; r < 4; r++) {
        float l = lrow[r];
        l += __shfl_xor(l, 1);
        l += __shfl_xor(l, 2);
        l += __shfl_xor(l, 4);
        l += __shfl_xor(l, 8);
        lrow[r] = 1.0f / l;
    }
#pragma unroll
    for (int ct = 0; ct < 4; ct++)
#pragma unroll
        for (int r = 0; r < 4; r++) {
            int row = r0 + wave * 16 + quad * 4 + r;
            t1[((size_t)bh * MM + row) * DD + ct * 16 + ln] = o[ct][r] * lrow[r];
        }
}

// ---------------------------------------------------------------------------
// MFMA fused attn1: oh[b,i,h*64+d] = softmax(q_i kL^T) @ t2
#define KLS 72
#define T2S 264
__global__ __launch_bounds__(256, 1) void attn1_mfma(
        const bf16* __restrict__ q, const short* __restrict__ kl16,
        const short* __restrict__ t2t, bf16* __restrict__ oh) {
    __shared__ short kls[MM * KLS];
    __shared__ short t2s[DD * T2S];
    __shared__ short ps1[4][16 * T2S];
    int bh = blockIdx.y;
    int n0 = blockIdx.x * 64;
    int tid = threadIdx.x;
    const short* kLb = kl16 + (size_t)bh * MM * DD;
    for (int idx = tid; idx < MM * DD / 8; idx += 256) {   // 8 iters, 16B each
        int l = idx >> 3, d8 = (idx & 7) * 8;
        *(uint4*)&kls[l * KLS + d8] = *(const uint4*)&kLb[idx * 8];
    }
    const short* t2b = t2t + (size_t)bh * DD * MM;
    for (int idx = tid; idx < DD * MM / 8; idx += 256) {   // 8 iters, 16B each
        int c = idx >> 5, r = (idx & 31) * 8;
        *(uint4*)&t2s[c * T2S + r] = *(const uint4*)&t2b[idx * 8];
    }
    __syncthreads();
    int wave = tid >> 6, lane = tid & 63;
    int ln = lane & 15, quad = lane >> 4;
    int m = n0 + wave * 16 + ln;
    const bf16* qrow = q + ((size_t)bh * NN + m) * DD;
    bf16x8 a0 = *(const bf16x8*)(qrow + quad * 8);
    bf16x8 a1 = *(const bf16x8*)(qrow + 32 + quad * 8);
    f32x4 acc[16];
#pragma unroll
    for (int nt = 0; nt < 16; nt++) {
        const short* kp = &kls[(nt * 16 + ln) * KLS + quad * 8];
        bf16x8 b0 = *(const bf16x8*)kp;
        bf16x8 b1 = *(const bf16x8*)(kp + 32);
        f32x4 c = {0.f, 0.f, 0.f, 0.f};
        c = __builtin_amdgcn_mfma_f32_16x16x32_bf16(a0, b0, c, 0, 0, 0);
        c = __builtin_amdgcn_mfma_f32_16x16x32_bf16(a1, b1, c, 0, 0, 0);
        acc[nt] = c;
    }
    float inv[4];
#pragma unroll
    for (int r = 0; r < 4; r++) {
        float v = -1e30f;
#pragma unroll
        for (int nt = 0; nt < 16; nt++) v = fmaxf(v, acc[nt][r]);
        v = fmaxf(v, __shfl_xor(v, 1));
        v = fmaxf(v, __shfl_xor(v, 2));
        v = fmaxf(v, __shfl_xor(v, 4));
        v = fmaxf(v, __shfl_xor(v, 8));
        float s = 0.f;
#pragma unroll
        for (int nt = 0; nt < 16; nt++) { float e = __expf(acc[nt][r] - v); acc[nt][r] = e; s += e; }
        s += __shfl_xor(s, 1);
        s += __shfl_xor(s, 2);
        s += __shfl_xor(s, 4);
        s += __shfl_xor(s, 8);
        inv[r] = 1.0f / s;
    }
    short* pw = &ps1[wave][0];
#pragma unroll
    for (int nt = 0; nt < 16; nt++)
#pragma unroll
        for (int r = 0; r < 4; r++)
            pw[(quad * 4 + r) * T2S + nt * 16 + ln] = f2bs(acc[nt][r]);
    __syncthreads();
    f32x4 o[4];
#pragma unroll
    for (int nt = 0; nt < 4; nt++) o[nt] = (f32x4){0.f, 0.f, 0.f, 0.f};
#pragma unroll
    for (int ks = 0; ks < 8; ks++) {
        bf16x8 pa = *(const bf16x8*)&pw[ln * T2S + ks * 32 + quad * 8];
#pragma unroll
        for (int nt = 0; nt < 4; nt++) {
            bf16x8 pb = *(const bf16x8*)&t2s[(nt * 16 + ln) * T2S + ks * 32 + quad * 8];
            o[nt] = __builtin_amdgcn_mfma_f32_16x16x32_bf16(pa, pb, o[nt], 0, 0, 0);
        }
    }
    int b_ = bh >> 3, h = bh & 7;
#pragma unroll
    for (int nt = 0; nt < 4; nt++)
#pragma unroll
        for (int r = 0; r < 4; r++) {
            int row = n0 + wave * 16 + quad * 4 + r;
            int col = nt * 16 + ln;
            oh[((size_t)(b_ * NN + row)) * DIM + h * 64 + col] = f2b(o[nt][r] * inv[r]);
        }
}

// depthwise conv residual, vectorized: thread = (bh, n, 8-d chunk)
__global__ __launch_bounds__(256) void conv_add2(const bf16* __restrict__ v,
                                                 const float* __restrict__ w,
                                                 bf16* __restrict__ oh) {
    int tid = threadIdx.x;
    int c = tid & 7;                 // d-chunk (8 bf16)
    int nsub = tid >> 3;             // 0..31
    int bh = blockIdx.x >> 8;
    int n = ((blockIdx.x & 255) << 5) + nsub;
    int b_ = bh >> 3, h = bh & 7;
    const bf16* vb = v + (size_t)bh * NN * DD + c * 8;
    float acc[8] = {};
#pragma unroll
    for (int t = 0; t < KER; t++) {
        int src = n + t - 16;
        if (src >= 0 && src < NN) {
            uint4 pk = *(const uint4*)(vb + (size_t)src * DD);
            float wt = w[h * KER + t];
            unsigned int ua[4] = {pk.x, pk.y, pk.z, pk.w};
#pragma unroll
            for (int j = 0; j < 4; j++) {
                acc[2 * j]     += wt * blo(ua[j]);
                acc[2 * j + 1] += wt * bhi(ua[j]);
            }
        }
    }
    size_t oidx = ((size_t)(b_ * NN + n)) * DIM + h * 64 + c * 8;
    uint4 cur = *(uint4*)&oh[oidx];
    unsigned int cu[4] = {cur.x, cur.y, cur.z, cur.w};
    short outp[8];
#pragma unroll
    for (int j = 0; j < 4; j++) {
        outp[2 * j]     = f2bs(blo(cu[j]) + acc[2 * j]);
        outp[2 * j + 1] = f2bs(bhi(cu[j]) + acc[2 * j + 1]);
    }
    *(uint4*)&oh[oidx] = *(uint4*)outp;
}

// ---------------------------------------------------------------------------

extern "C" void kernel_launch(void* const* d_in, const int* in_sizes, int n_in,
                              void* d_out, int out_size, void* d_ws, size_t ws_size,
                              hipStream_t stream) {
    const float* x    = (const float*)d_in[0];
    const float* Wqkv = (const float*)d_in[1];
    const float* Wout = (const float*)d_in[2];
    const float* bout = (const float*)d_in[3];
    const float* cw   = (const float*)d_in[4];
    float* out = (float*)d_out;

    const size_t SZ_QKV = (size_t)BB * NH * NN * DD;   // 16,777,216 elems
    const size_t SZ_L   = (size_t)BB * NH * MM * DD;   // 524,288
    const size_t SZ_M2  = (size_t)BB * NH * MM * MM;   // 2,097,152

    // --- workspace plumbing (unchanged footprint) ---
    char* p = (char*)d_ws;
    bf16* q    = (bf16*)p;  p += SZ_QKV * 2;    // 32 MB
    bf16* v    = (bf16*)p;  p += SZ_QKV * 2;    // 32 MB
    float* x2   = (float*)p; p += SZ_M2 * 4;    // 8 MB each
    float* zf   = (float*)p; p += SZ_M2 * 4;    // final fp32 z lives here
    float* z2r  = (float*)p; p += SZ_M2 * 4;    // region reused for x2 pairs
    float* bAr  = (float*)p; p += SZ_M2 * 4;    // region reused for bufA pairs
    float* bBr  = (float*)p; p += SZ_M2 * 4;    // region reused for bufA^T pairs
    float* qL   = (float*)p; p += SZ_L * 4;     // 2 MB each
    float* kL   = (float*)p; p += SZ_L * 4;
    float* t1   = (float*)p; p += SZ_L * 4;
    short* t2t  = (short*)p; p += SZ_L * 4;
    float* scal = (float*)p; p += 2 * 4;
    size_t need = (size_t)(p - (char*)d_ws);
    bf16* k  = (bf16*)d_out;                     // first 32 MB of out buffer
    bf16* vT = (bf16*)d_out + SZ_QKV;            // second 32 MB of out buffer
    bf16* oh = (bf16*)x2;                        // 32 MB over dead pinv region

    // split-precision scratch for projections (aliased, dead at use time):
    short* xh  = (short*)x2;                     // 32 MB over x2..bAr
    short* xl  = (short*)vT;                     // vT half of d_out
    short* wqh = (short*)bBr;                    // 1.5 MB
    short* wql = (short*)bBr + (size_t)K3 * DIM;
    short* woh = (short*)q;                      // q dead after attn1_mfma
    short* wol = (short*)q + (size_t)DIM * DIM;
    short* kl16 = (short*)t1;                    // t1 dead after bgemm_t2t

    // pinv pair scratch (after attn3v, k/vT in d_out are dead):
    const size_t U = SZ_M2;                      // 4 MiB per bf16 array
    short* db = (short*)d_out;
    short* bufBTh = db + 0 * U;  short* bufBTl = db + 1 * U;
    short* z2BTh  = db + 2 * U;  short* z2BTl  = db + 3 * U;
    short* zPair[2][4] = {                       // {Ah, Al, BTh, BTl} x 2 buffers
        { db + 4 * U, db + 5 * U, db + 6 * U, db + 7 * U },
        { db + 8 * U, db + 9 * U, db + 10 * U, db + 11 * U } };
    short* x2Ah = (short*)z2r;   short* x2Al = (short*)z2r + U;
    short* bufAh = (short*)bAr;  short* bufAl = (short*)bAr + U;
    short* bufATh = (short*)bBr; short* bufATl = (short*)bBr + U;

    if (ws_size < need) {
        zero_out<<<out_size / 256, 256, 0, stream>>>(out);
        return;
    }

    // 1. split inputs, project qkv via MFMA
    split_x<<<(int)(SZ_QKV / (256 * 8)), 256, 0, stream>>>(x, xh, xl);
    split_wT<<<(K3 * DIM) / 256, 256, 0, stream>>>(Wqkv, wqh, wql, K3);
    gemm_qkv_mfma<<<3072, 256, 0, stream>>>(xh, xl, wqh, wql, q, k, v);
    // 2. vT = v^T (overwrites xl -- dead)
    transpose_v<<<(BB * NH * MM) / 4, 256, 0, stream>>>(v, vT);
    // 3. landmark means + attn2 softmax (x2 overwrites xh -- dead)
    landmark_means<<<(BB * NH * MM * DD) / 256, 256, 0, stream>>>(q, k, qL, kL);
    attn2_softmax<<<BB * NH * MM, 256, 0, stream>>>(qL, kL, x2);
    // 4. attn3v FIRST (frees k/vT = all of d_out for pinv scratch)
    attn3v_mfma<<<dim3(4, BB * NH), 256, 0, stream>>>(qL, k, vT, t1);
    // 5. pinv scalars + z0 pairs + x2 pairs
    init_scal<<<1, 64, 0, stream>>>(scal);
    rsum_max<<<BB * NH * MM, 256, 0, stream>>>(x2, scal);
    csum_max<<<BB * NH, 256, 0, stream>>>(x2, scal);
    z_init_pair<<<(int)(SZ_M2 / (256 * 8)), 256, 0, stream>>>(
        x2, scal, zPair[0][0], zPair[0][1], zPair[0][2], zPair[0][3]);
    split_x<<<(int)(SZ_M2 / (256 * 8)), 256, 0, stream>>>(x2, x2Ah, x2Al);
    // 6. Newton-Schulz pinv, split-precision MFMA (64x64 tiles, 512 blocks)
    int cur = 0;
    for (int it = 0; it < 6; it++) {
        int nxt = cur ^ 1;
        // bufA = x2 @ z          -> A-pairs + BT-pairs
        bgemm_pair<<<dim3(4, 4, BB * NH), 256, 0, stream>>>(
            x2Ah, x2Al, zPair[cur][2], zPair[cur][3],
            bufAh, bufAl, bufATh, bufATl, nullptr, 1.f, 0.f, 1 | 2);
        // bufB^T = 7I - bufA^T   (elementwise)
        eye7_pair<<<(int)(SZ_M2 / (256 * 8)), 256, 0, stream>>>(
            bufATh, bufATl, bufBTh, bufBTl);
        // z2 = 15I - bufA @ bufB -> BT-pairs
        bgemm_pair<<<dim3(4, 4, BB * NH), 256, 0, stream>>>(
            bufAh, bufAl, bufBTh, bufBTl,
            nullptr, nullptr, z2BTh, z2BTl, nullptr, -1.f, 15.f, 2);
        // bufB2 = 13I - bufA @ z2 -> BT-pairs (overwrite bufBT)
        bgemm_pair<<<dim3(4, 4, BB * NH), 256, 0, stream>>>(
            bufAh, bufAl, z2BTh, z2BTl,
            nullptr, nullptr, bufBTh, bufBTl, nullptr, -1.f, 13.f, 2);
        // z_next = 0.25 z @ bufB2; last iteration needs only fp32 (zf)
        int fl = (it == 5) ? 4 : (1 | 2);
        bgemm_pair<<<dim3(4, 4, BB * NH), 256, 0, stream>>>(
            zPair[cur][0], zPair[cur][1], bufBTh, bufBTl,
            zPair[nxt][0], zPair[nxt][1], zPair[nxt][2], zPair[nxt][3],
            zf, 0.25f, 0.f, fl);
        cur = nxt;
    }
    // 7. t2t = (z @ t1)^T in bf16 [bh][64][256]
    bgemm_t2t<<<dim3(1, 4, BB * NH), 256, 0, stream>>>(zf, t1, t2t);
    // 7b. kL -> bf16 (over dead t1) for attn1 staging
    kl_to_bf16<<<(int)(SZ_L / (256 * 4)), 256, 0, stream>>>(kL, kl16);
    // 8. oh = softmax(q kL^T) @ t2  (oh overwrites x2/zf/z2r/bAr -- all dead)
    attn1_mfma<<<dim3(NN / 64, BB * NH), 256, 0, stream>>>(q, kl16, t2t, oh);
    // 9. oh += depthwise conv residual (v dead after)
    conv_add2<<<BB * NH * 256, 256, 0, stream>>>(v, cw, oh);
    // 10. out = oh @ (WoutH + WoutL) + bout (overwrites d_out; scratch dead)
    split_wT<<<(DIM * DIM) / 256, 256, 0, stream>>>(Wout, woh, wol, DIM);
    gemm_out_mfma<<<1024, 256, 0, stream>>>(oh, woh, wol, bout, out);

    (void)in_sizes; (void)n_in; (void)ws_size;
}

// Round 6
// 1181.209 us; speedup vs baseline: 1.1155x; 1.1155x over previous
//
#include <hip/hip_runtime.h>
#include <hip/hip_bf16.h>
#include <math.h>

// Problem constants
#define BB 4
#define NH 8
#define NN 8192
#define DD 64
#define MM 256
#define LG 32
#define DIM 512
#define K3 1536
#define KER 33

typedef __hip_bfloat16 bf16;
typedef __attribute__((ext_vector_type(8))) short bf16x8;
typedef __attribute__((ext_vector_type(4))) float f32x4;

__device__ __forceinline__ float b2f(bf16 x) { return __bfloat162float(x); }
__device__ __forceinline__ bf16 f2b(float x) { return __float2bfloat16(x); }
__device__ __forceinline__ short f2bs(float x) { bf16 h = __float2bfloat16(x); return *reinterpret_cast<short*>(&h); }
__device__ __forceinline__ float bsf(short s) { return __uint_as_float(((unsigned int)(unsigned short)s) << 16); }
// bf16-pair unpack from a uint32 (lo short = first element)
__device__ __forceinline__ float blo(unsigned int u) { return __uint_as_float(u << 16); }
__device__ __forceinline__ float bhi(unsigned int u) { return __uint_as_float(u & 0xffff0000u); }

// async global->LDS, 16B per lane (dest must be linear: base + lane*16)
__device__ __forceinline__ void g2lds16(const void* g, void* l) {
    __builtin_amdgcn_global_load_lds(
        (const __attribute__((address_space(1))) unsigned int*)g,
        (__attribute__((address_space(3))) unsigned int*)l, 16, 0, 0);
}

// diagnostic fallback: zero the output
__global__ void zero_out(float* __restrict__ o) {
    o[(size_t)blockIdx.x * 256 + threadIdx.x] = 0.f;
}

// ---------------------------------------------------------------------------
// split fp32 -> bf16 hi + bf16 lo (residual), 8 elems/thread, 16B stores
__global__ void split_x(const float* __restrict__ x, short* __restrict__ xh,
                        short* __restrict__ xl) {
    size_t i = ((size_t)blockIdx.x * 256 + threadIdx.x) * 8;
    const float4* xp = (const float4*)(x + i);
    float4 v0 = xp[0], v1 = xp[1];
    float vv[8] = {v0.x, v0.y, v0.z, v0.w, v1.x, v1.y, v1.z, v1.w};
    short hb[8], lb[8];
#pragma unroll
    for (int u = 0; u < 8; u++) {
        bf16 h = f2b(vv[u]);
        hb[u] = *(short*)&h;
        lb[u] = f2bs(vv[u] - b2f(h));
    }
    *(uint4*)(xh + i) = *(uint4*)hb;
    *(uint4*)(xl + i) = *(uint4*)lb;
}

// split + transpose weight: W[k][n] fp32 -> wh/wl [n][K=512] bf16
__global__ void split_wT(const float* __restrict__ W, short* __restrict__ wh,
                         short* __restrict__ wl, int Nn) {
    int idx = blockIdx.x * 256 + threadIdx.x;   // n*512 + k
    int k = idx & 511, n = idx >> 9;
    float v = W[(size_t)k * Nn + n];
    bf16 h = f2b(v);
    wh[idx] = *(short*)&h;
    wl[idx] = f2bs(v - b2f(h));
}

// ---------------------------------------------------------------------------
// qkv projection via MFMA, split-precision (Xh@Wh + Xl@Wh + Xh@Wl).
__global__ __launch_bounds__(256) void gemm_qkv_mfma(
        const short* __restrict__ xh, const short* __restrict__ xl,
        const short* __restrict__ wh, const short* __restrict__ wl,
        bf16* __restrict__ q, bf16* __restrict__ k, bf16* __restrict__ v) {
    __shared__ short Ah[128 * 32];
    __shared__ short Al[128 * 32];
    __shared__ short Bh[128 * 32];
    __shared__ short Bl[128 * 32];
    int orig = blockIdx.x;
    int wg = (orig & 7) * 384 + (orig >> 3);
    int by = wg / 12, bx = wg - by * 12;
    int rowBase = by * 128, colBase = bx * 128;
    int tid = threadIdx.x;
    int rl = tid >> 2;
    int ch = (tid & 3) * 8;
    int wave = tid >> 6, lane = tid & 63;
    int ln = lane & 15, quad = lane >> 4;
    int wr = (wave >> 1) * 64, wc = (wave & 1) * 64;
    f32x4 acc[4][4];
#pragma unroll
    for (int mt = 0; mt < 4; mt++)
#pragma unroll
        for (int nt = 0; nt < 4; nt++) acc[mt][nt] = (f32x4){0.f, 0.f, 0.f, 0.f};

    for (int k0 = 0; k0 < DIM; k0 += 32) {
        __syncthreads();
#pragma unroll
        for (int p = 0; p < 2; p++) {
            int r = p * 64 + rl;
            size_t ga = (size_t)(rowBase + r) * DIM + k0 + ch;
            size_t gb = (size_t)(colBase + r) * DIM + k0 + ch;
            int lo = r * 32 + ch;
            g2lds16(xh + ga, &Ah[lo]);
            g2lds16(xl + ga, &Al[lo]);
            g2lds16(wh + gb, &Bh[lo]);
            g2lds16(wl + gb, &Bl[lo]);
        }
        __syncthreads();
        bf16x8 a_h[4], a_l[4], b_h[4], b_l[4];
#pragma unroll
        for (int mt = 0; mt < 4; mt++) {
            int o = (wr + mt * 16 + ln) * 32 + quad * 8;
            a_h[mt] = *(const bf16x8*)&Ah[o];
            a_l[mt] = *(const bf16x8*)&Al[o];
        }
#pragma unroll
        for (int nt = 0; nt < 4; nt++) {
            int o = (wc + nt * 16 + ln) * 32 + quad * 8;
            b_h[nt] = *(const bf16x8*)&Bh[o];
            b_l[nt] = *(const bf16x8*)&Bl[o];
        }
#pragma unroll
        for (int mt = 0; mt < 4; mt++)
#pragma unroll
            for (int nt = 0; nt < 4; nt++) {
                acc[mt][nt] = __builtin_amdgcn_mfma_f32_16x16x32_bf16(a_h[mt], b_h[nt], acc[mt][nt], 0, 0, 0);
                acc[mt][nt] = __builtin_amdgcn_mfma_f32_16x16x32_bf16(a_l[mt], b_h[nt], acc[mt][nt], 0, 0, 0);
                acc[mt][nt] = __builtin_amdgcn_mfma_f32_16x16x32_bf16(a_h[mt], b_l[nt], acc[mt][nt], 0, 0, 0);
            }
    }
    int part = colBase >> 9;
    bf16* dst = part == 0 ? q : (part == 1 ? k : v);
    float scale = part == 0 ? 0.125f : 1.0f;
#pragma unroll
    for (int mt = 0; mt < 4; mt++)
#pragma unroll
        for (int nt = 0; nt < 4; nt++)
#pragma unroll
            for (int r = 0; r < 4; r++) {
                int row = rowBase + wr + mt * 16 + quad * 4 + r;
                int col = colBase + wc + nt * 16 + ln;
                int h = (col & 511) >> 6, d = col & 63;
                int b_ = row >> 13, n_ = row & 8191;
                size_t di = ((size_t)(b_ * NH + h) * NN + n_) * DD + d;
                dst[di] = f2b(acc[mt][nt][r] * scale);
            }
}

// out projection via MFMA: oh(bf16) @ (Wh+Wl) + bias -> fp32
__global__ __launch_bounds__(256) void gemm_out_mfma(
        const bf16* __restrict__ A, const short* __restrict__ wh,
        const short* __restrict__ wl, const float* __restrict__ bias,
        float* __restrict__ C) {
    __shared__ short As[128 * 32];
    __shared__ short Bh[128 * 32];
    __shared__ short Bl[128 * 32];
    int orig = blockIdx.x;                       // nwg = 1024
    int wg = (orig & 7) * 128 + (orig >> 3);
    int by = wg >> 2, bx = wg & 3;
    int rowBase = by * 128, colBase = bx * 128;
    int tid = threadIdx.x;
    int rl = tid >> 2, ch = (tid & 3) * 8;
    int wave = tid >> 6, lane = tid & 63;
    int ln = lane & 15, quad = lane >> 4;
    int wr = (wave >> 1) * 64, wc = (wave & 1) * 64;
    const short* Ab = (const short*)A;
    f32x4 acc[4][4];
#pragma unroll
    for (int mt = 0; mt < 4; mt++)
#pragma unroll
        for (int nt = 0; nt < 4; nt++) acc[mt][nt] = (f32x4){0.f, 0.f, 0.f, 0.f};

    for (int k0 = 0; k0 < DIM; k0 += 32) {
        __syncthreads();
#pragma unroll
        for (int p = 0; p < 2; p++) {
            int r = p * 64 + rl;
            size_t ga = (size_t)(rowBase + r) * DIM + k0 + ch;
            size_t gb = (size_t)(colBase + r) * DIM + k0 + ch;
            int lo = r * 32 + ch;
            g2lds16(Ab + ga, &As[lo]);
            g2lds16(wh + gb, &Bh[lo]);
            g2lds16(wl + gb, &Bl[lo]);
        }
        __syncthreads();
        bf16x8 a[4], b_h[4], b_l[4];
#pragma unroll
        for (int mt = 0; mt < 4; mt++)
            a[mt] = *(const bf16x8*)&As[(wr + mt * 16 + ln) * 32 + quad * 8];
#pragma unroll
        for (int nt = 0; nt < 4; nt++) {
            int o = (wc + nt * 16 + ln) * 32 + quad * 8;
            b_h[nt] = *(const bf16x8*)&Bh[o];
            b_l[nt] = *(const bf16x8*)&Bl[o];
        }
#pragma unroll
        for (int mt = 0; mt < 4; mt++)
#pragma unroll
            for (int nt = 0; nt < 4; nt++) {
                acc[mt][nt] = __builtin_amdgcn_mfma_f32_16x16x32_bf16(a[mt], b_h[nt], acc[mt][nt], 0, 0, 0);
                acc[mt][nt] = __builtin_amdgcn_mfma_f32_16x16x32_bf16(a[mt], b_l[nt], acc[mt][nt], 0, 0, 0);
            }
    }
#pragma unroll
    for (int mt = 0; mt < 4; mt++)
#pragma unroll
        for (int nt = 0; nt < 4; nt++)
#pragma unroll
            for (int r = 0; r < 4; r++) {
                int row = rowBase + wr + mt * 16 + quad * 4 + r;
                int col = colBase + wc + nt * 16 + ln;
                C[(size_t)row * DIM + col] = acc[mt][nt][r] + bias[col];
            }
}

// ---------------------------------------------------------------------------
// Batched split-precision MFMA GEMM for the pinv chain.
// 64x64 tile, 4 waves, grid dim3(4,4,32) = 512 blocks (2 blocks/CU).
__global__ __launch_bounds__(256) void bgemm_pair(
        const short* __restrict__ Ah, const short* __restrict__ Al,
        const short* __restrict__ Bh, const short* __restrict__ Bl,
        short* __restrict__ oAh, short* __restrict__ oAl,
        short* __restrict__ oBh, short* __restrict__ oBl,
        float* __restrict__ oF, float scale, float alpha, int flags) {
    __shared__ short sAh[64 * 32];
    __shared__ short sAl[64 * 32];
    __shared__ short sBh[64 * 32];
    __shared__ short sBl[64 * 32];
    int bat = blockIdx.z;
    int rowBase = blockIdx.y * 64;    // 0..192
    int colBase = blockIdx.x * 64;    // 0..192
    const size_t MB = (size_t)bat * (MM * MM);
    int tid = threadIdx.x;
    int rl = tid >> 2, ch = (tid & 3) * 8;   // rl 0..63
    int wave = tid >> 6, lane = tid & 63;
    int ln = lane & 15, quad = lane >> 4;
    int wr = (wave >> 1) * 32, wc = (wave & 1) * 32;
    f32x4 acc[2][2];
#pragma unroll
    for (int mt = 0; mt < 2; mt++)
#pragma unroll
        for (int nt = 0; nt < 2; nt++) acc[mt][nt] = (f32x4){0.f, 0.f, 0.f, 0.f};

    for (int k0 = 0; k0 < MM; k0 += 32) {
        __syncthreads();
        {
            size_t ga = MB + (size_t)(rowBase + rl) * MM + k0 + ch;
            size_t gb = MB + (size_t)(colBase + rl) * MM + k0 + ch;
            int lo = rl * 32 + ch;
            g2lds16(Ah + ga, &sAh[lo]);
            g2lds16(Al + ga, &sAl[lo]);
            g2lds16(Bh + gb, &sBh[lo]);
            g2lds16(Bl + gb, &sBl[lo]);
        }
        __syncthreads();
        bf16x8 a_h[2], a_l[2], b_h[2], b_l[2];
#pragma unroll
        for (int mt = 0; mt < 2; mt++) {
            int o = (wr + mt * 16 + ln) * 32 + quad * 8;
            a_h[mt] = *(const bf16x8*)&sAh[o];
            a_l[mt] = *(const bf16x8*)&sAl[o];
        }
#pragma unroll
        for (int nt = 0; nt < 2; nt++) {
            int o = (wc + nt * 16 + ln) * 32 + quad * 8;
            b_h[nt] = *(const bf16x8*)&sBh[o];
            b_l[nt] = *(const bf16x8*)&sBl[o];
        }
#pragma unroll
        for (int mt = 0; mt < 2; mt++)
#pragma unroll
            for (int nt = 0; nt < 2; nt++) {
                acc[mt][nt] = __builtin_amdgcn_mfma_f32_16x16x32_bf16(a_h[mt], b_h[nt], acc[mt][nt], 0, 0, 0);
                acc[mt][nt] = __builtin_amdgcn_mfma_f32_16x16x32_bf16(a_l[mt], b_h[nt], acc[mt][nt], 0, 0, 0);
                acc[mt][nt] = __builtin_amdgcn_mfma_f32_16x16x32_bf16(a_h[mt], b_l[nt], acc[mt][nt], 0, 0, 0);
            }
    }
#pragma unroll
    for (int mt = 0; mt < 2; mt++)
#pragma unroll
        for (int nt = 0; nt < 2; nt++) {
            short bh4[4], bl4[4];
            int col = colBase + wc + nt * 16 + ln;
            int row0 = rowBase + wr + mt * 16 + quad * 4;
#pragma unroll
            for (int r = 0; r < 4; r++) {
                int row = row0 + r;
                float val = scale * acc[mt][nt][r];
                if (row == col) val += alpha;
                if (flags & 4) oF[MB + (size_t)row * MM + col] = val;
                short vh = f2bs(val);
                short vl = f2bs(val - bsf(vh));
                if (flags & 1) {
                    oAh[MB + (size_t)row * MM + col] = vh;
                    oAl[MB + (size_t)row * MM + col] = vl;
                }
                bh4[r] = vh; bl4[r] = vl;
            }
            if (flags & 2) {
                size_t o = MB + (size_t)col * MM + row0;
                *(uint2*)&oBh[o] = *(uint2*)bh4;
                *(uint2*)&oBl[o] = *(uint2*)bl4;
            }
        }
}

// bufB^T pairs = 7I - bufA^T pairs (elementwise on B^T layout [bat][n][k])
__global__ void eye7_pair(const short* __restrict__ ATh, const short* __restrict__ ATl,
                          short* __restrict__ BTh, short* __restrict__ BTl) {
    size_t base = ((size_t)blockIdx.x * 256 + threadIdx.x) * 8;
    int i0 = (int)(base & 255);         // k index (fastest)
    int j = (int)((base >> 8) & 255);   // n index
    uint4 hv = *(const uint4*)&ATh[base];
    uint4 lv = *(const uint4*)&ATl[base];
    unsigned int hu[4] = {hv.x, hv.y, hv.z, hv.w};
    unsigned int lu[4] = {lv.x, lv.y, lv.z, lv.w};
    short ho[8], lo_[8];
#pragma unroll
    for (int u = 0; u < 8; u++) {
        float a = (u & 1 ? bhi(hu[u >> 1]) : blo(hu[u >> 1])) +
                  (u & 1 ? bhi(lu[u >> 1]) : blo(lu[u >> 1]));
        float v = ((i0 + u) == j ? 7.0f : 0.0f) - a;
        short vh = f2bs(v);
        ho[u] = vh;
        lo_[u] = f2bs(v - bsf(vh));
    }
    *(uint4*)&BTh[base] = *(uint4*)ho;
    *(uint4*)&BTl[base] = *(uint4*)lo_;
}

// z0 = x2^T / (scal0*scal1 + 1e-12) -> A-layout pairs + B^T-layout pairs
__global__ void z_init_pair(const float* __restrict__ x2, const float* __restrict__ scal,
                            short* __restrict__ zAh, short* __restrict__ zAl,
                            short* __restrict__ zBh, short* __restrict__ zBl) {
    size_t base = ((size_t)blockIdx.x * 256 + threadIdx.x) * 8;
    float inv = 1.0f / (scal[0] * scal[1] + 1e-12f);
    int c0 = (int)(base & 255);
    int r = (int)((base >> 8) & 255);
    size_t MB = (base >> 16) << 16;
    const float4* xp = (const float4*)(x2 + base);
    float4 v0 = xp[0], v1 = xp[1];
    float vv[8] = {v0.x, v0.y, v0.z, v0.w, v1.x, v1.y, v1.z, v1.w};
    short ho[8], lo_[8];
#pragma unroll
    for (int u = 0; u < 8; u++) {
        float v = vv[u] * inv;
        short vh = f2bs(v);
        ho[u] = vh; lo_[u] = f2bs(v - bsf(vh));
    }
    *(uint4*)&zBh[base] = *(uint4*)ho;
    *(uint4*)&zBl[base] = *(uint4*)lo_;
#pragma unroll
    for (int u = 0; u < 8; u++) {
        float v = x2[MB + (size_t)(c0 + u) * MM + r] * inv;
        short vh = f2bs(v);
        ho[u] = vh; lo_[u] = f2bs(v - bsf(vh));
    }
    *(uint4*)&zAh[base] = *(uint4*)ho;
    *(uint4*)&zAl[base] = *(uint4*)lo_;
}

// t2t = (z @ t1)^T per batch, stored bf16 [bh][d=64][landmark=256]
__global__ void bgemm_t2t(const float* __restrict__ A, const float* __restrict__ B,
                          short* __restrict__ T) {
    __shared__ float As[16][64];
    __shared__ float Bs[16][64];
    int bat = blockIdx.z;
    const float* Ab = A + (size_t)bat * MM * MM;   // z [256,256]
    const float* Bb = B + (size_t)bat * MM * DD;   // t1 [256,64]
    short* Tb = T + (size_t)bat * DD * MM;
    int tid = threadIdx.x;
    int rowBase = blockIdx.y * 64;
    int ty = tid >> 4, tx = tid & 15;
    float acc[4][4] = {};
    for (int k0 = 0; k0 < MM; k0 += 16) {
        for (int idx = tid; idx < 64 * 16; idx += 256) {
            int r = idx >> 4, c = idx & 15;
            As[c][r] = Ab[(size_t)(rowBase + r) * MM + k0 + c];
        }
        for (int idx = tid; idx < 16 * 64; idx += 256) {
            int r = idx >> 6, c = idx & 63;
            Bs[r][c] = Bb[(size_t)(k0 + r) * DD + c];
        }
        __syncthreads();
#pragma unroll
        for (int kk = 0; kk < 16; kk++) {
            float a[4], b[4];
#pragma unroll
            for (int i = 0; i < 4; i++) a[i] = As[kk][ty * 4 + i];
#pragma unroll
            for (int j = 0; j < 4; j++) b[j] = Bs[kk][tx * 4 + j];
#pragma unroll
            for (int i = 0; i < 4; i++)
#pragma unroll
                for (int j = 0; j < 4; j++) acc[i][j] += a[i] * b[j];
        }
        __syncthreads();
    }
#pragma unroll
    for (int i = 0; i < 4; i++) {
        int r = rowBase + ty * 4 + i;     // landmark
#pragma unroll
        for (int j = 0; j < 4; j++) {
            int c = tx * 4 + j;           // d
            Tb[(size_t)c * MM + r] = f2bs(acc[i][j]);
        }
    }
}

// ---------------------------------------------------------------------------
// landmark means: qL/kL[bh,mi,d] = mean over 32 tokens (bf16 in, fp32 out)
__global__ void landmark_means(const bf16* __restrict__ q, const bf16* __restrict__ k,
                               float* __restrict__ qL, float* __restrict__ kL) {
    int idx = blockIdx.x * 256 + threadIdx.x;   // (bh*256 + mi)*64 + d
    int d = idx & 63;
    int mi = (idx >> 6) & 255;
    int bh = idx >> 14;
    const bf16* qp = q + ((size_t)bh * NN + mi * LG) * DD + d;
    const bf16* kp = k + ((size_t)bh * NN + mi * LG) * DD + d;
    float sq = 0.f, sk = 0.f;
#pragma unroll
    for (int j = 0; j < LG; j++) { sq += b2f(qp[(size_t)j * DD]); sk += b2f(kp[(size_t)j * DD]); }
    qL[idx] = sq * (1.f / LG);
    kL[idx] = sk * (1.f / LG);
}

// kL fp32 -> bf16 copy (for attn1 staging)
__global__ void kl_to_bf16(const float* __restrict__ kL, short* __restrict__ kl16) {
    size_t i = ((size_t)blockIdx.x * 256 + threadIdx.x) * 4;
    float4 v = *(const float4*)(kL + i);
    short o[4] = {f2bs(v.x), f2bs(v.y), f2bs(v.z), f2bs(v.w)};
    *(uint2*)&kl16[i] = *(uint2*)o;
}

// attn2 = softmax(qL @ kL^T), one block per row (all fp32)
__global__ void attn2_softmax(const float* __restrict__ qL, const float* __restrict__ kL,
                              float* __restrict__ x2) {
    __shared__ float qs[64];
    __shared__ float red[256];
    int bh = blockIdx.x >> 8, i = blockIdx.x & 255;
    int t = threadIdx.x;
    if (t < 64) qs[t] = qL[((size_t)bh * MM + i) * DD + t];
    __syncthreads();
    const float4* kp = (const float4*)(kL + ((size_t)bh * MM + t) * DD);
    float l = 0.f;
#pragma unroll
    for (int u = 0; u < 16; u++) {
        float4 kv = kp[u];
        l += qs[u*4+0]*kv.x + qs[u*4+1]*kv.y + qs[u*4+2]*kv.z + qs[u*4+3]*kv.w;
    }
    red[t] = l; __syncthreads();
    for (int s = 128; s > 0; s >>= 1) { if (t < s) red[t] = fmaxf(red[t], red[t + s]); __syncthreads(); }
    float mx = red[0]; __syncthreads();
    float e = __expf(l - mx);
    red[t] = e; __syncthreads();
    for (int s = 128; s > 0; s >>= 1) { if (t < s) red[t] += red[t + s]; __syncthreads(); }
    x2[((size_t)bh * MM + i) * MM + t] = e / red[0];
}

__global__ void init_scal(float* scal) {
    if (threadIdx.x == 0) { scal[0] = 0.f; scal[1] = 0.f; }
}

// max over (bh,i) of sum_j |x|  -> scal[0]
__global__ void rsum_max(const float* __restrict__ x2, float* scal) {
    __shared__ float red[256];
    int t = threadIdx.x;
    float v = fabsf(x2[(size_t)blockIdx.x * MM + t]);
    red[t] = v; __syncthreads();
    for (int s = 128; s > 0; s >>= 1) { if (t < s) red[t] += red[t + s]; __syncthreads(); }
    if (t == 0) atomicMax((unsigned int*)&scal[0], __float_as_uint(red[0]));
}

// max over (bh,j) of sum_i |x|  -> scal[1]
__global__ void csum_max(const float* __restrict__ x2, float* scal) {
    __shared__ float red[256];
    int t = threadIdx.x;
    const float* xp = x2 + (size_t)blockIdx.x * MM * MM;
    float s = 0.f;
    for (int i = 0; i < MM; i++) s += fabsf(xp[(size_t)i * MM + t]);
    red[t] = s; __syncthreads();
    for (int st = 128; st > 0; st >>= 1) { if (t < st) red[t] = fmaxf(red[t], red[t + st]); __syncthreads(); }
    if (t == 0) atomicMax((unsigned int*)&scal[1], __float_as_uint(red[0]));
}

// ---------------------------------------------------------------------------
// v transpose: vT[bh][d][n] <- v[bh][n][d].
__global__ void transpose_v(const bf16* __restrict__ v, bf16* __restrict__ vT) {
    int gw = blockIdx.x * 4 + (threadIdx.x >> 6);   // global wave id
    int lane = threadIdx.x & 63;                     // = d
    int bh = gw >> 8;
    int c  = gw & 255;                               // n-chunk (32 tokens)
    const bf16* vb = v + ((size_t)bh * NN + c * 32) * DD + lane;
    unsigned short buf[32];
#pragma unroll
    for (int i = 0; i < 32; i++) buf[i] = *(const unsigned short*)(vb + (size_t)i * DD);
    bf16* dst = vT + ((size_t)bh * DD + lane) * NN + c * 32;
#pragma unroll
    for (int u = 0; u < 4; u++)
        *(uint4*)(dst + u * 8) = *(uint4*)&buf[u * 8];
}

// ---------------------------------------------------------------------------
// MFMA flash attn3v: t1 = softmax(qL @ k^T over n) @ v
// 2 waves / 32 landmark rows per block; grid 256 blocks (8 rb x 32 bh),
// XCD-pinned: all 8 row-blocks of one bh map to the same XCD (g%8) so the
// 2 MB k+vT working set is fetched once into that XCD's 4 MB L2.
#define NJ 128
#define KS2 72
#define VS2 136
#define PS2 136
__global__ __launch_bounds__(128, 2) void attn3v_mfma(
        const float* __restrict__ qL, const bf16* __restrict__ k,
        const bf16* __restrict__ vT, float* __restrict__ t1) {
    __shared__ short ks[NJ * KS2];          // 18432 B  [j][d]
    __shared__ short vs[DD * VS2];          // 17408 B  [d][j]
    __shared__ short ps[2][16 * PS2];       //  8704 B  per-wave P [row][j]
    // XCD-locality decode: g%8 = XCD; 4 bh per XCD, 8 row-blocks per bh.
    int g = blockIdx.x;
    int c = g & 7, t = g >> 3;
    int bh = c + 8 * (t >> 3);
    int r0 = (t & 7) * 32;
    int tid = threadIdx.x;
    int wave = tid >> 6, lane = tid & 63;
    int ln = lane & 15, quad = lane >> 4;
    int m = r0 + wave * 16 + ln;
    const float* qrow = qL + ((size_t)bh * MM + m) * DD;
    bf16x8 a0, a1;
#pragma unroll
    for (int u = 0; u < 8; u++) {
        ((short*)&a0)[u] = f2bs(qrow[quad * 8 + u]);
        ((short*)&a1)[u] = f2bs(qrow[32 + quad * 8 + u]);
    }
    const uint4* kg = (const uint4*)(k + (size_t)bh * NN * DD);
    const uint4* vg = (const uint4*)(vT + (size_t)bh * DD * NN);
    float mrow[4], lrow[4];
    f32x4 o[4];
#pragma unroll
    for (int r = 0; r < 4; r++) { mrow[r] = -1e30f; lrow[r] = 0.f; }
#pragma unroll
    for (int ct = 0; ct < 4; ct++) o[ct] = (f32x4){0.f, 0.f, 0.f, 0.f};
    short* pw = &ps[wave][0];

    for (int j0 = 0; j0 < NN; j0 += NJ) {
        __syncthreads();
#pragma unroll
        for (int it = 0; it < 8; it++) {
            int idx = it * 128 + tid;
            int row = idx >> 3, c8 = idx & 7;
            uint4 pk = kg[(size_t)(j0 + row) * 8 + c8];
            *(uint4*)&ks[row * KS2 + c8 * 8] = pk;
        }
#pragma unroll
        for (int it = 0; it < 8; it++) {
            int idx = it * 128 + tid;
            int row = idx >> 4, c8 = idx & 15;
            uint4 pv = vg[(size_t)row * (NN / 8) + (j0 / 8) + c8];
            *(uint4*)&vs[row * VS2 + c8 * 8] = pv;
        }
        __syncthreads();
        f32x4 s[8];
#pragma unroll
        for (int ct = 0; ct < 8; ct++) {
            const short* kp = &ks[(ct * 16 + ln) * KS2 + quad * 8];
            bf16x8 b0 = *(const bf16x8*)kp;
            bf16x8 b1 = *(const bf16x8*)(kp + 32);
            f32x4 cc = {0.f, 0.f, 0.f, 0.f};
            cc = __builtin_amdgcn_mfma_f32_16x16x32_bf16(a0, b0, cc, 0, 0, 0);
            cc = __builtin_amdgcn_mfma_f32_16x16x32_bf16(a1, b1, cc, 0, 0, 0);
            s[ct] = cc;
        }
#pragma unroll
        for (int r = 0; r < 4; r++) {
            float v = -1e30f;
#pragma unroll
            for (int ct = 0; ct < 8; ct++) v = fmaxf(v, s[ct][r]);
            v = fmaxf(v, __shfl_xor(v, 1));
            v = fmaxf(v, __shfl_xor(v, 2));
            v = fmaxf(v, __shfl_xor(v, 4));
            v = fmaxf(v, __shfl_xor(v, 8));
            float mn = fmaxf(mrow[r], v);
            float alpha = __expf(mrow[r] - mn);
            mrow[r] = mn;
            float psum = 0.f;
#pragma unroll
            for (int ct = 0; ct < 8; ct++) { float e = __expf(s[ct][r] - mn); s[ct][r] = e; psum += e; }
            lrow[r] = lrow[r] * alpha + psum;
#pragma unroll
            for (int c2 = 0; c2 < 4; c2++) o[c2][r] *= alpha;
        }
#pragma unroll
        for (int ct = 0; ct < 8; ct++)
#pragma unroll
            for (int r = 0; r < 4; r++)
                pw[(quad * 4 + r) * PS2 + ct * 16 + ln] = f2bs(s[ct][r]);
#pragma unroll
        for (int kstep = 0; kstep < 4; kstep++) {
            bf16x8 pa = *(const bf16x8*)&pw[ln * PS2 + kstep * 32 + quad * 8];
#pragma unroll
            for (int ct = 0; ct < 4; ct++) {
                bf16x8 pb = *(const bf16x8*)&vs[(ct * 16 + ln) * VS2 + kstep * 32 + quad * 8];
                o[ct] = __builtin_amdgcn_mfma_f32_16x16x32_bf16(pa, pb, o[ct], 0, 0, 0);
            }
        }
    }
#pragma unroll
    for (int r = 0; r < 4; r++) {
        float l = lrow[r];
        l += __shfl_xor(l, 1);
        l += __shfl_xor(l, 2);
        l += __shfl_xor(l, 4);
        l += __shfl_xor(l, 8);
        lrow[r] = 1.0f / l;
    }
#pragma unroll
    for (int ct = 0; ct < 4; ct++)
#pragma unroll
        for (int r = 0; r < 4; r++) {
            int row = r0 + wave * 16 + quad * 4 + r;
            t1[((size_t)bh * MM + row) * DD + ct * 16 + ln] = o[ct][r] * lrow[r];
        }
}

// ---------------------------------------------------------------------------
// MFMA fused attn1: oh[b,i,h*64+d] = softmax(q_i kL^T) @ t2
#define KLS 72
#define T2S 264
__global__ __launch_bounds__(256, 1) void attn1_mfma(
        const bf16* __restrict__ q, const short* __restrict__ kl16,
        const short* __restrict__ t2t, bf16* __restrict__ oh) {
    __shared__ short kls[MM * KLS];
    __shared__ short t2s[DD * T2S];
    __shared__ short ps1[4][16 * T2S];
    int bh = blockIdx.y;
    int n0 = blockIdx.x * 64;
    int tid = threadIdx.x;
    const short* kLb = kl16 + (size_t)bh * MM * DD;
    for (int idx = tid; idx < MM * DD / 8; idx += 256) {   // 8 iters, 16B each
        int l = idx >> 3, d8 = (idx & 7) * 8;
        *(uint4*)&kls[l * KLS + d8] = *(const uint4*)&kLb[idx * 8];
    }
    const short* t2b = t2t + (size_t)bh * DD * MM;
    for (int idx = tid; idx < DD * MM / 8; idx += 256) {   // 8 iters, 16B each
        int c = idx >> 5, r = (idx & 31) * 8;
        *(uint4*)&t2s[c * T2S + r] = *(const uint4*)&t2b[idx * 8];
    }
    __syncthreads();
    int wave = tid >> 6, lane = tid & 63;
    int ln = lane & 15, quad = lane >> 4;
    int m = n0 + wave * 16 + ln;
    const bf16* qrow = q + ((size_t)bh * NN + m) * DD;
    bf16x8 a0 = *(const bf16x8*)(qrow + quad * 8);
    bf16x8 a1 = *(const bf16x8*)(qrow + 32 + quad * 8);
    f32x4 acc[16];
#pragma unroll
    for (int nt = 0; nt < 16; nt++) {
        const short* kp = &kls[(nt * 16 + ln) * KLS + quad * 8];
        bf16x8 b0 = *(const bf16x8*)kp;
        bf16x8 b1 = *(const bf16x8*)(kp + 32);
        f32x4 c = {0.f, 0.f, 0.f, 0.f};
        c = __builtin_amdgcn_mfma_f32_16x16x32_bf16(a0, b0, c, 0, 0, 0);
        c = __builtin_amdgcn_mfma_f32_16x16x32_bf16(a1, b1, c, 0, 0, 0);
        acc[nt] = c;
    }
    float inv[4];
#pragma unroll
    for (int r = 0; r < 4; r++) {
        float v = -1e30f;
#pragma unroll
        for (int nt = 0; nt < 16; nt++) v = fmaxf(v, acc[nt][r]);
        v = fmaxf(v, __shfl_xor(v, 1));
        v = fmaxf(v, __shfl_xor(v, 2));
        v = fmaxf(v, __shfl_xor(v, 4));
        v = fmaxf(v, __shfl_xor(v, 8));
        float s = 0.f;
#pragma unroll
        for (int nt = 0; nt < 16; nt++) { float e = __expf(acc[nt][r] - v); acc[nt][r] = e; s += e; }
        s += __shfl_xor(s, 1);
        s += __shfl_xor(s, 2);
        s += __shfl_xor(s, 4);
        s += __shfl_xor(s, 8);
        inv[r] = 1.0f / s;
    }
    short* pw = &ps1[wave][0];
#pragma unroll
    for (int nt = 0; nt < 16; nt++)
#pragma unroll
        for (int r = 0; r < 4; r++)
            pw[(quad * 4 + r) * T2S + nt * 16 + ln] = f2bs(acc[nt][r]);
    __syncthreads();
    f32x4 o[4];
#pragma unroll
    for (int nt = 0; nt < 4; nt++) o[nt] = (f32x4){0.f, 0.f, 0.f, 0.f};
#pragma unroll
    for (int ks = 0; ks < 8; ks++) {
        bf16x8 pa = *(const bf16x8*)&pw[ln * T2S + ks * 32 + quad * 8];
#pragma unroll
        for (int nt = 0; nt < 4; nt++) {
            bf16x8 pb = *(const bf16x8*)&t2s[(nt * 16 + ln) * T2S + ks * 32 + quad * 8];
            o[nt] = __builtin_amdgcn_mfma_f32_16x16x32_bf16(pa, pb, o[nt], 0, 0, 0);
        }
    }
    int b_ = bh >> 3, h = bh & 7;
#pragma unroll
    for (int nt = 0; nt < 4; nt++)
#pragma unroll
        for (int r = 0; r < 4; r++) {
            int row = n0 + wave * 16 + quad * 4 + r;
            int col = nt * 16 + ln;
            oh[((size_t)(b_ * NN + row)) * DIM + h * 64 + col] = f2b(o[nt][r] * inv[r]);
        }
}

// depthwise conv residual, vectorized: thread = (bh, n, 8-d chunk)
__global__ __launch_bounds__(256) void conv_add2(const bf16* __restrict__ v,
                                                 const float* __restrict__ w,
                                                 bf16* __restrict__ oh) {
    int tid = threadIdx.x;
    int c = tid & 7;                 // d-chunk (8 bf16)
    int nsub = tid >> 3;             // 0..31
    int bh = blockIdx.x >> 8;
    int n = ((blockIdx.x & 255) << 5) + nsub;
    int b_ = bh >> 3, h = bh & 7;
    const bf16* vb = v + (size_t)bh * NN * DD + c * 8;
    float acc[8] = {};
#pragma unroll
    for (int t = 0; t < KER; t++) {
        int src = n + t - 16;
        if (src >= 0 && src < NN) {
            uint4 pk = *(const uint4*)(vb + (size_t)src * DD);
            float wt = w[h * KER + t];
            unsigned int ua[4] = {pk.x, pk.y, pk.z, pk.w};
#pragma unroll
            for (int j = 0; j < 4; j++) {
                acc[2 * j]     += wt * blo(ua[j]);
                acc[2 * j + 1] += wt * bhi(ua[j]);
            }
        }
    }
    size_t oidx = ((size_t)(b_ * NN + n)) * DIM + h * 64 + c * 8;
    uint4 cur = *(uint4*)&oh[oidx];
    unsigned int cu[4] = {cur.x, cur.y, cur.z, cur.w};
    short outp[8];
#pragma unroll
    for (int j = 0; j < 4; j++) {
        outp[2 * j]     = f2bs(blo(cu[j]) + acc[2 * j]);
        outp[2 * j + 1] = f2bs(bhi(cu[j]) + acc[2 * j + 1]);
    }
    *(uint4*)&oh[oidx] = *(uint4*)outp;
}

// ---------------------------------------------------------------------------

extern "C" void kernel_launch(void* const* d_in, const int* in_sizes, int n_in,
                              void* d_out, int out_size, void* d_ws, size_t ws_size,
                              hipStream_t stream) {
    const float* x    = (const float*)d_in[0];
    const float* Wqkv = (const float*)d_in[1];
    const float* Wout = (const float*)d_in[2];
    const float* bout = (const float*)d_in[3];
    const float* cw   = (const float*)d_in[4];
    float* out = (float*)d_out;

    const size_t SZ_QKV = (size_t)BB * NH * NN * DD;   // 16,777,216 elems
    const size_t SZ_L   = (size_t)BB * NH * MM * DD;   // 524,288
    const size_t SZ_M2  = (size_t)BB * NH * MM * MM;   // 2,097,152

    // --- workspace plumbing (unchanged footprint) ---
    char* p = (char*)d_ws;
    bf16* q    = (bf16*)p;  p += SZ_QKV * 2;    // 32 MB
    bf16* v    = (bf16*)p;  p += SZ_QKV * 2;    // 32 MB
    float* x2   = (float*)p; p += SZ_M2 * 4;    // 8 MB each
    float* zf   = (float*)p; p += SZ_M2 * 4;    // final fp32 z lives here
    float* z2r  = (float*)p; p += SZ_M2 * 4;    // region reused for x2 pairs
    float* bAr  = (float*)p; p += SZ_M2 * 4;    // region reused for bufA pairs
    float* bBr  = (float*)p; p += SZ_M2 * 4;    // region reused for bufA^T pairs
    float* qL   = (float*)p; p += SZ_L * 4;     // 2 MB each
    float* kL   = (float*)p; p += SZ_L * 4;
    float* t1   = (float*)p; p += SZ_L * 4;
    short* t2t  = (short*)p; p += SZ_L * 4;
    float* scal = (float*)p; p += 2 * 4;
    size_t need = (size_t)(p - (char*)d_ws);
    bf16* k  = (bf16*)d_out;                     // first 32 MB of out buffer
    bf16* vT = (bf16*)d_out + SZ_QKV;            // second 32 MB of out buffer
    bf16* oh = (bf16*)x2;                        // 32 MB over dead pinv region

    // split-precision scratch for projections (aliased, dead at use time):
    short* xh  = (short*)x2;                     // 32 MB over x2..bAr
    short* xl  = (short*)vT;                     // vT half of d_out
    short* wqh = (short*)bBr;                    // 1.5 MB
    short* wql = (short*)bBr + (size_t)K3 * DIM;
    short* woh = (short*)q;                      // q dead after attn1_mfma
    short* wol = (short*)q + (size_t)DIM * DIM;
    short* kl16 = (short*)t1;                    // t1 dead after bgemm_t2t

    // pinv pair scratch (after attn3v, k/vT in d_out are dead):
    const size_t U = SZ_M2;                      // 4 MiB per bf16 array
    short* db = (short*)d_out;
    short* bufBTh = db + 0 * U;  short* bufBTl = db + 1 * U;
    short* z2BTh  = db + 2 * U;  short* z2BTl  = db + 3 * U;
    short* zPair[2][4] = {                       // {Ah, Al, BTh, BTl} x 2 buffers
        { db + 4 * U, db + 5 * U, db + 6 * U, db + 7 * U },
        { db + 8 * U, db + 9 * U, db + 10 * U, db + 11 * U } };
    short* x2Ah = (short*)z2r;   short* x2Al = (short*)z2r + U;
    short* bufAh = (short*)bAr;  short* bufAl = (short*)bAr + U;
    short* bufATh = (short*)bBr; short* bufATl = (short*)bBr + U;

    if (ws_size < need) {
        zero_out<<<out_size / 256, 256, 0, stream>>>(out);
        return;
    }

    // 1. split inputs, project qkv via MFMA
    split_x<<<(int)(SZ_QKV / (256 * 8)), 256, 0, stream>>>(x, xh, xl);
    split_wT<<<(K3 * DIM) / 256, 256, 0, stream>>>(Wqkv, wqh, wql, K3);
    gemm_qkv_mfma<<<3072, 256, 0, stream>>>(xh, xl, wqh, wql, q, k, v);
    // 2. vT = v^T (overwrites xl -- dead)
    transpose_v<<<(BB * NH * MM) / 4, 256, 0, stream>>>(v, vT);
    // 3. landmark means + attn2 softmax (x2 overwrites xh -- dead)
    landmark_means<<<(BB * NH * MM * DD) / 256, 256, 0, stream>>>(q, k, qL, kL);
    attn2_softmax<<<BB * NH * MM, 256, 0, stream>>>(qL, kL, x2);
    // 4. attn3v FIRST (frees k/vT = all of d_out for pinv scratch)
    //    256 blocks, XCD-pinned per bh for L2 reuse of k/vT
    attn3v_mfma<<<256, 128, 0, stream>>>(qL, k, vT, t1);
    // 5. pinv scalars + z0 pairs + x2 pairs
    init_scal<<<1, 64, 0, stream>>>(scal);
    rsum_max<<<BB * NH * MM, 256, 0, stream>>>(x2, scal);
    csum_max<<<BB * NH, 256, 0, stream>>>(x2, scal);
    z_init_pair<<<(int)(SZ_M2 / (256 * 8)), 256, 0, stream>>>(
        x2, scal, zPair[0][0], zPair[0][1], zPair[0][2], zPair[0][3]);
    split_x<<<(int)(SZ_M2 / (256 * 8)), 256, 0, stream>>>(x2, x2Ah, x2Al);
    // 6. Newton-Schulz pinv, split-precision MFMA (64x64 tiles, 512 blocks)
    int cur = 0;
    for (int it = 0; it < 6; it++) {
        int nxt = cur ^ 1;
        bgemm_pair<<<dim3(4, 4, BB * NH), 256, 0, stream>>>(
            x2Ah, x2Al, zPair[cur][2], zPair[cur][3],
            bufAh, bufAl, bufATh, bufATl, nullptr, 1.f, 0.f, 1 | 2);
        eye7_pair<<<(int)(SZ_M2 / (256 * 8)), 256, 0, stream>>>(
            bufATh, bufATl, bufBTh, bufBTl);
        bgemm_pair<<<dim3(4, 4, BB * NH), 256, 0, stream>>>(
            bufAh, bufAl, bufBTh, bufBTl,
            nullptr, nullptr, z2BTh, z2BTl, nullptr, -1.f, 15.f, 2);
        bgemm_pair<<<dim3(4, 4, BB * NH), 256, 0, stream>>>(
            bufAh, bufAl, z2BTh, z2BTl,
            nullptr, nullptr, bufBTh, bufBTl, nullptr, -1.f, 13.f, 2);
        int fl = (it == 5) ? 4 : (1 | 2);
        bgemm_pair<<<dim3(4, 4, BB * NH), 256, 0, stream>>>(
            zPair[cur][0], zPair[cur][1], bufBTh, bufBTl,
            zPair[nxt][0], zPair[nxt][1], zPair[nxt][2], zPair[nxt][3],
            zf, 0.25f, 0.f, fl);
        cur = nxt;
    }
    // 7. t2t = (z @ t1)^T in bf16 [bh][64][256]
    bgemm_t2t<<<dim3(1, 4, BB * NH), 256, 0, stream>>>(zf, t1, t2t);
    // 7b. kL -> bf16 (over dead t1) for attn1 staging
    kl_to_bf16<<<(int)(SZ_L / (256 * 4)), 256, 0, stream>>>(kL, kl16);
    // 8. oh = softmax(q kL^T) @ t2  (oh overwrites x2/zf/z2r/bAr -- all dead)
    attn1_mfma<<<dim3(NN / 64, BB * NH), 256, 0, stream>>>(q, kl16, t2t, oh);
    // 9. oh += depthwise conv residual (v dead after)
    conv_add2<<<BB * NH * 256, 256, 0, stream>>>(v, cw, oh);
    // 10. out = oh @ (WoutH + WoutL) + bout (overwrites d_out; scratch dead)
    split_wT<<<(DIM * DIM) / 256, 256, 0, stream>>>(Wout, woh, wol, DIM);
    gemm_out_mfma<<<1024, 256, 0, stream>>>(oh, woh, wol, bout, out);

    (void)in_sizes; (void)n_in; (void)ws_size;
}

// Round 9
// 1062.144 us; speedup vs baseline: 1.2406x; 1.1121x over previous
//
#include <hip/hip_runtime.h>
#include <hip/hip_bf16.h>
#include <math.h>

// Problem constants
#define BB 4
#define NH 8
#define NN 8192
#define DD 64
#define MM 256
#define LG 32
#define DIM 512
#define K3 1536
#define KER 33

typedef __hip_bfloat16 bf16;
typedef __attribute__((ext_vector_type(8))) short bf16x8;
typedef __attribute__((ext_vector_type(4))) float f32x4;

__device__ __forceinline__ float b2f(bf16 x) { return __bfloat162float(x); }
__device__ __forceinline__ bf16 f2b(float x) { return __float2bfloat16(x); }
__device__ __forceinline__ short f2bs(float x) { bf16 h = __float2bfloat16(x); return *reinterpret_cast<short*>(&h); }
__device__ __forceinline__ float bsf(short s) { return __uint_as_float(((unsigned int)(unsigned short)s) << 16); }
// bf16-pair unpack from a uint32 (lo short = first element)
__device__ __forceinline__ float blo(unsigned int u) { return __uint_as_float(u << 16); }
__device__ __forceinline__ float bhi(unsigned int u) { return __uint_as_float(u & 0xffff0000u); }

// async global->LDS, 16B per lane (dest must be linear: base + lane*16)
__device__ __forceinline__ void g2lds16(const void* g, void* l) {
    __builtin_amdgcn_global_load_lds(
        (const __attribute__((address_space(1))) unsigned int*)g,
        (__attribute__((address_space(3))) unsigned int*)l, 16, 0, 0);
}

// diagnostic fallback: zero the output
__global__ void zero_out(float* __restrict__ o) {
    o[(size_t)blockIdx.x * 256 + threadIdx.x] = 0.f;
}

// ---------------------------------------------------------------------------
// split fp32 -> bf16 hi + bf16 lo (residual), 8 elems/thread, 16B stores
__global__ void split_x(const float* __restrict__ x, short* __restrict__ xh,
                        short* __restrict__ xl) {
    size_t i = ((size_t)blockIdx.x * 256 + threadIdx.x) * 8;
    const float4* xp = (const float4*)(x + i);
    float4 v0 = xp[0], v1 = xp[1];
    float vv[8] = {v0.x, v0.y, v0.z, v0.w, v1.x, v1.y, v1.z, v1.w};
    short hb[8], lb[8];
#pragma unroll
    for (int u = 0; u < 8; u++) {
        bf16 h = f2b(vv[u]);
        hb[u] = *(short*)&h;
        lb[u] = f2bs(vv[u] - b2f(h));
    }
    *(uint4*)(xh + i) = *(uint4*)hb;
    *(uint4*)(xl + i) = *(uint4*)lb;
}

// split + transpose weight: W[k][n] fp32 -> wh/wl [n][K=512] bf16
__global__ void split_wT(const float* __restrict__ W, short* __restrict__ wh,
                         short* __restrict__ wl, int Nn) {
    int idx = blockIdx.x * 256 + threadIdx.x;   // n*512 + k
    int k = idx & 511, n = idx >> 9;
    float v = W[(size_t)k * Nn + n];
    bf16 h = f2b(v);
    wh[idx] = *(short*)&h;
    wl[idx] = f2bs(v - b2f(h));
}

// ---------------------------------------------------------------------------
// qkv projection via MFMA, split-precision (Xh@Wh + Xl@Wh + Xh@Wl).
__global__ __launch_bounds__(256) void gemm_qkv_mfma(
        const short* __restrict__ xh, const short* __restrict__ xl,
        const short* __restrict__ wh, const short* __restrict__ wl,
        bf16* __restrict__ q, bf16* __restrict__ k, bf16* __restrict__ v) {
    __shared__ short Ah[128 * 32];
    __shared__ short Al[128 * 32];
    __shared__ short Bh[128 * 32];
    __shared__ short Bl[128 * 32];
    int orig = blockIdx.x;
    int wg = (orig & 7) * 384 + (orig >> 3);
    int by = wg / 12, bx = wg - by * 12;
    int rowBase = by * 128, colBase = bx * 128;
    int tid = threadIdx.x;
    int rl = tid >> 2;
    int ch = (tid & 3) * 8;
    int wave = tid >> 6, lane = tid & 63;
    int ln = lane & 15, quad = lane >> 4;
    int wr = (wave >> 1) * 64, wc = (wave & 1) * 64;
    f32x4 acc[4][4];
#pragma unroll
    for (int mt = 0; mt < 4; mt++)
#pragma unroll
        for (int nt = 0; nt < 4; nt++) acc[mt][nt] = (f32x4){0.f, 0.f, 0.f, 0.f};

    for (int k0 = 0; k0 < DIM; k0 += 32) {
        __syncthreads();
#pragma unroll
        for (int p = 0; p < 2; p++) {
            int r = p * 64 + rl;
            size_t ga = (size_t)(rowBase + r) * DIM + k0 + ch;
            size_t gb = (size_t)(colBase + r) * DIM + k0 + ch;
            int lo = r * 32 + ch;
            g2lds16(xh + ga, &Ah[lo]);
            g2lds16(xl + ga, &Al[lo]);
            g2lds16(wh + gb, &Bh[lo]);
            g2lds16(wl + gb, &Bl[lo]);
        }
        __syncthreads();
        bf16x8 a_h[4], a_l[4], b_h[4], b_l[4];
#pragma unroll
        for (int mt = 0; mt < 4; mt++) {
            int o = (wr + mt * 16 + ln) * 32 + quad * 8;
            a_h[mt] = *(const bf16x8*)&Ah[o];
            a_l[mt] = *(const bf16x8*)&Al[o];
        }
#pragma unroll
        for (int nt = 0; nt < 4; nt++) {
            int o = (wc + nt * 16 + ln) * 32 + quad * 8;
            b_h[nt] = *(const bf16x8*)&Bh[o];
            b_l[nt] = *(const bf16x8*)&Bl[o];
        }
#pragma unroll
        for (int mt = 0; mt < 4; mt++)
#pragma unroll
            for (int nt = 0; nt < 4; nt++) {
                acc[mt][nt] = __builtin_amdgcn_mfma_f32_16x16x32_bf16(a_h[mt], b_h[nt], acc[mt][nt], 0, 0, 0);
                acc[mt][nt] = __builtin_amdgcn_mfma_f32_16x16x32_bf16(a_l[mt], b_h[nt], acc[mt][nt], 0, 0, 0);
                acc[mt][nt] = __builtin_amdgcn_mfma_f32_16x16x32_bf16(a_h[mt], b_l[nt], acc[mt][nt], 0, 0, 0);
            }
    }
    int part = colBase >> 9;
    bf16* dst = part == 0 ? q : (part == 1 ? k : v);
    float scale = part == 0 ? 0.125f : 1.0f;
#pragma unroll
    for (int mt = 0; mt < 4; mt++)
#pragma unroll
        for (int nt = 0; nt < 4; nt++)
#pragma unroll
            for (int r = 0; r < 4; r++) {
                int row = rowBase + wr + mt * 16 + quad * 4 + r;
                int col = colBase + wc + nt * 16 + ln;
                int h = (col & 511) >> 6, d = col & 63;
                int b_ = row >> 13, n_ = row & 8191;
                size_t di = ((size_t)(b_ * NH + h) * NN + n_) * DD + d;
                dst[di] = f2b(acc[mt][nt][r] * scale);
            }
}

// out projection via MFMA: oh(bf16) @ (Wh+Wl) + bias -> fp32
__global__ __launch_bounds__(256) void gemm_out_mfma(
        const bf16* __restrict__ A, const short* __restrict__ wh,
        const short* __restrict__ wl, const float* __restrict__ bias,
        float* __restrict__ C) {
    __shared__ short As[128 * 32];
    __shared__ short Bh[128 * 32];
    __shared__ short Bl[128 * 32];
    int orig = blockIdx.x;                       // nwg = 1024
    int wg = (orig & 7) * 128 + (orig >> 3);
    int by = wg >> 2, bx = wg & 3;
    int rowBase = by * 128, colBase = bx * 128;
    int tid = threadIdx.x;
    int rl = tid >> 2, ch = (tid & 3) * 8;
    int wave = tid >> 6, lane = tid & 63;
    int ln = lane & 15, quad = lane >> 4;
    int wr = (wave >> 1) * 64, wc = (wave & 1) * 64;
    const short* Ab = (const short*)A;
    f32x4 acc[4][4];
#pragma unroll
    for (int mt = 0; mt < 4; mt++)
#pragma unroll
        for (int nt = 0; nt < 4; nt++) acc[mt][nt] = (f32x4){0.f, 0.f, 0.f, 0.f};

    for (int k0 = 0; k0 < DIM; k0 += 32) {
        __syncthreads();
#pragma unroll
        for (int p = 0; p < 2; p++) {
            int r = p * 64 + rl;
            size_t ga = (size_t)(rowBase + r) * DIM + k0 + ch;
            size_t gb = (size_t)(colBase + r) * DIM + k0 + ch;
            int lo = r * 32 + ch;
            g2lds16(Ab + ga, &As[lo]);
            g2lds16(wh + gb, &Bh[lo]);
            g2lds16(wl + gb, &Bl[lo]);
        }
        __syncthreads();
        bf16x8 a[4], b_h[4], b_l[4];
#pragma unroll
        for (int mt = 0; mt < 4; mt++)
            a[mt] = *(const bf16x8*)&As[(wr + mt * 16 + ln) * 32 + quad * 8];
#pragma unroll
        for (int nt = 0; nt < 4; nt++) {
            int o = (wc + nt * 16 + ln) * 32 + quad * 8;
            b_h[nt] = *(const bf16x8*)&Bh[o];
            b_l[nt] = *(const bf16x8*)&Bl[o];
        }
#pragma unroll
        for (int mt = 0; mt < 4; mt++)
#pragma unroll
            for (int nt = 0; nt < 4; nt++) {
                acc[mt][nt] = __builtin_amdgcn_mfma_f32_16x16x32_bf16(a[mt], b_h[nt], acc[mt][nt], 0, 0, 0);
                acc[mt][nt] = __builtin_amdgcn_mfma_f32_16x16x32_bf16(a[mt], b_l[nt], acc[mt][nt], 0, 0, 0);
            }
    }
#pragma unroll
    for (int mt = 0; mt < 4; mt++)
#pragma unroll
        for (int nt = 0; nt < 4; nt++)
#pragma unroll
            for (int r = 0; r < 4; r++) {
                int row = rowBase + wr + mt * 16 + quad * 4 + r;
                int col = colBase + wc + nt * 16 + ln;
                C[(size_t)row * DIM + col] = acc[mt][nt][r] + bias[col];
            }
}

// ---------------------------------------------------------------------------
// Batched split-precision MFMA GEMM for the pinv chain.
// val = scale*(A@B) + alpha*I.  A-layout/fp32 outputs get val;
// B^T-layout output gets scaleB*val + alphaB*I (lets eye7 fuse into GEMM1).
// 64x64 tile, 4 waves, grid dim3(4,4,32) = 512 blocks (2 blocks/CU).
__global__ __launch_bounds__(256) void bgemm_pair(
        const short* __restrict__ Ah, const short* __restrict__ Al,
        const short* __restrict__ Bh, const short* __restrict__ Bl,
        short* __restrict__ oAh, short* __restrict__ oAl,
        short* __restrict__ oBh, short* __restrict__ oBl,
        float* __restrict__ oF, float scale, float alpha,
        float scaleB, float alphaB, int flags) {
    __shared__ short sAh[64 * 32];
    __shared__ short sAl[64 * 32];
    __shared__ short sBh[64 * 32];
    __shared__ short sBl[64 * 32];
    int bat = blockIdx.z;
    int rowBase = blockIdx.y * 64;    // 0..192
    int colBase = blockIdx.x * 64;    // 0..192
    const size_t MB = (size_t)bat * (MM * MM);
    int tid = threadIdx.x;
    int rl = tid >> 2, ch = (tid & 3) * 8;   // rl 0..63
    int wave = tid >> 6, lane = tid & 63;
    int ln = lane & 15, quad = lane >> 4;
    int wr = (wave >> 1) * 32, wc = (wave & 1) * 32;
    f32x4 acc[2][2];
#pragma unroll
    for (int mt = 0; mt < 2; mt++)
#pragma unroll
        for (int nt = 0; nt < 2; nt++) acc[mt][nt] = (f32x4){0.f, 0.f, 0.f, 0.f};

    for (int k0 = 0; k0 < MM; k0 += 32) {
        __syncthreads();
        {
            size_t ga = MB + (size_t)(rowBase + rl) * MM + k0 + ch;
            size_t gb = MB + (size_t)(colBase + rl) * MM + k0 + ch;
            int lo = rl * 32 + ch;
            g2lds16(Ah + ga, &sAh[lo]);
            g2lds16(Al + ga, &sAl[lo]);
            g2lds16(Bh + gb, &sBh[lo]);
            g2lds16(Bl + gb, &sBl[lo]);
        }
        __syncthreads();
        bf16x8 a_h[2], a_l[2], b_h[2], b_l[2];
#pragma unroll
        for (int mt = 0; mt < 2; mt++) {
            int o = (wr + mt * 16 + ln) * 32 + quad * 8;
            a_h[mt] = *(const bf16x8*)&sAh[o];
            a_l[mt] = *(const bf16x8*)&sAl[o];
        }
#pragma unroll
        for (int nt = 0; nt < 2; nt++) {
            int o = (wc + nt * 16 + ln) * 32 + quad * 8;
            b_h[nt] = *(const bf16x8*)&sBh[o];
            b_l[nt] = *(const bf16x8*)&sBl[o];
        }
#pragma unroll
        for (int mt = 0; mt < 2; mt++)
#pragma unroll
            for (int nt = 0; nt < 2; nt++) {
                acc[mt][nt] = __builtin_amdgcn_mfma_f32_16x16x32_bf16(a_h[mt], b_h[nt], acc[mt][nt], 0, 0, 0);
                acc[mt][nt] = __builtin_amdgcn_mfma_f32_16x16x32_bf16(a_l[mt], b_h[nt], acc[mt][nt], 0, 0, 0);
                acc[mt][nt] = __builtin_amdgcn_mfma_f32_16x16x32_bf16(a_h[mt], b_l[nt], acc[mt][nt], 0, 0, 0);
            }
    }
#pragma unroll
    for (int mt = 0; mt < 2; mt++)
#pragma unroll
        for (int nt = 0; nt < 2; nt++) {
            short bh4[4], bl4[4];
            int col = colBase + wc + nt * 16 + ln;
            int row0 = rowBase + wr + mt * 16 + quad * 4;
#pragma unroll
            for (int r = 0; r < 4; r++) {
                int row = row0 + r;
                float val = scale * acc[mt][nt][r];
                if (row == col) val += alpha;
                if (flags & 4) oF[MB + (size_t)row * MM + col] = val;
                if (flags & 1) {
                    short vh = f2bs(val);
                    oAh[MB + (size_t)row * MM + col] = vh;
                    oAl[MB + (size_t)row * MM + col] = f2bs(val - bsf(vh));
                }
                float bv = scaleB * val;
                if (row == col) bv += alphaB;
                short bvh = f2bs(bv);
                bh4[r] = bvh; bl4[r] = f2bs(bv - bsf(bvh));
            }
            if (flags & 2) {
                size_t o = MB + (size_t)col * MM + row0;
                *(uint2*)&oBh[o] = *(uint2*)bh4;
                *(uint2*)&oBl[o] = *(uint2*)bl4;
            }
        }
}

// z0 = x2^T / (colmax + 1e-12) -> zA pairs + zBT pairs; also x2 -> A pairs.
// (rowmax of a softmax = 1 analytically, so scal[0] holds only colmax.)
__global__ void z_init_split(const float* __restrict__ x2, const float* __restrict__ scal,
                             short* __restrict__ x2Ah, short* __restrict__ x2Al,
                             short* __restrict__ zAh, short* __restrict__ zAl,
                             short* __restrict__ zBh, short* __restrict__ zBl) {
    size_t base = ((size_t)blockIdx.x * 256 + threadIdx.x) * 8;
    float inv = 1.0f / (scal[0] + 1e-12f);
    int c0 = (int)(base & 255);
    int r = (int)((base >> 8) & 255);
    size_t MB = (base >> 16) << 16;
    const float4* xp = (const float4*)(x2 + base);
    float4 v0 = xp[0], v1 = xp[1];
    float vv[8] = {v0.x, v0.y, v0.z, v0.w, v1.x, v1.y, v1.z, v1.w};
    short ho[8], lo_[8], h2[8], l2[8];
#pragma unroll
    for (int u = 0; u < 8; u++) {
        short xh = f2bs(vv[u]);
        h2[u] = xh; l2[u] = f2bs(vv[u] - bsf(xh));
        float zv = vv[u] * inv;
        short zh = f2bs(zv);
        ho[u] = zh; lo_[u] = f2bs(zv - bsf(zh));
    }
    *(uint4*)&x2Ah[base] = *(uint4*)h2;
    *(uint4*)&x2Al[base] = *(uint4*)l2;
    *(uint4*)&zBh[base] = *(uint4*)ho;
    *(uint4*)&zBl[base] = *(uint4*)lo_;
    // A layout: zA[bat][r][c] = z[r][c] = x2[bat][c][r]*inv  (strided read)
#pragma unroll
    for (int u = 0; u < 8; u++) {
        float v = x2[MB + (size_t)(c0 + u) * MM + r] * inv;
        short vh = f2bs(v);
        ho[u] = vh; lo_[u] = f2bs(v - bsf(vh));
    }
    *(uint4*)&zAh[base] = *(uint4*)ho;
    *(uint4*)&zAl[base] = *(uint4*)lo_;
}

// t2t = (z @ t1)^T per batch, stored bf16 [bh][d=64][landmark=256]
__global__ void bgemm_t2t(const float* __restrict__ A, const float* __restrict__ B,
                          short* __restrict__ T) {
    __shared__ float As[16][64];
    __shared__ float Bs[16][64];
    int bat = blockIdx.z;
    const float* Ab = A + (size_t)bat * MM * MM;   // z [256,256]
    const float* Bb = B + (size_t)bat * MM * DD;   // t1 [256,64]
    short* Tb = T + (size_t)bat * DD * MM;
    int tid = threadIdx.x;
    int rowBase = blockIdx.y * 64;
    int ty = tid >> 4, tx = tid & 15;
    float acc[4][4] = {};
    for (int k0 = 0; k0 < MM; k0 += 16) {
        for (int idx = tid; idx < 64 * 16; idx += 256) {
            int r = idx >> 4, c = idx & 15;
            As[c][r] = Ab[(size_t)(rowBase + r) * MM + k0 + c];
        }
        for (int idx = tid; idx < 16 * 64; idx += 256) {
            int r = idx >> 6, c = idx & 63;
            Bs[r][c] = Bb[(size_t)(k0 + r) * DD + c];
        }
        __syncthreads();
#pragma unroll
        for (int kk = 0; kk < 16; kk++) {
            float a[4], b[4];
#pragma unroll
            for (int i = 0; i < 4; i++) a[i] = As[kk][ty * 4 + i];
#pragma unroll
            for (int j = 0; j < 4; j++) b[j] = Bs[kk][tx * 4 + j];
#pragma unroll
            for (int i = 0; i < 4; i++)
#pragma unroll
                for (int j = 0; j < 4; j++) acc[i][j] += a[i] * b[j];
        }
        __syncthreads();
    }
#pragma unroll
    for (int i = 0; i < 4; i++) {
        int r = rowBase + ty * 4 + i;     // landmark
#pragma unroll
        for (int j = 0; j < 4; j++) {
            int c = tx * 4 + j;           // d
            Tb[(size_t)c * MM + r] = f2bs(acc[i][j]);
        }
    }
}

// ---------------------------------------------------------------------------
// landmark means: qL/kL[bh,mi,d] = mean over 32 tokens (bf16 in, fp32 out)
__global__ void landmark_means(const bf16* __restrict__ q, const bf16* __restrict__ k,
                               float* __restrict__ qL, float* __restrict__ kL) {
    int idx = blockIdx.x * 256 + threadIdx.x;   // (bh*256 + mi)*64 + d
    int d = idx & 63;
    int mi = (idx >> 6) & 255;
    int bh = idx >> 14;
    const bf16* qp = q + ((size_t)bh * NN + mi * LG) * DD + d;
    const bf16* kp = k + ((size_t)bh * NN + mi * LG) * DD + d;
    float sq = 0.f, sk = 0.f;
#pragma unroll
    for (int j = 0; j < LG; j++) { sq += b2f(qp[(size_t)j * DD]); sk += b2f(kp[(size_t)j * DD]); }
    qL[idx] = sq * (1.f / LG);
    kL[idx] = sk * (1.f / LG);
}

// kL fp32 -> bf16 copy (for attn1 staging)
__global__ void kl_to_bf16(const float* __restrict__ kL, short* __restrict__ kl16) {
    size_t i = ((size_t)blockIdx.x * 256 + threadIdx.x) * 4;
    float4 v = *(const float4*)(kL + i);
    short o[4] = {f2bs(v.x), f2bs(v.y), f2bs(v.z), f2bs(v.w)};
    *(uint2*)&kl16[i] = *(uint2*)o;
}

// attn2 = softmax(qL @ kL^T), one block per row (all fp32)
__global__ void attn2_softmax(const float* __restrict__ qL, const float* __restrict__ kL,
                              float* __restrict__ x2) {
    __shared__ float qs[64];
    __shared__ float red[256];
    int bh = blockIdx.x >> 8, i = blockIdx.x & 255;
    int t = threadIdx.x;
    if (t < 64) qs[t] = qL[((size_t)bh * MM + i) * DD + t];
    __syncthreads();
    const float4* kp = (const float4*)(kL + ((size_t)bh * MM + t) * DD);
    float l = 0.f;
#pragma unroll
    for (int u = 0; u < 16; u++) {
        float4 kv = kp[u];
        l += qs[u*4+0]*kv.x + qs[u*4+1]*kv.y + qs[u*4+2]*kv.z + qs[u*4+3]*kv.w;
    }
    red[t] = l; __syncthreads();
    for (int s = 128; s > 0; s >>= 1) { if (t < s) red[t] = fmaxf(red[t], red[t + s]); __syncthreads(); }
    float mx = red[0]; __syncthreads();
    float e = __expf(l - mx);
    red[t] = e; __syncthreads();
    for (int s = 128; s > 0; s >>= 1) { if (t < s) red[t] += red[t + s]; __syncthreads(); }
    x2[((size_t)bh * MM + i) * MM + t] = e / red[0];
}

__global__ void init_scal(float* scal) {
    if (threadIdx.x == 0) { scal[0] = 0.f; scal[1] = 0.f; }
}

// max over (bh,j) of sum_i |x|  -> scal[0]   (rowmax of softmax == 1)
__global__ void csum_max(const float* __restrict__ x2, float* scal) {
    __shared__ float red[256];
    int t = threadIdx.x;
    const float* xp = x2 + (size_t)blockIdx.x * MM * MM;
    float s = 0.f;
    for (int i = 0; i < MM; i++) s += fabsf(xp[(size_t)i * MM + t]);
    red[t] = s; __syncthreads();
    for (int st = 128; st > 0; st >>= 1) { if (t < st) red[t] = fmaxf(red[t], red[t + st]); __syncthreads(); }
    if (t == 0) atomicMax((unsigned int*)&scal[0], __float_as_uint(red[0]));
}

// ---------------------------------------------------------------------------
// v transpose: vT[bh][d][n] <- v[bh][n][d].
__global__ void transpose_v(const bf16* __restrict__ v, bf16* __restrict__ vT) {
    int gw = blockIdx.x * 4 + (threadIdx.x >> 6);   // global wave id
    int lane = threadIdx.x & 63;                     // = d
    int bh = gw >> 8;
    int c  = gw & 255;                               // n-chunk (32 tokens)
    const bf16* vb = v + ((size_t)bh * NN + c * 32) * DD + lane;
    unsigned short buf[32];
#pragma unroll
    for (int i = 0; i < 32; i++) buf[i] = *(const unsigned short*)(vb + (size_t)i * DD);
    bf16* dst = vT + ((size_t)bh * DD + lane) * NN + c * 32;
#pragma unroll
    for (int u = 0; u < 4; u++)
        *(uint4*)(dst + u * 8) = *(uint4*)&buf[u * 8];
}

// ---------------------------------------------------------------------------
// MFMA flash attn3v: t1 = softmax(qL @ k^T over n) @ v
// 2 waves / 32 landmark rows per block; grid 256 blocks (8 rb x 32 bh),
// XCD-pinned: all 8 row-blocks of one bh map to the same XCD (g%8).
#define NJ 128
#define KS2 72
#define VS2 136
#define PS2 136
__global__ __launch_bounds__(128, 2) void attn3v_mfma(
        const float* __restrict__ qL, const bf16* __restrict__ k,
        const bf16* __restrict__ vT, float* __restrict__ t1) {
    __shared__ short ks[NJ * KS2];          // 18432 B  [j][d]
    __shared__ short vs[DD * VS2];          // 17408 B  [d][j]
    __shared__ short ps[2][16 * PS2];       //  8704 B  per-wave P [row][j]
    int g = blockIdx.x;
    int c = g & 7, t = g >> 3;
    int bh = c + 8 * (t >> 3);
    int r0 = (t & 7) * 32;
    int tid = threadIdx.x;
    int wave = tid >> 6, lane = tid & 63;
    int ln = lane & 15, quad = lane >> 4;
    int m = r0 + wave * 16 + ln;
    const float* qrow = qL + ((size_t)bh * MM + m) * DD;
    bf16x8 a0, a1;
#pragma unroll
    for (int u = 0; u < 8; u++) {
        ((short*)&a0)[u] = f2bs(qrow[quad * 8 + u]);
        ((short*)&a1)[u] = f2bs(qrow[32 + quad * 8 + u]);
    }
    const uint4* kg = (const uint4*)(k + (size_t)bh * NN * DD);
    const uint4* vg = (const uint4*)(vT + (size_t)bh * DD * NN);
    float mrow[4], lrow[4];
    f32x4 o[4];
#pragma unroll
    for (int r = 0; r < 4; r++) { mrow[r] = -1e30f; lrow[r] = 0.f; }
#pragma unroll
    for (int ct = 0; ct < 4; ct++) o[ct] = (f32x4){0.f, 0.f, 0.f, 0.f};
    short* pw = &ps[wave][0];

    for (int j0 = 0; j0 < NN; j0 += NJ) {
        __syncthreads();
#pragma unroll
        for (int it = 0; it < 8; it++) {
            int idx = it * 128 + tid;
            int row = idx >> 3, c8 = idx & 7;
            uint4 pk = kg[(size_t)(j0 + row) * 8 + c8];
            *(uint4*)&ks[row * KS2 + c8 * 8] = pk;
        }
#pragma unroll
        for (int it = 0; it < 8; it++) {
            int idx = it * 128 + tid;
            int row = idx >> 4, c8 = idx & 15;
            uint4 pv = vg[(size_t)row * (NN / 8) + (j0 / 8) + c8];
            *(uint4*)&vs[row * VS2 + c8 * 8] = pv;
        }
        __syncthreads();
        f32x4 s[8];
#pragma unroll
        for (int ct = 0; ct < 8; ct++) {
            const short* kp = &ks[(ct * 16 + ln) * KS2 + quad * 8];
            bf16x8 b0 = *(const bf16x8*)kp;
            bf16x8 b1 = *(const bf16x8*)(kp + 32);
            f32x4 cc = {0.f, 0.f, 0.f, 0.f};
            cc = __builtin_amdgcn_mfma_f32_16x16x32_bf16(a0, b0, cc, 0, 0, 0);
            cc = __builtin_amdgcn_mfma_f32_16x16x32_bf16(a1, b1, cc, 0, 0, 0);
            s[ct] = cc;
        }
#pragma unroll
        for (int r = 0; r < 4; r++) {
            float v = -1e30f;
#pragma unroll
            for (int ct = 0; ct < 8; ct++) v = fmaxf(v, s[ct][r]);
            v = fmaxf(v, __shfl_xor(v, 1));
            v = fmaxf(v, __shfl_xor(v, 2));
            v = fmaxf(v, __shfl_xor(v, 4));
            v = fmaxf(v, __shfl_xor(v, 8));
            float mn = fmaxf(mrow[r], v);
            float alpha = __expf(mrow[r] - mn);
            mrow[r] = mn;
            float psum = 0.f;
#pragma unroll
            for (int ct = 0; ct < 8; ct++) { float e = __expf(s[ct][r] - mn); s[ct][r] = e; psum += e; }
            lrow[r] = lrow[r] * alpha + psum;
#pragma unroll
            for (int c2 = 0; c2 < 4; c2++) o[c2][r] *= alpha;
        }
#pragma unroll
        for (int ct = 0; ct < 8; ct++)
#pragma unroll
            for (int r = 0; r < 4; r++)
                pw[(quad * 4 + r) * PS2 + ct * 16 + ln] = f2bs(s[ct][r]);
#pragma unroll
        for (int kstep = 0; kstep < 4; kstep++) {
            bf16x8 pa = *(const bf16x8*)&pw[ln * PS2 + kstep * 32 + quad * 8];
#pragma unroll
            for (int ct = 0; ct < 4; ct++) {
                bf16x8 pb = *(const bf16x8*)&vs[(ct * 16 + ln) * VS2 + kstep * 32 + quad * 8];
                o[ct] = __builtin_amdgcn_mfma_f32_16x16x32_bf16(pa, pb, o[ct], 0, 0, 0);
            }
        }
    }
#pragma unroll
    for (int r = 0; r < 4; r++) {
        float l = lrow[r];
        l += __shfl_xor(l, 1);
        l += __shfl_xor(l, 2);
        l += __shfl_xor(l, 4);
        l += __shfl_xor(l, 8);
        lrow[r] = 1.0f / l;
    }
#pragma unroll
    for (int ct = 0; ct < 4; ct++)
#pragma unroll
        for (int r = 0; r < 4; r++) {
            int row = r0 + wave * 16 + quad * 4 + r;
            t1[((size_t)bh * MM + row) * DD + ct * 16 + ln] = o[ct][r] * lrow[r];
        }
}

// ---------------------------------------------------------------------------
// MFMA fused attn1 + depthwise conv residual:
// oh[b,i,h*64+d] = softmax(q_i kL^T) @ t2 + conv(v)
#define KLS 72
#define T2S 264
#define VLS 72
__global__ __launch_bounds__(256, 1) void attn1_mfma(
        const bf16* __restrict__ q, const short* __restrict__ kl16,
        const short* __restrict__ t2t, const bf16* __restrict__ v,
        const float* __restrict__ cw, bf16* __restrict__ oh) {
    __shared__ short kls[MM * KLS];
    __shared__ short t2s[DD * T2S];
    __shared__ short ps1[4][16 * T2S];
    __shared__ short vload[96 * VLS];       // v[n0-16 .. n0+80) x 64d
    int bh = blockIdx.y;
    int n0 = blockIdx.x * 64;
    int tid = threadIdx.x;
    int b_ = bh >> 3, h = bh & 7;
    const short* kLb = kl16 + (size_t)bh * MM * DD;
    for (int idx = tid; idx < MM * DD / 8; idx += 256) {   // 8 iters, 16B each
        int l = idx >> 3, d8 = (idx & 7) * 8;
        *(uint4*)&kls[l * KLS + d8] = *(const uint4*)&kLb[idx * 8];
    }
    const short* t2b = t2t + (size_t)bh * DD * MM;
    for (int idx = tid; idx < DD * MM / 8; idx += 256) {   // 8 iters, 16B each
        int c = idx >> 5, r = (idx & 31) * 8;
        *(uint4*)&t2s[c * T2S + r] = *(const uint4*)&t2b[idx * 8];
    }
    // stage conv v window: 96 rows x 8 uint4
    const bf16* vb = v + (size_t)bh * NN * DD;
    for (int idx = tid; idx < 96 * 8; idx += 256) {
        int row = idx >> 3, c8 = (idx & 7) * 8;
        int gn = n0 - 16 + row;
        uint4 pv;
        pv.x = pv.y = pv.z = pv.w = 0u;
        if (gn >= 0 && gn < NN) pv = *(const uint4*)(vb + (size_t)gn * DD + c8);
        *(uint4*)&vload[row * VLS + c8] = pv;
    }
    __syncthreads();
    int wave = tid >> 6, lane = tid & 63;
    int ln = lane & 15, quad = lane >> 4;
    int m = n0 + wave * 16 + ln;
    const bf16* qrow = q + ((size_t)bh * NN + m) * DD;
    bf16x8 a0 = *(const bf16x8*)(qrow + quad * 8);
    bf16x8 a1 = *(const bf16x8*)(qrow + 32 + quad * 8);
    f32x4 acc[16];
#pragma unroll
    for (int nt = 0; nt < 16; nt++) {
        const short* kp = &kls[(nt * 16 + ln) * KLS + quad * 8];
        bf16x8 b0 = *(const bf16x8*)kp;
        bf16x8 b1 = *(const bf16x8*)(kp + 32);
        f32x4 c = {0.f, 0.f, 0.f, 0.f};
        c = __builtin_amdgcn_mfma_f32_16x16x32_bf16(a0, b0, c, 0, 0, 0);
        c = __builtin_amdgcn_mfma_f32_16x16x32_bf16(a1, b1, c, 0, 0, 0);
        acc[nt] = c;
    }
    float inv[4];
#pragma unroll
    for (int r = 0; r < 4; r++) {
        float vx = -1e30f;
#pragma unroll
        for (int nt = 0; nt < 16; nt++) vx = fmaxf(vx, acc[nt][r]);
        vx = fmaxf(vx, __shfl_xor(vx, 1));
        vx = fmaxf(vx, __shfl_xor(vx, 2));
        vx = fmaxf(vx, __shfl_xor(vx, 4));
        vx = fmaxf(vx, __shfl_xor(vx, 8));
        float s = 0.f;
#pragma unroll
        for (int nt = 0; nt < 16; nt++) { float e = __expf(acc[nt][r] - vx); acc[nt][r] = e; s += e; }
        s += __shfl_xor(s, 1);
        s += __shfl_xor(s, 2);
        s += __shfl_xor(s, 4);
        s += __shfl_xor(s, 8);
        inv[r] = 1.0f / s;
    }
    short* pw = &ps1[wave][0];
#pragma unroll
    for (int nt = 0; nt < 16; nt++)
#pragma unroll
        for (int r = 0; r < 4; r++)
            pw[(quad * 4 + r) * T2S + nt * 16 + ln] = f2bs(acc[nt][r]);
    __syncthreads();
    f32x4 o[4];
#pragma unroll
    for (int nt = 0; nt < 4; nt++) o[nt] = (f32x4){0.f, 0.f, 0.f, 0.f};
#pragma unroll
    for (int ks = 0; ks < 8; ks++) {
        bf16x8 pa = *(const bf16x8*)&pw[ln * T2S + ks * 32 + quad * 8];
#pragma unroll
        for (int nt = 0; nt < 4; nt++) {
            bf16x8 pb = *(const bf16x8*)&t2s[(nt * 16 + ln) * T2S + ks * 32 + quad * 8];
            o[nt] = __builtin_amdgcn_mfma_f32_16x16x32_bf16(pa, pb, o[nt], 0, 0, 0);
        }
    }
    // epilogue: add conv residual from vload, write oh
    const float* wrow = cw + h * KER;
    int lbase = wave * 16 + quad * 4;    // output r=0's window start in vload
#pragma unroll
    for (int nt = 0; nt < 4; nt++) {
        int d = nt * 16 + ln;
        float win[36];
#pragma unroll
        for (int j = 0; j < 36; j++)
            win[j] = bsf(vload[(lbase + j) * VLS + d]);
        float res[4] = {0.f, 0.f, 0.f, 0.f};
#pragma unroll
        for (int t = 0; t < KER; t++) {
            float wt = wrow[t];
#pragma unroll
            for (int r = 0; r < 4; r++) res[r] += wt * win[r + t];
        }
#pragma unroll
        for (int r = 0; r < 4; r++) {
            int row = n0 + lbase + r;
            oh[((size_t)(b_ * NN + row)) * DIM + h * 64 + d] = f2b(o[nt][r] * inv[r] + res[r]);
        }
    }
}

// ---------------------------------------------------------------------------

extern "C" void kernel_launch(void* const* d_in, const int* in_sizes, int n_in,
                              void* d_out, int out_size, void* d_ws, size_t ws_size,
                              hipStream_t stream) {
    const float* x    = (const float*)d_in[0];
    const float* Wqkv = (const float*)d_in[1];
    const float* Wout = (const float*)d_in[2];
    const float* bout = (const float*)d_in[3];
    const float* cw   = (const float*)d_in[4];
    float* out = (float*)d_out;

    const size_t SZ_QKV = (size_t)BB * NH * NN * DD;   // 16,777,216 elems
    const size_t SZ_L   = (size_t)BB * NH * MM * DD;   // 524,288
    const size_t SZ_M2  = (size_t)BB * NH * MM * MM;   // 2,097,152

    // --- workspace plumbing (unchanged footprint) ---
    char* p = (char*)d_ws;
    bf16* q    = (bf16*)p;  p += SZ_QKV * 2;    // 32 MB
    bf16* v    = (bf16*)p;  p += SZ_QKV * 2;    // 32 MB
    float* x2   = (float*)p; p += SZ_M2 * 4;    // 8 MB each
    float* zf   = (float*)p; p += SZ_M2 * 4;    // final fp32 z lives here
    float* z2r  = (float*)p; p += SZ_M2 * 4;    // region reused for x2 pairs
    float* bAr  = (float*)p; p += SZ_M2 * 4;    // region reused for bufA pairs
    float* bBr  = (float*)p; p += SZ_M2 * 4;    // region for wqh/wql
    float* qL   = (float*)p; p += SZ_L * 4;     // 2 MB each
    float* kL   = (float*)p; p += SZ_L * 4;
    float* t1   = (float*)p; p += SZ_L * 4;
    short* t2t  = (short*)p; p += SZ_L * 4;
    float* scal = (float*)p; p += 2 * 4;
    size_t need = (size_t)(p - (char*)d_ws);
    bf16* k  = (bf16*)d_out;                     // first 32 MB of out buffer
    bf16* vT = (bf16*)d_out + SZ_QKV;            // second 32 MB of out buffer
    bf16* oh = (bf16*)x2;                        // 32 MB over dead pinv region

    // split-precision scratch for projections (aliased, dead at use time):
    short* xh  = (short*)x2;                     // 32 MB over x2..bAr
    short* xl  = (short*)vT;                     // vT half of d_out
    short* wqh = (short*)bBr;                    // 1.5 MB
    short* wql = (short*)bBr + (size_t)K3 * DIM;
    short* woh = (short*)q;                      // q dead after attn1_mfma
    short* wol = (short*)q + (size_t)DIM * DIM;
    short* kl16 = (short*)t1;                    // t1 dead after bgemm_t2t

    // pinv pair scratch (after attn3v, k/vT in d_out are dead):
    const size_t U = SZ_M2;                      // 4 MiB per bf16 array
    short* db = (short*)d_out;
    short* bufBTh = db + 0 * U;  short* bufBTl = db + 1 * U;
    short* z2BTh  = db + 2 * U;  short* z2BTl  = db + 3 * U;
    short* zPair[2][4] = {                       // {Ah, Al, BTh, BTl} x 2 buffers
        { db + 4 * U, db + 5 * U, db + 6 * U, db + 7 * U },
        { db + 8 * U, db + 9 * U, db + 10 * U, db + 11 * U } };
    short* x2Ah = (short*)z2r;   short* x2Al = (short*)z2r + U;
    short* bufAh = (short*)bAr;  short* bufAl = (short*)bAr + U;

    if (ws_size < need) {
        zero_out<<<out_size / 256, 256, 0, stream>>>(out);
        return;
    }

    // 1. split inputs, project qkv via MFMA
    split_x<<<(int)(SZ_QKV / (256 * 8)), 256, 0, stream>>>(x, xh, xl);
    split_wT<<<(K3 * DIM) / 256, 256, 0, stream>>>(Wqkv, wqh, wql, K3);
    gemm_qkv_mfma<<<3072, 256, 0, stream>>>(xh, xl, wqh, wql, q, k, v);
    // 2. vT = v^T (overwrites xl -- dead)
    transpose_v<<<(BB * NH * MM) / 4, 256, 0, stream>>>(v, vT);
    // 3. landmark means + attn2 softmax (x2 overwrites xh -- dead)
    landmark_means<<<(BB * NH * MM * DD) / 256, 256, 0, stream>>>(q, k, qL, kL);
    attn2_softmax<<<BB * NH * MM, 256, 0, stream>>>(qL, kL, x2);
    // 4. attn3v FIRST (frees k/vT = all of d_out for pinv scratch)
    attn3v_mfma<<<256, 128, 0, stream>>>(qL, k, vT, t1);
    // 5. pinv scalars + z0/x2 pairs (rowmax of softmax == 1 analytically)
    init_scal<<<1, 64, 0, stream>>>(scal);
    csum_max<<<BB * NH, 256, 0, stream>>>(x2, scal);
    z_init_split<<<(int)(SZ_M2 / (256 * 8)), 256, 0, stream>>>(
        x2, scal, x2Ah, x2Al,
        zPair[0][0], zPair[0][1], zPair[0][2], zPair[0][3]);
    // 6. Newton-Schulz pinv, split-precision MFMA (eye7 fused into GEMM1)
    int cur = 0;
    for (int it = 0; it < 6; it++) {
        int nxt = cur ^ 1;
        // bufA = x2 @ z  (A-pairs); bufB^T = (7I - bufA)^T  (BT-pairs)
        bgemm_pair<<<dim3(4, 4, BB * NH), 256, 0, stream>>>(
            x2Ah, x2Al, zPair[cur][2], zPair[cur][3],
            bufAh, bufAl, bufBTh, bufBTl, nullptr,
            1.f, 0.f, -1.f, 7.f, 1 | 2);
        // z2 = 15I - bufA @ bufB -> BT-pairs
        bgemm_pair<<<dim3(4, 4, BB * NH), 256, 0, stream>>>(
            bufAh, bufAl, bufBTh, bufBTl,
            nullptr, nullptr, z2BTh, z2BTl, nullptr,
            -1.f, 15.f, 1.f, 0.f, 2);
        // bufB2 = 13I - bufA @ z2 -> BT-pairs (overwrite bufBT)
        bgemm_pair<<<dim3(4, 4, BB * NH), 256, 0, stream>>>(
            bufAh, bufAl, z2BTh, z2BTl,
            nullptr, nullptr, bufBTh, bufBTl, nullptr,
            -1.f, 13.f, 1.f, 0.f, 2);
        // z_next = 0.25 z @ bufB2; last iteration needs only fp32 (zf)
        int fl = (it == 5) ? 4 : (1 | 2);
        bgemm_pair<<<dim3(4, 4, BB * NH), 256, 0, stream>>>(
            zPair[cur][0], zPair[cur][1], bufBTh, bufBTl,
            zPair[nxt][0], zPair[nxt][1], zPair[nxt][2], zPair[nxt][3],
            zf, 0.25f, 0.f, 1.f, 0.f, fl);
        cur = nxt;
    }
    // 7. t2t = (z @ t1)^T in bf16 [bh][64][256]
    bgemm_t2t<<<dim3(1, 4, BB * NH), 256, 0, stream>>>(zf, t1, t2t);
    // 7b. kL -> bf16 (over dead t1) for attn1 staging
    kl_to_bf16<<<(int)(SZ_L / (256 * 4)), 256, 0, stream>>>(kL, kl16);
    // 8. oh = softmax(q kL^T) @ t2 + conv(v)   (conv fused; q dead after)
    attn1_mfma<<<dim3(NN / 64, BB * NH), 256, 0, stream>>>(q, kl16, t2t, v, cw, oh);
    // 9. out = oh @ (WoutH + WoutL) + bout (overwrites d_out; scratch dead)
    split_wT<<<(DIM * DIM) / 256, 256, 0, stream>>>(Wout, woh, wol, DIM);
    gemm_out_mfma<<<1024, 256, 0, stream>>>(oh, woh, wol, bout, out);

    (void)in_sizes; (void)n_in; (void)ws_size;
}

// Round 10
// 1043.919 us; speedup vs baseline: 1.2623x; 1.0175x over previous
//
#include <hip/hip_runtime.h>
#include <hip/hip_bf16.h>
#include <math.h>

// Problem constants
#define BB 4
#define NH 8
#define NN 8192
#define DD 64
#define MM 256
#define LG 32
#define DIM 512
#define K3 1536
#define KER 33

typedef __hip_bfloat16 bf16;
typedef __attribute__((ext_vector_type(8))) short bf16x8;
typedef __attribute__((ext_vector_type(4))) float f32x4;

__device__ __forceinline__ float b2f(bf16 x) { return __bfloat162float(x); }
__device__ __forceinline__ bf16 f2b(float x) { return __float2bfloat16(x); }
__device__ __forceinline__ short f2bs(float x) { bf16 h = __float2bfloat16(x); return *reinterpret_cast<short*>(&h); }
__device__ __forceinline__ float bsf(short s) { return __uint_as_float(((unsigned int)(unsigned short)s) << 16); }
// bf16-pair unpack from a uint32 (lo short = first element)
__device__ __forceinline__ float blo(unsigned int u) { return __uint_as_float(u << 16); }
__device__ __forceinline__ float bhi(unsigned int u) { return __uint_as_float(u & 0xffff0000u); }

// async global->LDS, 16B per lane (dest must be linear: base + lane*16)
__device__ __forceinline__ void g2lds16(const void* g, void* l) {
    __builtin_amdgcn_global_load_lds(
        (const __attribute__((address_space(1))) unsigned int*)g,
        (__attribute__((address_space(3))) unsigned int*)l, 16, 0, 0);
}

// diagnostic fallback: zero the output
__global__ void zero_out(float* __restrict__ o) {
    o[(size_t)blockIdx.x * 256 + threadIdx.x] = 0.f;
}

// ---------------------------------------------------------------------------
// split fp32 -> bf16 hi + bf16 lo (residual), 8 elems/thread, 16B stores
__global__ void split_x(const float* __restrict__ x, short* __restrict__ xh,
                        short* __restrict__ xl) {
    size_t i = ((size_t)blockIdx.x * 256 + threadIdx.x) * 8;
    const float4* xp = (const float4*)(x + i);
    float4 v0 = xp[0], v1 = xp[1];
    float vv[8] = {v0.x, v0.y, v0.z, v0.w, v1.x, v1.y, v1.z, v1.w};
    short hb[8], lb[8];
#pragma unroll
    for (int u = 0; u < 8; u++) {
        bf16 h = f2b(vv[u]);
        hb[u] = *(short*)&h;
        lb[u] = f2bs(vv[u] - b2f(h));
    }
    *(uint4*)(xh + i) = *(uint4*)hb;
    *(uint4*)(xl + i) = *(uint4*)lb;
}

// split + transpose weight: W[k][n] fp32 -> wh/wl [n][K=512] bf16
__global__ void split_wT(const float* __restrict__ W, short* __restrict__ wh,
                         short* __restrict__ wl, int Nn) {
    int idx = blockIdx.x * 256 + threadIdx.x;   // n*512 + k
    int k = idx & 511, n = idx >> 9;
    float v = W[(size_t)k * Nn + n];
    bf16 h = f2b(v);
    wh[idx] = *(short*)&h;
    wl[idx] = f2bs(v - b2f(h));
}

// ---------------------------------------------------------------------------
// qkv projection via MFMA, split-precision (Xh@Wh + Xl@Wh + Xh@Wl).
__global__ __launch_bounds__(256) void gemm_qkv_mfma(
        const short* __restrict__ xh, const short* __restrict__ xl,
        const short* __restrict__ wh, const short* __restrict__ wl,
        bf16* __restrict__ q, bf16* __restrict__ k, bf16* __restrict__ v) {
    __shared__ short Ah[128 * 32];
    __shared__ short Al[128 * 32];
    __shared__ short Bh[128 * 32];
    __shared__ short Bl[128 * 32];
    int orig = blockIdx.x;
    int wg = (orig & 7) * 384 + (orig >> 3);
    int by = wg / 12, bx = wg - by * 12;
    int rowBase = by * 128, colBase = bx * 128;
    int tid = threadIdx.x;
    int rl = tid >> 2;
    int ch = (tid & 3) * 8;
    int wave = tid >> 6, lane = tid & 63;
    int ln = lane & 15, quad = lane >> 4;
    int wr = (wave >> 1) * 64, wc = (wave & 1) * 64;
    f32x4 acc[4][4];
#pragma unroll
    for (int mt = 0; mt < 4; mt++)
#pragma unroll
        for (int nt = 0; nt < 4; nt++) acc[mt][nt] = (f32x4){0.f, 0.f, 0.f, 0.f};

    for (int k0 = 0; k0 < DIM; k0 += 32) {
        __syncthreads();
#pragma unroll
        for (int p = 0; p < 2; p++) {
            int r = p * 64 + rl;
            size_t ga = (size_t)(rowBase + r) * DIM + k0 + ch;
            size_t gb = (size_t)(colBase + r) * DIM + k0 + ch;
            int lo = r * 32 + ch;
            g2lds16(xh + ga, &Ah[lo]);
            g2lds16(xl + ga, &Al[lo]);
            g2lds16(wh + gb, &Bh[lo]);
            g2lds16(wl + gb, &Bl[lo]);
        }
        __syncthreads();
        bf16x8 a_h[4], a_l[4], b_h[4], b_l[4];
#pragma unroll
        for (int mt = 0; mt < 4; mt++) {
            int o = (wr + mt * 16 + ln) * 32 + quad * 8;
            a_h[mt] = *(const bf16x8*)&Ah[o];
            a_l[mt] = *(const bf16x8*)&Al[o];
        }
#pragma unroll
        for (int nt = 0; nt < 4; nt++) {
            int o = (wc + nt * 16 + ln) * 32 + quad * 8;
            b_h[nt] = *(const bf16x8*)&Bh[o];
            b_l[nt] = *(const bf16x8*)&Bl[o];
        }
#pragma unroll
        for (int mt = 0; mt < 4; mt++)
#pragma unroll
            for (int nt = 0; nt < 4; nt++) {
                acc[mt][nt] = __builtin_amdgcn_mfma_f32_16x16x32_bf16(a_h[mt], b_h[nt], acc[mt][nt], 0, 0, 0);
                acc[mt][nt] = __builtin_amdgcn_mfma_f32_16x16x32_bf16(a_l[mt], b_h[nt], acc[mt][nt], 0, 0, 0);
                acc[mt][nt] = __builtin_amdgcn_mfma_f32_16x16x32_bf16(a_h[mt], b_l[nt], acc[mt][nt], 0, 0, 0);
            }
    }
    int part = colBase >> 9;
    bf16* dst = part == 0 ? q : (part == 1 ? k : v);
    float scale = part == 0 ? 0.125f : 1.0f;
#pragma unroll
    for (int mt = 0; mt < 4; mt++)
#pragma unroll
        for (int nt = 0; nt < 4; nt++)
#pragma unroll
            for (int r = 0; r < 4; r++) {
                int row = rowBase + wr + mt * 16 + quad * 4 + r;
                int col = colBase + wc + nt * 16 + ln;
                int h = (col & 511) >> 6, d = col & 63;
                int b_ = row >> 13, n_ = row & 8191;
                size_t di = ((size_t)(b_ * NH + h) * NN + n_) * DD + d;
                dst[di] = f2b(acc[mt][nt][r] * scale);
            }
}

// out projection via MFMA: oh(bf16) @ (Wh+Wl) + bias -> fp32
__global__ __launch_bounds__(256) void gemm_out_mfma(
        const bf16* __restrict__ A, const short* __restrict__ wh,
        const short* __restrict__ wl, const float* __restrict__ bias,
        float* __restrict__ C) {
    __shared__ short As[128 * 32];
    __shared__ short Bh[128 * 32];
    __shared__ short Bl[128 * 32];
    int orig = blockIdx.x;                       // nwg = 1024
    int wg = (orig & 7) * 128 + (orig >> 3);
    int by = wg >> 2, bx = wg & 3;
    int rowBase = by * 128, colBase = bx * 128;
    int tid = threadIdx.x;
    int rl = tid >> 2, ch = (tid & 3) * 8;
    int wave = tid >> 6, lane = tid & 63;
    int ln = lane & 15, quad = lane >> 4;
    int wr = (wave >> 1) * 64, wc = (wave & 1) * 64;
    const short* Ab = (const short*)A;
    f32x4 acc[4][4];
#pragma unroll
    for (int mt = 0; mt < 4; mt++)
#pragma unroll
        for (int nt = 0; nt < 4; nt++) acc[mt][nt] = (f32x4){0.f, 0.f, 0.f, 0.f};

    for (int k0 = 0; k0 < DIM; k0 += 32) {
        __syncthreads();
#pragma unroll
        for (int p = 0; p < 2; p++) {
            int r = p * 64 + rl;
            size_t ga = (size_t)(rowBase + r) * DIM + k0 + ch;
            size_t gb = (size_t)(colBase + r) * DIM + k0 + ch;
            int lo = r * 32 + ch;
            g2lds16(Ab + ga, &As[lo]);
            g2lds16(wh + gb, &Bh[lo]);
            g2lds16(wl + gb, &Bl[lo]);
        }
        __syncthreads();
        bf16x8 a[4], b_h[4], b_l[4];
#pragma unroll
        for (int mt = 0; mt < 4; mt++)
            a[mt] = *(const bf16x8*)&As[(wr + mt * 16 + ln) * 32 + quad * 8];
#pragma unroll
        for (int nt = 0; nt < 4; nt++) {
            int o = (wc + nt * 16 + ln) * 32 + quad * 8;
            b_h[nt] = *(const bf16x8*)&Bh[o];
            b_l[nt] = *(const bf16x8*)&Bl[o];
        }
#pragma unroll
        for (int mt = 0; mt < 4; mt++)
#pragma unroll
            for (int nt = 0; nt < 4; nt++) {
                acc[mt][nt] = __builtin_amdgcn_mfma_f32_16x16x32_bf16(a[mt], b_h[nt], acc[mt][nt], 0, 0, 0);
                acc[mt][nt] = __builtin_amdgcn_mfma_f32_16x16x32_bf16(a[mt], b_l[nt], acc[mt][nt], 0, 0, 0);
            }
    }
#pragma unroll
    for (int mt = 0; mt < 4; mt++)
#pragma unroll
        for (int nt = 0; nt < 4; nt++)
#pragma unroll
            for (int r = 0; r < 4; r++) {
                int row = rowBase + wr + mt * 16 + quad * 4 + r;
                int col = colBase + wc + nt * 16 + ln;
                C[(size_t)row * DIM + col] = acc[mt][nt][r] + bias[col];
            }
}

// ---------------------------------------------------------------------------
// Batched split-precision MFMA GEMM for the pinv chain.
// val = scale*(A@B) + alpha*I.  A-layout/fp32 outputs get val;
// B^T-layout output gets scaleB*val + alphaB*I (lets eye7 fuse into GEMM1).
// 64x64 tile, 4 waves, grid dim3(4,4,32) = 512 blocks (2 blocks/CU).
__global__ __launch_bounds__(256) void bgemm_pair(
        const short* __restrict__ Ah, const short* __restrict__ Al,
        const short* __restrict__ Bh, const short* __restrict__ Bl,
        short* __restrict__ oAh, short* __restrict__ oAl,
        short* __restrict__ oBh, short* __restrict__ oBl,
        float* __restrict__ oF, float scale, float alpha,
        float scaleB, float alphaB, int flags) {
    __shared__ short sAh[64 * 32];
    __shared__ short sAl[64 * 32];
    __shared__ short sBh[64 * 32];
    __shared__ short sBl[64 * 32];
    int bat = blockIdx.z;
    int rowBase = blockIdx.y * 64;    // 0..192
    int colBase = blockIdx.x * 64;    // 0..192
    const size_t MB = (size_t)bat * (MM * MM);
    int tid = threadIdx.x;
    int rl = tid >> 2, ch = (tid & 3) * 8;   // rl 0..63
    int wave = tid >> 6, lane = tid & 63;
    int ln = lane & 15, quad = lane >> 4;
    int wr = (wave >> 1) * 32, wc = (wave & 1) * 32;
    f32x4 acc[2][2];
#pragma unroll
    for (int mt = 0; mt < 2; mt++)
#pragma unroll
        for (int nt = 0; nt < 2; nt++) acc[mt][nt] = (f32x4){0.f, 0.f, 0.f, 0.f};

    for (int k0 = 0; k0 < MM; k0 += 32) {
        __syncthreads();
        {
            size_t ga = MB + (size_t)(rowBase + rl) * MM + k0 + ch;
            size_t gb = MB + (size_t)(colBase + rl) * MM + k0 + ch;
            int lo = rl * 32 + ch;
            g2lds16(Ah + ga, &sAh[lo]);
            g2lds16(Al + ga, &sAl[lo]);
            g2lds16(Bh + gb, &sBh[lo]);
            g2lds16(Bl + gb, &sBl[lo]);
        }
        __syncthreads();
        bf16x8 a_h[2], a_l[2], b_h[2], b_l[2];
#pragma unroll
        for (int mt = 0; mt < 2; mt++) {
            int o = (wr + mt * 16 + ln) * 32 + quad * 8;
            a_h[mt] = *(const bf16x8*)&sAh[o];
            a_l[mt] = *(const bf16x8*)&sAl[o];
        }
#pragma unroll
        for (int nt = 0; nt < 2; nt++) {
            int o = (wc + nt * 16 + ln) * 32 + quad * 8;
            b_h[nt] = *(const bf16x8*)&sBh[o];
            b_l[nt] = *(const bf16x8*)&sBl[o];
        }
#pragma unroll
        for (int mt = 0; mt < 2; mt++)
#pragma unroll
            for (int nt = 0; nt < 2; nt++) {
                acc[mt][nt] = __builtin_amdgcn_mfma_f32_16x16x32_bf16(a_h[mt], b_h[nt], acc[mt][nt], 0, 0, 0);
                acc[mt][nt] = __builtin_amdgcn_mfma_f32_16x16x32_bf16(a_l[mt], b_h[nt], acc[mt][nt], 0, 0, 0);
                acc[mt][nt] = __builtin_amdgcn_mfma_f32_16x16x32_bf16(a_h[mt], b_l[nt], acc[mt][nt], 0, 0, 0);
            }
    }
#pragma unroll
    for (int mt = 0; mt < 2; mt++)
#pragma unroll
        for (int nt = 0; nt < 2; nt++) {
            short bh4[4], bl4[4];
            int col = colBase + wc + nt * 16 + ln;
            int row0 = rowBase + wr + mt * 16 + quad * 4;
#pragma unroll
            for (int r = 0; r < 4; r++) {
                int row = row0 + r;
                float val = scale * acc[mt][nt][r];
                if (row == col) val += alpha;
                if (flags & 4) oF[MB + (size_t)row * MM + col] = val;
                if (flags & 1) {
                    short vh = f2bs(val);
                    oAh[MB + (size_t)row * MM + col] = vh;
                    oAl[MB + (size_t)row * MM + col] = f2bs(val - bsf(vh));
                }
                float bv = scaleB * val;
                if (row == col) bv += alphaB;
                short bvh = f2bs(bv);
                bh4[r] = bvh; bl4[r] = f2bs(bv - bsf(bvh));
            }
            if (flags & 2) {
                size_t o = MB + (size_t)col * MM + row0;
                *(uint2*)&oBh[o] = *(uint2*)bh4;
                *(uint2*)&oBl[o] = *(uint2*)bl4;
            }
        }
}

// z0 = x2^T / (colmax + 1e-12) -> zA pairs + zBT pairs; also x2 -> A pairs.
// (rowmax of a softmax = 1 analytically, so scal[0] holds only colmax.)
__global__ void z_init_split(const float* __restrict__ x2, const float* __restrict__ scal,
                             short* __restrict__ x2Ah, short* __restrict__ x2Al,
                             short* __restrict__ zAh, short* __restrict__ zAl,
                             short* __restrict__ zBh, short* __restrict__ zBl) {
    size_t base = ((size_t)blockIdx.x * 256 + threadIdx.x) * 8;
    float inv = 1.0f / (scal[0] + 1e-12f);
    int c0 = (int)(base & 255);
    int r = (int)((base >> 8) & 255);
    size_t MB = (base >> 16) << 16;
    const float4* xp = (const float4*)(x2 + base);
    float4 v0 = xp[0], v1 = xp[1];
    float vv[8] = {v0.x, v0.y, v0.z, v0.w, v1.x, v1.y, v1.z, v1.w};
    short ho[8], lo_[8], h2[8], l2[8];
#pragma unroll
    for (int u = 0; u < 8; u++) {
        short xh = f2bs(vv[u]);
        h2[u] = xh; l2[u] = f2bs(vv[u] - bsf(xh));
        float zv = vv[u] * inv;
        short zh = f2bs(zv);
        ho[u] = zh; lo_[u] = f2bs(zv - bsf(zh));
    }
    *(uint4*)&x2Ah[base] = *(uint4*)h2;
    *(uint4*)&x2Al[base] = *(uint4*)l2;
    *(uint4*)&zBh[base] = *(uint4*)ho;
    *(uint4*)&zBl[base] = *(uint4*)lo_;
    // A layout: zA[bat][r][c] = z[r][c] = x2[bat][c][r]*inv  (strided read)
#pragma unroll
    for (int u = 0; u < 8; u++) {
        float v = x2[MB + (size_t)(c0 + u) * MM + r] * inv;
        short vh = f2bs(v);
        ho[u] = vh; lo_[u] = f2bs(v - bsf(vh));
    }
    *(uint4*)&zAh[base] = *(uint4*)ho;
    *(uint4*)&zAl[base] = *(uint4*)lo_;
}

// t2t = (z @ t1)^T per batch, stored bf16 [bh][d=64][landmark=256]
__global__ void bgemm_t2t(const float* __restrict__ A, const float* __restrict__ B,
                          short* __restrict__ T) {
    __shared__ float As[16][64];
    __shared__ float Bs[16][64];
    int bat = blockIdx.z;
    const float* Ab = A + (size_t)bat * MM * MM;   // z [256,256]
    const float* Bb = B + (size_t)bat * MM * DD;   // t1 [256,64]
    short* Tb = T + (size_t)bat * DD * MM;
    int tid = threadIdx.x;
    int rowBase = blockIdx.y * 64;
    int ty = tid >> 4, tx = tid & 15;
    float acc[4][4] = {};
    for (int k0 = 0; k0 < MM; k0 += 16) {
        for (int idx = tid; idx < 64 * 16; idx += 256) {
            int r = idx >> 4, c = idx & 15;
            As[c][r] = Ab[(size_t)(rowBase + r) * MM + k0 + c];
        }
        for (int idx = tid; idx < 16 * 64; idx += 256) {
            int r = idx >> 6, c = idx & 63;
            Bs[r][c] = Bb[(size_t)(k0 + r) * DD + c];
        }
        __syncthreads();
#pragma unroll
        for (int kk = 0; kk < 16; kk++) {
            float a[4], b[4];
#pragma unroll
            for (int i = 0; i < 4; i++) a[i] = As[kk][ty * 4 + i];
#pragma unroll
            for (int j = 0; j < 4; j++) b[j] = Bs[kk][tx * 4 + j];
#pragma unroll
            for (int i = 0; i < 4; i++)
#pragma unroll
                for (int j = 0; j < 4; j++) acc[i][j] += a[i] * b[j];
        }
        __syncthreads();
    }
#pragma unroll
    for (int i = 0; i < 4; i++) {
        int r = rowBase + ty * 4 + i;     // landmark
#pragma unroll
        for (int j = 0; j < 4; j++) {
            int c = tx * 4 + j;           // d
            Tb[(size_t)c * MM + r] = f2bs(acc[i][j]);
        }
    }
}

// ---------------------------------------------------------------------------
// landmark means: qL/kL[bh,mi,d] = mean over 32 tokens (bf16 in, fp32 out)
__global__ void landmark_means(const bf16* __restrict__ q, const bf16* __restrict__ k,
                               float* __restrict__ qL, float* __restrict__ kL) {
    int idx = blockIdx.x * 256 + threadIdx.x;   // (bh*256 + mi)*64 + d
    int d = idx & 63;
    int mi = (idx >> 6) & 255;
    int bh = idx >> 14;
    const bf16* qp = q + ((size_t)bh * NN + mi * LG) * DD + d;
    const bf16* kp = k + ((size_t)bh * NN + mi * LG) * DD + d;
    float sq = 0.f, sk = 0.f;
#pragma unroll
    for (int j = 0; j < LG; j++) { sq += b2f(qp[(size_t)j * DD]); sk += b2f(kp[(size_t)j * DD]); }
    qL[idx] = sq * (1.f / LG);
    kL[idx] = sk * (1.f / LG);
}

// kL fp32 -> bf16 copy (for attn1 B-fragments)
__global__ void kl_to_bf16(const float* __restrict__ kL, short* __restrict__ kl16) {
    size_t i = ((size_t)blockIdx.x * 256 + threadIdx.x) * 4;
    float4 v = *(const float4*)(kL + i);
    short o[4] = {f2bs(v.x), f2bs(v.y), f2bs(v.z), f2bs(v.w)};
    *(uint2*)&kl16[i] = *(uint2*)o;
}

// attn2 = softmax(qL @ kL^T), one block per row (all fp32)
__global__ void attn2_softmax(const float* __restrict__ qL, const float* __restrict__ kL,
                              float* __restrict__ x2) {
    __shared__ float qs[64];
    __shared__ float red[256];
    int bh = blockIdx.x >> 8, i = blockIdx.x & 255;
    int t = threadIdx.x;
    if (t < 64) qs[t] = qL[((size_t)bh * MM + i) * DD + t];
    __syncthreads();
    const float4* kp = (const float4*)(kL + ((size_t)bh * MM + t) * DD);
    float l = 0.f;
#pragma unroll
    for (int u = 0; u < 16; u++) {
        float4 kv = kp[u];
        l += qs[u*4+0]*kv.x + qs[u*4+1]*kv.y + qs[u*4+2]*kv.z + qs[u*4+3]*kv.w;
    }
    red[t] = l; __syncthreads();
    for (int s = 128; s > 0; s >>= 1) { if (t < s) red[t] = fmaxf(red[t], red[t + s]); __syncthreads(); }
    float mx = red[0]; __syncthreads();
    float e = __expf(l - mx);
    red[t] = e; __syncthreads();
    for (int s = 128; s > 0; s >>= 1) { if (t < s) red[t] += red[t + s]; __syncthreads(); }
    x2[((size_t)bh * MM + i) * MM + t] = e / red[0];
}

__global__ void init_scal(float* scal) {
    if (threadIdx.x == 0) { scal[0] = 0.f; scal[1] = 0.f; }
}

// max over (bh,j) of sum_i |x|  -> scal[0]   (rowmax of softmax == 1)
__global__ void csum_max(const float* __restrict__ x2, float* scal) {
    __shared__ float red[256];
    int t = threadIdx.x;
    const float* xp = x2 + (size_t)blockIdx.x * MM * MM;
    float s = 0.f;
    for (int i = 0; i < MM; i++) s += fabsf(xp[(size_t)i * MM + t]);
    red[t] = s; __syncthreads();
    for (int st = 128; st > 0; st >>= 1) { if (t < st) red[t] = fmaxf(red[t], red[t + st]); __syncthreads(); }
    if (t == 0) atomicMax((unsigned int*)&scal[0], __float_as_uint(red[0]));
}

// ---------------------------------------------------------------------------
// v transpose: vT[bh][d][n] <- v[bh][n][d].
__global__ void transpose_v(const bf16* __restrict__ v, bf16* __restrict__ vT) {
    int gw = blockIdx.x * 4 + (threadIdx.x >> 6);   // global wave id
    int lane = threadIdx.x & 63;                     // = d
    int bh = gw >> 8;
    int c  = gw & 255;                               // n-chunk (32 tokens)
    const bf16* vb = v + ((size_t)bh * NN + c * 32) * DD + lane;
    unsigned short buf[32];
#pragma unroll
    for (int i = 0; i < 32; i++) buf[i] = *(const unsigned short*)(vb + (size_t)i * DD);
    bf16* dst = vT + ((size_t)bh * DD + lane) * NN + c * 32;
#pragma unroll
    for (int u = 0; u < 4; u++)
        *(uint4*)(dst + u * 8) = *(uint4*)&buf[u * 8];
}

// ---------------------------------------------------------------------------
// MFMA flash attn3v: t1 = softmax(qL @ k^T over n) @ v
// 2 waves / 32 landmark rows per block; grid 256 blocks (8 rb x 32 bh),
// XCD-pinned: all 8 row-blocks of one bh map to the same XCD (g%8).
#define NJ 128
#define KS2 72
#define VS2 136
#define PS2 136
__global__ __launch_bounds__(128, 2) void attn3v_mfma(
        const float* __restrict__ qL, const bf16* __restrict__ k,
        const bf16* __restrict__ vT, float* __restrict__ t1) {
    __shared__ short ks[NJ * KS2];          // 18432 B  [j][d]
    __shared__ short vs[DD * VS2];          // 17408 B  [d][j]
    __shared__ short ps[2][16 * PS2];       //  8704 B  per-wave P [row][j]
    int g = blockIdx.x;
    int c = g & 7, t = g >> 3;
    int bh = c + 8 * (t >> 3);
    int r0 = (t & 7) * 32;
    int tid = threadIdx.x;
    int wave = tid >> 6, lane = tid & 63;
    int ln = lane & 15, quad = lane >> 4;
    int m = r0 + wave * 16 + ln;
    const float* qrow = qL + ((size_t)bh * MM + m) * DD;
    bf16x8 a0, a1;
#pragma unroll
    for (int u = 0; u < 8; u++) {
        ((short*)&a0)[u] = f2bs(qrow[quad * 8 + u]);
        ((short*)&a1)[u] = f2bs(qrow[32 + quad * 8 + u]);
    }
    const uint4* kg = (const uint4*)(k + (size_t)bh * NN * DD);
    const uint4* vg = (const uint4*)(vT + (size_t)bh * DD * NN);
    float mrow[4], lrow[4];
    f32x4 o[4];
#pragma unroll
    for (int r = 0; r < 4; r++) { mrow[r] = -1e30f; lrow[r] = 0.f; }
#pragma unroll
    for (int ct = 0; ct < 4; ct++) o[ct] = (f32x4){0.f, 0.f, 0.f, 0.f};
    short* pw = &ps[wave][0];

    for (int j0 = 0; j0 < NN; j0 += NJ) {
        __syncthreads();
#pragma unroll
        for (int it = 0; it < 8; it++) {
            int idx = it * 128 + tid;
            int row = idx >> 3, c8 = idx & 7;
            uint4 pk = kg[(size_t)(j0 + row) * 8 + c8];
            *(uint4*)&ks[row * KS2 + c8 * 8] = pk;
        }
#pragma unroll
        for (int it = 0; it < 8; it++) {
            int idx = it * 128 + tid;
            int row = idx >> 4, c8 = idx & 15;
            uint4 pv = vg[(size_t)row * (NN / 8) + (j0 / 8) + c8];
            *(uint4*)&vs[row * VS2 + c8 * 8] = pv;
        }
        __syncthreads();
        f32x4 s[8];
#pragma unroll
        for (int ct = 0; ct < 8; ct++) {
            const short* kp = &ks[(ct * 16 + ln) * KS2 + quad * 8];
            bf16x8 b0 = *(const bf16x8*)kp;
            bf16x8 b1 = *(const bf16x8*)(kp + 32);
            f32x4 cc = {0.f, 0.f, 0.f, 0.f};
            cc = __builtin_amdgcn_mfma_f32_16x16x32_bf16(a0, b0, cc, 0, 0, 0);
            cc = __builtin_amdgcn_mfma_f32_16x16x32_bf16(a1, b1, cc, 0, 0, 0);
            s[ct] = cc;
        }
#pragma unroll
        for (int r = 0; r < 4; r++) {
            float v = -1e30f;
#pragma unroll
            for (int ct = 0; ct < 8; ct++) v = fmaxf(v, s[ct][r]);
            v = fmaxf(v, __shfl_xor(v, 1));
            v = fmaxf(v, __shfl_xor(v, 2));
            v = fmaxf(v, __shfl_xor(v, 4));
            v = fmaxf(v, __shfl_xor(v, 8));
            float mn = fmaxf(mrow[r], v);
            float alpha = __expf(mrow[r] - mn);
            mrow[r] = mn;
            float psum = 0.f;
#pragma unroll
            for (int ct = 0; ct < 8; ct++) { float e = __expf(s[ct][r] - mn); s[ct][r] = e; psum += e; }
            lrow[r] = lrow[r] * alpha + psum;
#pragma unroll
            for (int c2 = 0; c2 < 4; c2++) o[c2][r] *= alpha;
        }
#pragma unroll
        for (int ct = 0; ct < 8; ct++)
#pragma unroll
            for (int r = 0; r < 4; r++)
                pw[(quad * 4 + r) * PS2 + ct * 16 + ln] = f2bs(s[ct][r]);
#pragma unroll
        for (int kstep = 0; kstep < 4; kstep++) {
            bf16x8 pa = *(const bf16x8*)&pw[ln * PS2 + kstep * 32 + quad * 8];
#pragma unroll
            for (int ct = 0; ct < 4; ct++) {
                bf16x8 pb = *(const bf16x8*)&vs[(ct * 16 + ln) * VS2 + kstep * 32 + quad * 8];
                o[ct] = __builtin_amdgcn_mfma_f32_16x16x32_bf16(pa, pb, o[ct], 0, 0, 0);
            }
        }
    }
#pragma unroll
    for (int r = 0; r < 4; r++) {
        float l = lrow[r];
        l += __shfl_xor(l, 1);
        l += __shfl_xor(l, 2);
        l += __shfl_xor(l, 4);
        l += __shfl_xor(l, 8);
        lrow[r] = 1.0f / l;
    }
#pragma unroll
    for (int ct = 0; ct < 4; ct++)
#pragma unroll
        for (int r = 0; r < 4; r++) {
            int row = r0 + wave * 16 + quad * 4 + r;
            t1[((size_t)bh * MM + row) * DD + ct * 16 + ln] = o[ct][r] * lrow[r];
        }
}

// ---------------------------------------------------------------------------
// MFMA fused attn1 + depthwise conv residual:
// oh[b,i,h*64+d] = softmax(q_i kL^T) @ t2 + conv(v)
// kl16 (16 KB/bh) and t2t (32 KB/bh) are L2-resident & shared by the 128
// blocks of a bh -> read MFMA B-fragments directly from global (no LDS
// staging). LDS = ps1 + vload = 47.6 KB -> 3 blocks/CU (was 1).
#define T2S 264
#define VLS 72
__global__ __launch_bounds__(256, 3) void attn1_mfma(
        const bf16* __restrict__ q, const short* __restrict__ kl16,
        const short* __restrict__ t2t, const bf16* __restrict__ v,
        const float* __restrict__ cw, bf16* __restrict__ oh) {
    __shared__ short ps1[4][16 * T2S];      // 33792 B
    __shared__ short vload[96 * VLS];       // 13824 B  v[n0-16 .. n0+80) x 64d
    int bh = blockIdx.y;
    int n0 = blockIdx.x * 64;
    int tid = threadIdx.x;
    int b_ = bh >> 3, h = bh & 7;
    // stage conv v window: 96 rows x 8 uint4
    const bf16* vb = v + (size_t)bh * NN * DD;
    for (int idx = tid; idx < 96 * 8; idx += 256) {
        int row = idx >> 3, c8 = (idx & 7) * 8;
        int gn = n0 - 16 + row;
        uint4 pv;
        pv.x = pv.y = pv.z = pv.w = 0u;
        if (gn >= 0 && gn < NN) pv = *(const uint4*)(vb + (size_t)gn * DD + c8);
        *(uint4*)&vload[row * VLS + c8] = pv;
    }
    int wave = tid >> 6, lane = tid & 63;
    int ln = lane & 15, quad = lane >> 4;
    int m = n0 + wave * 16 + ln;
    const bf16* qrow = q + ((size_t)bh * NN + m) * DD;
    bf16x8 a0 = *(const bf16x8*)(qrow + quad * 8);
    bf16x8 a1 = *(const bf16x8*)(qrow + 32 + quad * 8);
    // QK^T: B-fragments straight from kl16 (L2-hot, coalesced 2KB/wave-tile)
    const short* klb = kl16 + (size_t)bh * MM * DD;
    f32x4 acc[16];
#pragma unroll
    for (int nt = 0; nt < 16; nt++) {
        const short* kp = klb + (nt * 16 + ln) * DD + quad * 8;
        bf16x8 b0 = *(const bf16x8*)kp;
        bf16x8 b1 = *(const bf16x8*)(kp + 32);
        f32x4 c = {0.f, 0.f, 0.f, 0.f};
        c = __builtin_amdgcn_mfma_f32_16x16x32_bf16(a0, b0, c, 0, 0, 0);
        c = __builtin_amdgcn_mfma_f32_16x16x32_bf16(a1, b1, c, 0, 0, 0);
        acc[nt] = c;
    }
    float inv[4];
#pragma unroll
    for (int r = 0; r < 4; r++) {
        float vx = -1e30f;
#pragma unroll
        for (int nt = 0; nt < 16; nt++) vx = fmaxf(vx, acc[nt][r]);
        vx = fmaxf(vx, __shfl_xor(vx, 1));
        vx = fmaxf(vx, __shfl_xor(vx, 2));
        vx = fmaxf(vx, __shfl_xor(vx, 4));
        vx = fmaxf(vx, __shfl_xor(vx, 8));
        float s = 0.f;
#pragma unroll
        for (int nt = 0; nt < 16; nt++) { float e = __expf(acc[nt][r] - vx); acc[nt][r] = e; s += e; }
        s += __shfl_xor(s, 1);
        s += __shfl_xor(s, 2);
        s += __shfl_xor(s, 4);
        s += __shfl_xor(s, 8);
        inv[r] = 1.0f / s;
    }
    short* pw = &ps1[wave][0];
#pragma unroll
    for (int nt = 0; nt < 16; nt++)
#pragma unroll
        for (int r = 0; r < 4; r++)
            pw[(quad * 4 + r) * T2S + nt * 16 + ln] = f2bs(acc[nt][r]);
    __syncthreads();
    // PV: B-fragments straight from t2t [bh][d][landmark] (L2-hot)
    const short* t2b = t2t + (size_t)bh * DD * MM;
    f32x4 o[4];
#pragma unroll
    for (int nt = 0; nt < 4; nt++) o[nt] = (f32x4){0.f, 0.f, 0.f, 0.f};
#pragma unroll
    for (int ks = 0; ks < 8; ks++) {
        bf16x8 pa = *(const bf16x8*)&pw[ln * T2S + ks * 32 + quad * 8];
#pragma unroll
        for (int nt = 0; nt < 4; nt++) {
            bf16x8 pb = *(const bf16x8*)(t2b + (nt * 16 + ln) * MM + ks * 32 + quad * 8);
            o[nt] = __builtin_amdgcn_mfma_f32_16x16x32_bf16(pa, pb, o[nt], 0, 0, 0);
        }
    }
    // epilogue: add conv residual from vload, write oh
    const float* wrow = cw + h * KER;
    int lbase = wave * 16 + quad * 4;    // output r=0's window start in vload
#pragma unroll
    for (int nt = 0; nt < 4; nt++) {
        int d = nt * 16 + ln;
        float win[36];
#pragma unroll
        for (int j = 0; j < 36; j++)
            win[j] = bsf(vload[(lbase + j) * VLS + d]);
        float res[4] = {0.f, 0.f, 0.f, 0.f};
#pragma unroll
        for (int t = 0; t < KER; t++) {
            float wt = wrow[t];
#pragma unroll
            for (int r = 0; r < 4; r++) res[r] += wt * win[r + t];
        }
#pragma unroll
        for (int r = 0; r < 4; r++) {
            int row = n0 + lbase + r;
            oh[((size_t)(b_ * NN + row)) * DIM + h * 64 + d] = f2b(o[nt][r] * inv[r] + res[r]);
        }
    }
}

// ---------------------------------------------------------------------------

extern "C" void kernel_launch(void* const* d_in, const int* in_sizes, int n_in,
                              void* d_out, int out_size, void* d_ws, size_t ws_size,
                              hipStream_t stream) {
    const float* x    = (const float*)d_in[0];
    const float* Wqkv = (const float*)d_in[1];
    const float* Wout = (const float*)d_in[2];
    const float* bout = (const float*)d_in[3];
    const float* cw   = (const float*)d_in[4];
    float* out = (float*)d_out;

    const size_t SZ_QKV = (size_t)BB * NH * NN * DD;   // 16,777,216 elems
    const size_t SZ_L   = (size_t)BB * NH * MM * DD;   // 524,288
    const size_t SZ_M2  = (size_t)BB * NH * MM * MM;   // 2,097,152

    // --- workspace plumbing (unchanged footprint) ---
    char* p = (char*)d_ws;
    bf16* q    = (bf16*)p;  p += SZ_QKV * 2;    // 32 MB
    bf16* v    = (bf16*)p;  p += SZ_QKV * 2;    // 32 MB
    float* x2   = (float*)p; p += SZ_M2 * 4;    // 8 MB each
    float* zf   = (float*)p; p += SZ_M2 * 4;    // final fp32 z lives here
    float* z2r  = (float*)p; p += SZ_M2 * 4;    // region reused for x2 pairs
    float* bAr  = (float*)p; p += SZ_M2 * 4;    // region reused for bufA pairs
    float* bBr  = (float*)p; p += SZ_M2 * 4;    // region for wqh/wql
    float* qL   = (float*)p; p += SZ_L * 4;     // 2 MB each
    float* kL   = (float*)p; p += SZ_L * 4;
    float* t1   = (float*)p; p += SZ_L * 4;
    short* t2t  = (short*)p; p += SZ_L * 4;
    float* scal = (float*)p; p += 2 * 4;
    size_t need = (size_t)(p - (char*)d_ws);
    bf16* k  = (bf16*)d_out;                     // first 32 MB of out buffer
    bf16* vT = (bf16*)d_out + SZ_QKV;            // second 32 MB of out buffer
    bf16* oh = (bf16*)x2;                        // 32 MB over dead pinv region

    // split-precision scratch for projections (aliased, dead at use time):
    short* xh  = (short*)x2;                     // 32 MB over x2..bAr
    short* xl  = (short*)vT;                     // vT half of d_out
    short* wqh = (short*)bBr;                    // 1.5 MB
    short* wql = (short*)bBr + (size_t)K3 * DIM;
    short* woh = (short*)q;                      // q dead after attn1_mfma
    short* wol = (short*)q + (size_t)DIM * DIM;
    short* kl16 = (short*)t1;                    // t1 dead after bgemm_t2t

    // pinv pair scratch (after attn3v, k/vT in d_out are dead):
    const size_t U = SZ_M2;                      // 4 MiB per bf16 array
    short* db = (short*)d_out;
    short* bufBTh = db + 0 * U;  short* bufBTl = db + 1 * U;
    short* z2BTh  = db + 2 * U;  short* z2BTl  = db + 3 * U;
    short* zPair[2][4] = {                       // {Ah, Al, BTh, BTl} x 2 buffers
        { db + 4 * U, db + 5 * U, db + 6 * U, db + 7 * U },
        { db + 8 * U, db + 9 * U, db + 10 * U, db + 11 * U } };
    short* x2Ah = (short*)z2r;   short* x2Al = (short*)z2r + U;
    short* bufAh = (short*)bAr;  short* bufAl = (short*)bAr + U;

    if (ws_size < need) {
        zero_out<<<out_size / 256, 256, 0, stream>>>(out);
        return;
    }

    // 1. split inputs, project qkv via MFMA
    split_x<<<(int)(SZ_QKV / (256 * 8)), 256, 0, stream>>>(x, xh, xl);
    split_wT<<<(K3 * DIM) / 256, 256, 0, stream>>>(Wqkv, wqh, wql, K3);
    gemm_qkv_mfma<<<3072, 256, 0, stream>>>(xh, xl, wqh, wql, q, k, v);
    // 2. vT = v^T (overwrites xl -- dead)
    transpose_v<<<(BB * NH * MM) / 4, 256, 0, stream>>>(v, vT);
    // 3. landmark means + attn2 softmax (x2 overwrites xh -- dead)
    landmark_means<<<(BB * NH * MM * DD) / 256, 256, 0, stream>>>(q, k, qL, kL);
    attn2_softmax<<<BB * NH * MM, 256, 0, stream>>>(qL, kL, x2);
    // 4. attn3v FIRST (frees k/vT = all of d_out for pinv scratch)
    attn3v_mfma<<<256, 128, 0, stream>>>(qL, k, vT, t1);
    // 5. pinv scalars + z0/x2 pairs (rowmax of softmax == 1 analytically)
    init_scal<<<1, 64, 0, stream>>>(scal);
    csum_max<<<BB * NH, 256, 0, stream>>>(x2, scal);
    z_init_split<<<(int)(SZ_M2 / (256 * 8)), 256, 0, stream>>>(
        x2, scal, x2Ah, x2Al,
        zPair[0][0], zPair[0][1], zPair[0][2], zPair[0][3]);
    // 6. Newton-Schulz pinv, split-precision MFMA (eye7 fused into GEMM1)
    int cur = 0;
    for (int it = 0; it < 6; it++) {
        int nxt = cur ^ 1;
        // bufA = x2 @ z  (A-pairs); bufB^T = (7I - bufA)^T  (BT-pairs)
        bgemm_pair<<<dim3(4, 4, BB * NH), 256, 0, stream>>>(
            x2Ah, x2Al, zPair[cur][2], zPair[cur][3],
            bufAh, bufAl, bufBTh, bufBTl, nullptr,
            1.f, 0.f, -1.f, 7.f, 1 | 2);
        // z2 = 15I - bufA @ bufB -> BT-pairs
        bgemm_pair<<<dim3(4, 4, BB * NH), 256, 0, stream>>>(
            bufAh, bufAl, bufBTh, bufBTl,
            nullptr, nullptr, z2BTh, z2BTl, nullptr,
            -1.f, 15.f, 1.f, 0.f, 2);
        // bufB2 = 13I - bufA @ z2 -> BT-pairs (overwrite bufBT)
        bgemm_pair<<<dim3(4, 4, BB * NH), 256, 0, stream>>>(
            bufAh, bufAl, z2BTh, z2BTl,
            nullptr, nullptr, bufBTh, bufBTl, nullptr,
            -1.f, 13.f, 1.f, 0.f, 2);
        // z_next = 0.25 z @ bufB2; last iteration needs only fp32 (zf)
        int fl = (it == 5) ? 4 : (1 | 2);
        bgemm_pair<<<dim3(4, 4, BB * NH), 256, 0, stream>>>(
            zPair[cur][0], zPair[cur][1], bufBTh, bufBTl,
            zPair[nxt][0], zPair[nxt][1], zPair[nxt][2], zPair[nxt][3],
            zf, 0.25f, 0.f, 1.f, 0.f, fl);
        cur = nxt;
    }
    // 7. t2t = (z @ t1)^T in bf16 [bh][64][256]
    bgemm_t2t<<<dim3(1, 4, BB * NH), 256, 0, stream>>>(zf, t1, t2t);
    // 7b. kL -> bf16 (over dead t1) for attn1 B-fragments
    kl_to_bf16<<<(int)(SZ_L / (256 * 4)), 256, 0, stream>>>(kL, kl16);
    // 8. oh = softmax(q kL^T) @ t2 + conv(v)   (conv fused; q dead after)
    attn1_mfma<<<dim3(NN / 64, BB * NH), 256, 0, stream>>>(q, kl16, t2t, v, cw, oh);
    // 9. out = oh @ (WoutH + WoutL) + bout (overwrites d_out; scratch dead)
    split_wT<<<(DIM * DIM) / 256, 256, 0, stream>>>(Wout, woh, wol, DIM);
    gemm_out_mfma<<<1024, 256, 0, stream>>>(oh, woh, wol, bout, out);

    (void)in_sizes; (void)n_in; (void)ws_size;
}

// Round 11
// 1005.103 us; speedup vs baseline: 1.3110x; 1.0386x over previous
//
#include <hip/hip_runtime.h>
#include <hip/hip_bf16.h>
#include <math.h>

// Problem constants
#define BB 4
#define NH 8
#define NN 8192
#define DD 64
#define MM 256
#define LG 32
#define DIM 512
#define K3 1536
#define KER 33

typedef __hip_bfloat16 bf16;
typedef __attribute__((ext_vector_type(8))) short bf16x8;
typedef __attribute__((ext_vector_type(4))) float f32x4;

__device__ __forceinline__ float b2f(bf16 x) { return __bfloat162float(x); }
__device__ __forceinline__ bf16 f2b(float x) { return __float2bfloat16(x); }
__device__ __forceinline__ short f2bs(float x) { bf16 h = __float2bfloat16(x); return *reinterpret_cast<short*>(&h); }
__device__ __forceinline__ float bsf(short s) { return __uint_as_float(((unsigned int)(unsigned short)s) << 16); }
// bf16-pair unpack from a uint32 (lo short = first element)
__device__ __forceinline__ float blo(unsigned int u) { return __uint_as_float(u << 16); }
__device__ __forceinline__ float bhi(unsigned int u) { return __uint_as_float(u & 0xffff0000u); }

// async global->LDS, 16B per lane (dest must be linear: base + lane*16)
__device__ __forceinline__ void g2lds16(const void* g, void* l) {
    __builtin_amdgcn_global_load_lds(
        (const __attribute__((address_space(1))) unsigned int*)g,
        (__attribute__((address_space(3))) unsigned int*)l, 16, 0, 0);
}

// diagnostic fallback: zero the output
__global__ void zero_out(float* __restrict__ o) {
    o[(size_t)blockIdx.x * 256 + threadIdx.x] = 0.f;
}

// ---------------------------------------------------------------------------
// split fp32 -> bf16 hi + bf16 lo (residual), 8 elems/thread, 16B stores
__global__ void split_x(const float* __restrict__ x, short* __restrict__ xh,
                        short* __restrict__ xl) {
    size_t i = ((size_t)blockIdx.x * 256 + threadIdx.x) * 8;
    const float4* xp = (const float4*)(x + i);
    float4 v0 = xp[0], v1 = xp[1];
    float vv[8] = {v0.x, v0.y, v0.z, v0.w, v1.x, v1.y, v1.z, v1.w};
    short hb[8], lb[8];
#pragma unroll
    for (int u = 0; u < 8; u++) {
        bf16 h = f2b(vv[u]);
        hb[u] = *(short*)&h;
        lb[u] = f2bs(vv[u] - b2f(h));
    }
    *(uint4*)(xh + i) = *(uint4*)hb;
    *(uint4*)(xl + i) = *(uint4*)lb;
}

// split + transpose weight: W[k][n] fp32 -> wh/wl [n][K=512] bf16
__global__ void split_wT(const float* __restrict__ W, short* __restrict__ wh,
                         short* __restrict__ wl, int Nn) {
    int idx = blockIdx.x * 256 + threadIdx.x;   // n*512 + k
    int k = idx & 511, n = idx >> 9;
    float v = W[(size_t)k * Nn + n];
    bf16 h = f2b(v);
    wh[idx] = *(short*)&h;
    wl[idx] = f2bs(v - b2f(h));
}

// ---------------------------------------------------------------------------
// qkv projection via MFMA, split-precision (Xh@Wh + Xl@Wh + Xh@Wl).
__global__ __launch_bounds__(256) void gemm_qkv_mfma(
        const short* __restrict__ xh, const short* __restrict__ xl,
        const short* __restrict__ wh, const short* __restrict__ wl,
        bf16* __restrict__ q, bf16* __restrict__ k, bf16* __restrict__ v) {
    __shared__ short Ah[128 * 32];
    __shared__ short Al[128 * 32];
    __shared__ short Bh[128 * 32];
    __shared__ short Bl[128 * 32];
    int orig = blockIdx.x;
    int wg = (orig & 7) * 384 + (orig >> 3);
    int by = wg / 12, bx = wg - by * 12;
    int rowBase = by * 128, colBase = bx * 128;
    int tid = threadIdx.x;
    int rl = tid >> 2;
    int ch = (tid & 3) * 8;
    int wave = tid >> 6, lane = tid & 63;
    int ln = lane & 15, quad = lane >> 4;
    int wr = (wave >> 1) * 64, wc = (wave & 1) * 64;
    f32x4 acc[4][4];
#pragma unroll
    for (int mt = 0; mt < 4; mt++)
#pragma unroll
        for (int nt = 0; nt < 4; nt++) acc[mt][nt] = (f32x4){0.f, 0.f, 0.f, 0.f};

    for (int k0 = 0; k0 < DIM; k0 += 32) {
        __syncthreads();
#pragma unroll
        for (int p = 0; p < 2; p++) {
            int r = p * 64 + rl;
            size_t ga = (size_t)(rowBase + r) * DIM + k0 + ch;
            size_t gb = (size_t)(colBase + r) * DIM + k0 + ch;
            int lo = r * 32 + ch;
            g2lds16(xh + ga, &Ah[lo]);
            g2lds16(xl + ga, &Al[lo]);
            g2lds16(wh + gb, &Bh[lo]);
            g2lds16(wl + gb, &Bl[lo]);
        }
        __syncthreads();
        bf16x8 a_h[4], a_l[4], b_h[4], b_l[4];
#pragma unroll
        for (int mt = 0; mt < 4; mt++) {
            int o = (wr + mt * 16 + ln) * 32 + quad * 8;
            a_h[mt] = *(const bf16x8*)&Ah[o];
            a_l[mt] = *(const bf16x8*)&Al[o];
        }
#pragma unroll
        for (int nt = 0; nt < 4; nt++) {
            int o = (wc + nt * 16 + ln) * 32 + quad * 8;
            b_h[nt] = *(const bf16x8*)&Bh[o];
            b_l[nt] = *(const bf16x8*)&Bl[o];
        }
#pragma unroll
        for (int mt = 0; mt < 4; mt++)
#pragma unroll
            for (int nt = 0; nt < 4; nt++) {
                acc[mt][nt] = __builtin_amdgcn_mfma_f32_16x16x32_bf16(a_h[mt], b_h[nt], acc[mt][nt], 0, 0, 0);
                acc[mt][nt] = __builtin_amdgcn_mfma_f32_16x16x32_bf16(a_l[mt], b_h[nt], acc[mt][nt], 0, 0, 0);
                acc[mt][nt] = __builtin_amdgcn_mfma_f32_16x16x32_bf16(a_h[mt], b_l[nt], acc[mt][nt], 0, 0, 0);
            }
    }
    int part = colBase >> 9;
    bf16* dst = part == 0 ? q : (part == 1 ? k : v);
    float scale = part == 0 ? 0.125f : 1.0f;
#pragma unroll
    for (int mt = 0; mt < 4; mt++)
#pragma unroll
        for (int nt = 0; nt < 4; nt++)
#pragma unroll
            for (int r = 0; r < 4; r++) {
                int row = rowBase + wr + mt * 16 + quad * 4 + r;
                int col = colBase + wc + nt * 16 + ln;
                int h = (col & 511) >> 6, d = col & 63;
                int b_ = row >> 13, n_ = row & 8191;
                size_t di = ((size_t)(b_ * NH + h) * NN + n_) * DD + d;
                dst[di] = f2b(acc[mt][nt][r] * scale);
            }
}

// out projection via MFMA: oh(bf16) @ (Wh+Wl) + bias -> fp32
__global__ __launch_bounds__(256) void gemm_out_mfma(
        const bf16* __restrict__ A, const short* __restrict__ wh,
        const short* __restrict__ wl, const float* __restrict__ bias,
        float* __restrict__ C) {
    __shared__ short As[128 * 32];
    __shared__ short Bh[128 * 32];
    __shared__ short Bl[128 * 32];
    int orig = blockIdx.x;                       // nwg = 1024
    int wg = (orig & 7) * 128 + (orig >> 3);
    int by = wg >> 2, bx = wg & 3;
    int rowBase = by * 128, colBase = bx * 128;
    int tid = threadIdx.x;
    int rl = tid >> 2, ch = (tid & 3) * 8;
    int wave = tid >> 6, lane = tid & 63;
    int ln = lane & 15, quad = lane >> 4;
    int wr = (wave >> 1) * 64, wc = (wave & 1) * 64;
    const short* Ab = (const short*)A;
    f32x4 acc[4][4];
#pragma unroll
    for (int mt = 0; mt < 4; mt++)
#pragma unroll
        for (int nt = 0; nt < 4; nt++) acc[mt][nt] = (f32x4){0.f, 0.f, 0.f, 0.f};

    for (int k0 = 0; k0 < DIM; k0 += 32) {
        __syncthreads();
#pragma unroll
        for (int p = 0; p < 2; p++) {
            int r = p * 64 + rl;
            size_t ga = (size_t)(rowBase + r) * DIM + k0 + ch;
            size_t gb = (size_t)(colBase + r) * DIM + k0 + ch;
            int lo = r * 32 + ch;
            g2lds16(Ab + ga, &As[lo]);
            g2lds16(wh + gb, &Bh[lo]);
            g2lds16(wl + gb, &Bl[lo]);
        }
        __syncthreads();
        bf16x8 a[4], b_h[4], b_l[4];
#pragma unroll
        for (int mt = 0; mt < 4; mt++)
            a[mt] = *(const bf16x8*)&As[(wr + mt * 16 + ln) * 32 + quad * 8];
#pragma unroll
        for (int nt = 0; nt < 4; nt++) {
            int o = (wc + nt * 16 + ln) * 32 + quad * 8;
            b_h[nt] = *(const bf16x8*)&Bh[o];
            b_l[nt] = *(const bf16x8*)&Bl[o];
        }
#pragma unroll
        for (int mt = 0; mt < 4; mt++)
#pragma unroll
            for (int nt = 0; nt < 4; nt++) {
                acc[mt][nt] = __builtin_amdgcn_mfma_f32_16x16x32_bf16(a[mt], b_h[nt], acc[mt][nt], 0, 0, 0);
                acc[mt][nt] = __builtin_amdgcn_mfma_f32_16x16x32_bf16(a[mt], b_l[nt], acc[mt][nt], 0, 0, 0);
            }
    }
#pragma unroll
    for (int mt = 0; mt < 4; mt++)
#pragma unroll
        for (int nt = 0; nt < 4; nt++)
#pragma unroll
            for (int r = 0; r < 4; r++) {
                int row = rowBase + wr + mt * 16 + quad * 4 + r;
                int col = colBase + wc + nt * 16 + ln;
                C[(size_t)row * DIM + col] = acc[mt][nt][r] + bias[col];
            }
}

// ---------------------------------------------------------------------------
// Batched split-precision MFMA GEMM for the pinv chain.
// val = scale*(A@B) + alpha*I.  A-layout/fp32 outputs get val;
// B^T-layout output gets scaleB*val + alphaB*I (lets eye7 fuse into GEMM1).
// 64x64 tile, 4 waves, grid dim3(4,4,32) = 512 blocks (2 blocks/CU).
__global__ __launch_bounds__(256) void bgemm_pair(
        const short* __restrict__ Ah, const short* __restrict__ Al,
        const short* __restrict__ Bh, const short* __restrict__ Bl,
        short* __restrict__ oAh, short* __restrict__ oAl,
        short* __restrict__ oBh, short* __restrict__ oBl,
        float* __restrict__ oF, float scale, float alpha,
        float scaleB, float alphaB, int flags) {
    __shared__ short sAh[64 * 32];
    __shared__ short sAl[64 * 32];
    __shared__ short sBh[64 * 32];
    __shared__ short sBl[64 * 32];
    int bat = blockIdx.z;
    int rowBase = blockIdx.y * 64;    // 0..192
    int colBase = blockIdx.x * 64;    // 0..192
    const size_t MB = (size_t)bat * (MM * MM);
    int tid = threadIdx.x;
    int rl = tid >> 2, ch = (tid & 3) * 8;   // rl 0..63
    int wave = tid >> 6, lane = tid & 63;
    int ln = lane & 15, quad = lane >> 4;
    int wr = (wave >> 1) * 32, wc = (wave & 1) * 32;
    f32x4 acc[2][2];
#pragma unroll
    for (int mt = 0; mt < 2; mt++)
#pragma unroll
        for (int nt = 0; nt < 2; nt++) acc[mt][nt] = (f32x4){0.f, 0.f, 0.f, 0.f};

    for (int k0 = 0; k0 < MM; k0 += 32) {
        __syncthreads();
        {
            size_t ga = MB + (size_t)(rowBase + rl) * MM + k0 + ch;
            size_t gb = MB + (size_t)(colBase + rl) * MM + k0 + ch;
            int lo = rl * 32 + ch;
            g2lds16(Ah + ga, &sAh[lo]);
            g2lds16(Al + ga, &sAl[lo]);
            g2lds16(Bh + gb, &sBh[lo]);
            g2lds16(Bl + gb, &sBl[lo]);
        }
        __syncthreads();
        bf16x8 a_h[2], a_l[2], b_h[2], b_l[2];
#pragma unroll
        for (int mt = 0; mt < 2; mt++) {
            int o = (wr + mt * 16 + ln) * 32 + quad * 8;
            a_h[mt] = *(const bf16x8*)&sAh[o];
            a_l[mt] = *(const bf16x8*)&sAl[o];
        }
#pragma unroll
        for (int nt = 0; nt < 2; nt++) {
            int o = (wc + nt * 16 + ln) * 32 + quad * 8;
            b_h[nt] = *(const bf16x8*)&sBh[o];
            b_l[nt] = *(const bf16x8*)&sBl[o];
        }
#pragma unroll
        for (int mt = 0; mt < 2; mt++)
#pragma unroll
            for (int nt = 0; nt < 2; nt++) {
                acc[mt][nt] = __builtin_amdgcn_mfma_f32_16x16x32_bf16(a_h[mt], b_h[nt], acc[mt][nt], 0, 0, 0);
                acc[mt][nt] = __builtin_amdgcn_mfma_f32_16x16x32_bf16(a_l[mt], b_h[nt], acc[mt][nt], 0, 0, 0);
                acc[mt][nt] = __builtin_amdgcn_mfma_f32_16x16x32_bf16(a_h[mt], b_l[nt], acc[mt][nt], 0, 0, 0);
            }
    }
#pragma unroll
    for (int mt = 0; mt < 2; mt++)
#pragma unroll
        for (int nt = 0; nt < 2; nt++) {
            short bh4[4], bl4[4];
            int col = colBase + wc + nt * 16 + ln;
            int row0 = rowBase + wr + mt * 16 + quad * 4;
#pragma unroll
            for (int r = 0; r < 4; r++) {
                int row = row0 + r;
                float val = scale * acc[mt][nt][r];
                if (row == col) val += alpha;
                if (flags & 4) oF[MB + (size_t)row * MM + col] = val;
                if (flags & 1) {
                    short vh = f2bs(val);
                    oAh[MB + (size_t)row * MM + col] = vh;
                    oAl[MB + (size_t)row * MM + col] = f2bs(val - bsf(vh));
                }
                float bv = scaleB * val;
                if (row == col) bv += alphaB;
                short bvh = f2bs(bv);
                bh4[r] = bvh; bl4[r] = f2bs(bv - bsf(bvh));
            }
            if (flags & 2) {
                size_t o = MB + (size_t)col * MM + row0;
                *(uint2*)&oBh[o] = *(uint2*)bh4;
                *(uint2*)&oBl[o] = *(uint2*)bl4;
            }
        }
}

// z0 = x2^T / (colmax + 1e-12) -> zA pairs + zBT pairs; also x2 -> A pairs.
// (rowmax of a softmax = 1 analytically, so scal[0] holds only colmax.)
__global__ void z_init_split(const float* __restrict__ x2, const float* __restrict__ scal,
                             short* __restrict__ x2Ah, short* __restrict__ x2Al,
                             short* __restrict__ zAh, short* __restrict__ zAl,
                             short* __restrict__ zBh, short* __restrict__ zBl) {
    size_t base = ((size_t)blockIdx.x * 256 + threadIdx.x) * 8;
    float inv = 1.0f / (scal[0] + 1e-12f);
    int c0 = (int)(base & 255);
    int r = (int)((base >> 8) & 255);
    size_t MB = (base >> 16) << 16;
    const float4* xp = (const float4*)(x2 + base);
    float4 v0 = xp[0], v1 = xp[1];
    float vv[8] = {v0.x, v0.y, v0.z, v0.w, v1.x, v1.y, v1.z, v1.w};
    short ho[8], lo_[8], h2[8], l2[8];
#pragma unroll
    for (int u = 0; u < 8; u++) {
        short xh = f2bs(vv[u]);
        h2[u] = xh; l2[u] = f2bs(vv[u] - bsf(xh));
        float zv = vv[u] * inv;
        short zh = f2bs(zv);
        ho[u] = zh; lo_[u] = f2bs(zv - bsf(zh));
    }
    *(uint4*)&x2Ah[base] = *(uint4*)h2;
    *(uint4*)&x2Al[base] = *(uint4*)l2;
    *(uint4*)&zBh[base] = *(uint4*)ho;
    *(uint4*)&zBl[base] = *(uint4*)lo_;
    // A layout: zA[bat][r][c] = z[r][c] = x2[bat][c][r]*inv  (strided read)
#pragma unroll
    for (int u = 0; u < 8; u++) {
        float v = x2[MB + (size_t)(c0 + u) * MM + r] * inv;
        short vh = f2bs(v);
        ho[u] = vh; lo_[u] = f2bs(v - bsf(vh));
    }
    *(uint4*)&zAh[base] = *(uint4*)ho;
    *(uint4*)&zAl[base] = *(uint4*)lo_;
}

// t2t = (z @ t1)^T per batch, stored bf16 [bh][d=64][landmark=256]
__global__ void bgemm_t2t(const float* __restrict__ A, const float* __restrict__ B,
                          short* __restrict__ T) {
    __shared__ float As[16][64];
    __shared__ float Bs[16][64];
    int bat = blockIdx.z;
    const float* Ab = A + (size_t)bat * MM * MM;   // z [256,256]
    const float* Bb = B + (size_t)bat * MM * DD;   // t1 [256,64]
    short* Tb = T + (size_t)bat * DD * MM;
    int tid = threadIdx.x;
    int rowBase = blockIdx.y * 64;
    int ty = tid >> 4, tx = tid & 15;
    float acc[4][4] = {};
    for (int k0 = 0; k0 < MM; k0 += 16) {
        for (int idx = tid; idx < 64 * 16; idx += 256) {
            int r = idx >> 4, c = idx & 15;
            As[c][r] = Ab[(size_t)(rowBase + r) * MM + k0 + c];
        }
        for (int idx = tid; idx < 16 * 64; idx += 256) {
            int r = idx >> 6, c = idx & 63;
            Bs[r][c] = Bb[(size_t)(k0 + r) * DD + c];
        }
        __syncthreads();
#pragma unroll
        for (int kk = 0; kk < 16; kk++) {
            float a[4], b[4];
#pragma unroll
            for (int i = 0; i < 4; i++) a[i] = As[kk][ty * 4 + i];
#pragma unroll
            for (int j = 0; j < 4; j++) b[j] = Bs[kk][tx * 4 + j];
#pragma unroll
            for (int i = 0; i < 4; i++)
#pragma unroll
                for (int j = 0; j < 4; j++) acc[i][j] += a[i] * b[j];
        }
        __syncthreads();
    }
#pragma unroll
    for (int i = 0; i < 4; i++) {
        int r = rowBase + ty * 4 + i;     // landmark
#pragma unroll
        for (int j = 0; j < 4; j++) {
            int c = tx * 4 + j;           // d
            Tb[(size_t)c * MM + r] = f2bs(acc[i][j]);
        }
    }
}

// ---------------------------------------------------------------------------
// landmark means: qL/kL[bh,mi,d] = mean over 32 tokens (bf16 in, fp32 out)
__global__ void landmark_means(const bf16* __restrict__ q, const bf16* __restrict__ k,
                               float* __restrict__ qL, float* __restrict__ kL) {
    int idx = blockIdx.x * 256 + threadIdx.x;   // (bh*256 + mi)*64 + d
    int d = idx & 63;
    int mi = (idx >> 6) & 255;
    int bh = idx >> 14;
    const bf16* qp = q + ((size_t)bh * NN + mi * LG) * DD + d;
    const bf16* kp = k + ((size_t)bh * NN + mi * LG) * DD + d;
    float sq = 0.f, sk = 0.f;
#pragma unroll
    for (int j = 0; j < LG; j++) { sq += b2f(qp[(size_t)j * DD]); sk += b2f(kp[(size_t)j * DD]); }
    qL[idx] = sq * (1.f / LG);
    kL[idx] = sk * (1.f / LG);
}

// kL fp32 -> bf16 copy (for attn1 B-fragments)
__global__ void kl_to_bf16(const float* __restrict__ kL, short* __restrict__ kl16) {
    size_t i = ((size_t)blockIdx.x * 256 + threadIdx.x) * 4;
    float4 v = *(const float4*)(kL + i);
    short o[4] = {f2bs(v.x), f2bs(v.y), f2bs(v.z), f2bs(v.w)};
    *(uint2*)&kl16[i] = *(uint2*)o;
}

// attn2 = softmax(qL @ kL^T), one block per row (all fp32)
__global__ void attn2_softmax(const float* __restrict__ qL, const float* __restrict__ kL,
                              float* __restrict__ x2) {
    __shared__ float qs[64];
    __shared__ float red[256];
    int bh = blockIdx.x >> 8, i = blockIdx.x & 255;
    int t = threadIdx.x;
    if (t < 64) qs[t] = qL[((size_t)bh * MM + i) * DD + t];
    __syncthreads();
    const float4* kp = (const float4*)(kL + ((size_t)bh * MM + t) * DD);
    float l = 0.f;
#pragma unroll
    for (int u = 0; u < 16; u++) {
        float4 kv = kp[u];
        l += qs[u*4+0]*kv.x + qs[u*4+1]*kv.y + qs[u*4+2]*kv.z + qs[u*4+3]*kv.w;
    }
    red[t] = l; __syncthreads();
    for (int s = 128; s > 0; s >>= 1) { if (t < s) red[t] = fmaxf(red[t], red[t + s]); __syncthreads(); }
    float mx = red[0]; __syncthreads();
    float e = __expf(l - mx);
    red[t] = e; __syncthreads();
    for (int s = 128; s > 0; s >>= 1) { if (t < s) red[t] += red[t + s]; __syncthreads(); }
    x2[((size_t)bh * MM + i) * MM + t] = e / red[0];
}

__global__ void init_scal(float* scal) {
    if (threadIdx.x == 0) { scal[0] = 0.f; scal[1] = 0.f; }
}

// max over (bh,j) of sum_i |x|  -> scal[0]   (rowmax of softmax == 1)
__global__ void csum_max(const float* __restrict__ x2, float* scal) {
    __shared__ float red[256];
    int t = threadIdx.x;
    const float* xp = x2 + (size_t)blockIdx.x * MM * MM;
    float s = 0.f;
    for (int i = 0; i < MM; i++) s += fabsf(xp[(size_t)i * MM + t]);
    red[t] = s; __syncthreads();
    for (int st = 128; st > 0; st >>= 1) { if (t < st) red[t] = fmaxf(red[t], red[t + st]); __syncthreads(); }
    if (t == 0) atomicMax((unsigned int*)&scal[0], __float_as_uint(red[0]));
}

// ---------------------------------------------------------------------------
// v transpose: vT[bh][d][n] <- v[bh][n][d].
__global__ void transpose_v(const bf16* __restrict__ v, bf16* __restrict__ vT) {
    int gw = blockIdx.x * 4 + (threadIdx.x >> 6);   // global wave id
    int lane = threadIdx.x & 63;                     // = d
    int bh = gw >> 8;
    int c  = gw & 255;                               // n-chunk (32 tokens)
    const bf16* vb = v + ((size_t)bh * NN + c * 32) * DD + lane;
    unsigned short buf[32];
#pragma unroll
    for (int i = 0; i < 32; i++) buf[i] = *(const unsigned short*)(vb + (size_t)i * DD);
    bf16* dst = vT + ((size_t)bh * DD + lane) * NN + c * 32;
#pragma unroll
    for (int u = 0; u < 4; u++)
        *(uint4*)(dst + u * 8) = *(uint4*)&buf[u * 8];
}

// ---------------------------------------------------------------------------
// MFMA flash attn3v: t1 = softmax(qL @ k^T over n) @ v
// 4 waves / 32 landmark rows per block; wave-pairs split the j-loop
// (pair 0 = even 128-token chunks, pair 1 = odd), private ks/vs per pair,
// exact flash-combine merge at the end. Grid 256 blocks (8 rb x 32 bh),
// XCD-pinned: all 8 row-blocks of one bh map to the same XCD (g%8).
#define NJ 128
#define KS2 72
#define VS2 136
#define PS2 136
__global__ __launch_bounds__(256) void attn3v_mfma(
        const float* __restrict__ qL, const bf16* __restrict__ k,
        const bf16* __restrict__ vT, float* __restrict__ t1) {
    __shared__ short ks[2][NJ * KS2];       // 36864 B  [pair][j][d]
    __shared__ short vs[2][DD * VS2];       // 34816 B  [pair][d][j]
    __shared__ short ps[4][16 * PS2];       // 17408 B  per-wave P [row][j]
    __shared__ float mb[128 * 25];          // 12800 B  pair-B merge state
    int g = blockIdx.x;
    int c = g & 7, t = g >> 3;
    int bh = c + 8 * (t >> 3);
    int r0 = (t & 7) * 32;
    int tid = threadIdx.x;
    int wave = tid >> 6, lane = tid & 63;
    int pair = wave >> 1, wv = wave & 1;
    int ptid = tid & 127;
    int ln = lane & 15, quad = lane >> 4;
    int m = r0 + wv * 16 + ln;
    const float* qrow = qL + ((size_t)bh * MM + m) * DD;
    bf16x8 a0, a1;
#pragma unroll
    for (int u = 0; u < 8; u++) {
        ((short*)&a0)[u] = f2bs(qrow[quad * 8 + u]);
        ((short*)&a1)[u] = f2bs(qrow[32 + quad * 8 + u]);
    }
    const uint4* kg = (const uint4*)(k + (size_t)bh * NN * DD);
    const uint4* vg = (const uint4*)(vT + (size_t)bh * DD * NN);
    float mrow[4], lrow[4];
    f32x4 o[4];
#pragma unroll
    for (int r = 0; r < 4; r++) { mrow[r] = -1e30f; lrow[r] = 0.f; }
#pragma unroll
    for (int ct = 0; ct < 4; ct++) o[ct] = (f32x4){0.f, 0.f, 0.f, 0.f};
    short* pw = &ps[wave][0];
    short* ksp = &ks[pair][0];
    short* vsp = &vs[pair][0];

    for (int it = 0; it < NN / (2 * NJ); it++) {
        int j0 = (2 * it + pair) * NJ;
        __syncthreads();
#pragma unroll
        for (int s = 0; s < 8; s++) {
            int idx = s * 128 + ptid;
            int row = idx >> 3, c8 = idx & 7;
            uint4 pk = kg[(size_t)(j0 + row) * 8 + c8];
            *(uint4*)&ksp[row * KS2 + c8 * 8] = pk;
        }
#pragma unroll
        for (int s = 0; s < 8; s++) {
            int idx = s * 128 + ptid;
            int row = idx >> 4, c8 = idx & 15;
            uint4 pv = vg[(size_t)row * (NN / 8) + (j0 / 8) + c8];
            *(uint4*)&vsp[row * VS2 + c8 * 8] = pv;
        }
        __syncthreads();
        f32x4 s[8];
#pragma unroll
        for (int ct = 0; ct < 8; ct++) {
            const short* kp = &ksp[(ct * 16 + ln) * KS2 + quad * 8];
            bf16x8 b0 = *(const bf16x8*)kp;
            bf16x8 b1 = *(const bf16x8*)(kp + 32);
            f32x4 cc = {0.f, 0.f, 0.f, 0.f};
            cc = __builtin_amdgcn_mfma_f32_16x16x32_bf16(a0, b0, cc, 0, 0, 0);
            cc = __builtin_amdgcn_mfma_f32_16x16x32_bf16(a1, b1, cc, 0, 0, 0);
            s[ct] = cc;
        }
#pragma unroll
        for (int r = 0; r < 4; r++) {
            float v = -1e30f;
#pragma unroll
            for (int ct = 0; ct < 8; ct++) v = fmaxf(v, s[ct][r]);
            v = fmaxf(v, __shfl_xor(v, 1));
            v = fmaxf(v, __shfl_xor(v, 2));
            v = fmaxf(v, __shfl_xor(v, 4));
            v = fmaxf(v, __shfl_xor(v, 8));
            float mn = fmaxf(mrow[r], v);
            float alpha = __expf(mrow[r] - mn);
            mrow[r] = mn;
            float psum = 0.f;
#pragma unroll
            for (int ct = 0; ct < 8; ct++) { float e = __expf(s[ct][r] - mn); s[ct][r] = e; psum += e; }
            lrow[r] = lrow[r] * alpha + psum;
#pragma unroll
            for (int c2 = 0; c2 < 4; c2++) o[c2][r] *= alpha;
        }
#pragma unroll
        for (int ct = 0; ct < 8; ct++)
#pragma unroll
            for (int r = 0; r < 4; r++)
                pw[(quad * 4 + r) * PS2 + ct * 16 + ln] = f2bs(s[ct][r]);
#pragma unroll
        for (int kstep = 0; kstep < 4; kstep++) {
            bf16x8 pa = *(const bf16x8*)&pw[ln * PS2 + kstep * 32 + quad * 8];
#pragma unroll
            for (int ct = 0; ct < 4; ct++) {
                bf16x8 pb = *(const bf16x8*)&vsp[(ct * 16 + ln) * VS2 + kstep * 32 + quad * 8];
                o[ct] = __builtin_amdgcn_mfma_f32_16x16x32_bf16(pa, pb, o[ct], 0, 0, 0);
            }
        }
    }
    // flash-combine: pair 1 publishes its (m,l,O); pair 0 merges exactly.
    __syncthreads();
    if (wave >= 2) {
        float* mp = &mb[(tid - 128) * 25];
#pragma unroll
        for (int r = 0; r < 4; r++) { mp[r] = mrow[r]; mp[4 + r] = lrow[r]; }
#pragma unroll
        for (int ct = 0; ct < 4; ct++)
#pragma unroll
            for (int r = 0; r < 4; r++) mp[8 + ct * 4 + r] = o[ct][r];
    }
    __syncthreads();
    if (wave < 2) {
        const float* mp = &mb[(wave * 64 + lane) * 25];
#pragma unroll
        for (int r = 0; r < 4; r++) {
            float mB = mp[r], lB = mp[4 + r];
            float mn = fmaxf(mrow[r], mB);
            float eA = __expf(mrow[r] - mn);
            float eB = __expf(mB - mn);
            lrow[r] = lrow[r] * eA + lB * eB;
#pragma unroll
            for (int ct = 0; ct < 4; ct++)
                o[ct][r] = o[ct][r] * eA + mp[8 + ct * 4 + r] * eB;
        }
#pragma unroll
        for (int r = 0; r < 4; r++) {
            float l = lrow[r];
            l += __shfl_xor(l, 1);
            l += __shfl_xor(l, 2);
            l += __shfl_xor(l, 4);
            l += __shfl_xor(l, 8);
            lrow[r] = 1.0f / l;
        }
#pragma unroll
        for (int ct = 0; ct < 4; ct++)
#pragma unroll
            for (int r = 0; r < 4; r++) {
                int row = r0 + wv * 16 + quad * 4 + r;
                t1[((size_t)bh * MM + row) * DD + ct * 16 + ln] = o[ct][r] * lrow[r];
            }
    }
}

// ---------------------------------------------------------------------------
// MFMA fused attn1 + depthwise conv residual:
// oh[b,i,h*64+d] = softmax(q_i kL^T) @ t2 + conv(v)
// kl16/t2t are L2-resident -> B-fragments read directly from global.
// Conv v-window stored TRANSPOSED vt[d][col] so window reads are b64
// (9 per nt-group instead of 36 scalar u16). LDS 47.6 KB -> 3 blocks/CU.
#define T2S 264
#define VTS 108
__global__ __launch_bounds__(256, 3) void attn1_mfma(
        const bf16* __restrict__ q, const short* __restrict__ kl16,
        const short* __restrict__ t2t, const bf16* __restrict__ v,
        const float* __restrict__ cw, bf16* __restrict__ oh) {
    __shared__ short ps1[4][16 * T2S];      // 33792 B
    __shared__ short vt[64 * VTS];          // 13824 B  vt[d][col], col=n-16..n+79
    int bh = blockIdx.y;
    int n0 = blockIdx.x * 64;
    int tid = threadIdx.x;
    int b_ = bh >> 3, h = bh & 7;
    // stage conv v window transposed: read v[gn][d] coalesced, write vt[d][row]
    const bf16* vb = v + (size_t)bh * NN * DD;
    for (int idx = tid; idx < 96 * 8; idx += 256) {
        int row = idx >> 3, c8 = (idx & 7) * 8;
        int gn = n0 - 16 + row;
        uint4 pv;
        pv.x = pv.y = pv.z = pv.w = 0u;
        if (gn >= 0 && gn < NN) pv = *(const uint4*)(vb + (size_t)gn * DD + c8);
        short tmp[8];
        *(uint4*)tmp = pv;
#pragma unroll
        for (int u = 0; u < 8; u++) vt[(c8 + u) * VTS + row] = tmp[u];
    }
    int wave = tid >> 6, lane = tid & 63;
    int ln = lane & 15, quad = lane >> 4;
    int m = n0 + wave * 16 + ln;
    const bf16* qrow = q + ((size_t)bh * NN + m) * DD;
    bf16x8 a0 = *(const bf16x8*)(qrow + quad * 8);
    bf16x8 a1 = *(const bf16x8*)(qrow + 32 + quad * 8);
    // QK^T: B-fragments straight from kl16 (L2-hot, coalesced 2KB/wave-tile)
    const short* klb = kl16 + (size_t)bh * MM * DD;
    f32x4 acc[16];
#pragma unroll
    for (int nt = 0; nt < 16; nt++) {
        const short* kp = klb + (nt * 16 + ln) * DD + quad * 8;
        bf16x8 b0 = *(const bf16x8*)kp;
        bf16x8 b1 = *(const bf16x8*)(kp + 32);
        f32x4 c = {0.f, 0.f, 0.f, 0.f};
        c = __builtin_amdgcn_mfma_f32_16x16x32_bf16(a0, b0, c, 0, 0, 0);
        c = __builtin_amdgcn_mfma_f32_16x16x32_bf16(a1, b1, c, 0, 0, 0);
        acc[nt] = c;
    }
    float inv[4];
#pragma unroll
    for (int r = 0; r < 4; r++) {
        float vx = -1e30f;
#pragma unroll
        for (int nt = 0; nt < 16; nt++) vx = fmaxf(vx, acc[nt][r]);
        vx = fmaxf(vx, __shfl_xor(vx, 1));
        vx = fmaxf(vx, __shfl_xor(vx, 2));
        vx = fmaxf(vx, __shfl_xor(vx, 4));
        vx = fmaxf(vx, __shfl_xor(vx, 8));
        float s = 0.f;
#pragma unroll
        for (int nt = 0; nt < 16; nt++) { float e = __expf(acc[nt][r] - vx); acc[nt][r] = e; s += e; }
        s += __shfl_xor(s, 1);
        s += __shfl_xor(s, 2);
        s += __shfl_xor(s, 4);
        s += __shfl_xor(s, 8);
        inv[r] = 1.0f / s;
    }
    short* pw = &ps1[wave][0];
#pragma unroll
    for (int nt = 0; nt < 16; nt++)
#pragma unroll
        for (int r = 0; r < 4; r++)
            pw[(quad * 4 + r) * T2S + nt * 16 + ln] = f2bs(acc[nt][r]);
    __syncthreads();
    // PV: B-fragments straight from t2t [bh][d][landmark] (L2-hot)
    const short* t2b = t2t + (size_t)bh * DD * MM;
    f32x4 o[4];
#pragma unroll
    for (int nt = 0; nt < 4; nt++) o[nt] = (f32x4){0.f, 0.f, 0.f, 0.f};
#pragma unroll
    for (int ks = 0; ks < 8; ks++) {
        bf16x8 pa = *(const bf16x8*)&pw[ln * T2S + ks * 32 + quad * 8];
#pragma unroll
        for (int nt = 0; nt < 4; nt++) {
            bf16x8 pb = *(const bf16x8*)(t2b + (nt * 16 + ln) * MM + ks * 32 + quad * 8);
            o[nt] = __builtin_amdgcn_mfma_f32_16x16x32_bf16(pa, pb, o[nt], 0, 0, 0);
        }
    }
    // epilogue: add conv residual from vt (b64 window loads), write oh
    const float* wrow = cw + h * KER;
    int lbase = wave * 16 + quad * 4;    // output r=0's window start col
#pragma unroll
    for (int nt = 0; nt < 4; nt++) {
        int d = nt * 16 + ln;
        const short* vrow = &vt[d * VTS + lbase];
        float win[36];
#pragma unroll
        for (int j4 = 0; j4 < 9; j4++) {
            uint2 w4 = *(const uint2*)(vrow + j4 * 4);
            win[j4 * 4 + 0] = blo(w4.x); win[j4 * 4 + 1] = bhi(w4.x);
            win[j4 * 4 + 2] = blo(w4.y); win[j4 * 4 + 3] = bhi(w4.y);
        }
        float res[4] = {0.f, 0.f, 0.f, 0.f};
#pragma unroll
        for (int t = 0; t < KER; t++) {
            float wt = wrow[t];
#pragma unroll
            for (int r = 0; r < 4; r++) res[r] += wt * win[r + t];
        }
#pragma unroll
        for (int r = 0; r < 4; r++) {
            int row = n0 + lbase + r;
            oh[((size_t)(b_ * NN + row)) * DIM + h * 64 + d] = f2b(o[nt][r] * inv[r] + res[r]);
        }
    }
}

// ---------------------------------------------------------------------------

extern "C" void kernel_launch(void* const* d_in, const int* in_sizes, int n_in,
                              void* d_out, int out_size, void* d_ws, size_t ws_size,
                              hipStream_t stream) {
    const float* x    = (const float*)d_in[0];
    const float* Wqkv = (const float*)d_in[1];
    const float* Wout = (const float*)d_in[2];
    const float* bout = (const float*)d_in[3];
    const float* cw   = (const float*)d_in[4];
    float* out = (float*)d_out;

    const size_t SZ_QKV = (size_t)BB * NH * NN * DD;   // 16,777,216 elems
    const size_t SZ_L   = (size_t)BB * NH * MM * DD;   // 524,288
    const size_t SZ_M2  = (size_t)BB * NH * MM * MM;   // 2,097,152

    // --- workspace plumbing (unchanged footprint) ---
    char* p = (char*)d_ws;
    bf16* q    = (bf16*)p;  p += SZ_QKV * 2;    // 32 MB
    bf16* v    = (bf16*)p;  p += SZ_QKV * 2;    // 32 MB
    float* x2   = (float*)p; p += SZ_M2 * 4;    // 8 MB each
    float* zf   = (float*)p; p += SZ_M2 * 4;    // final fp32 z lives here
    float* z2r  = (float*)p; p += SZ_M2 * 4;    // region reused for x2 pairs
    float* bAr  = (float*)p; p += SZ_M2 * 4;    // region reused for bufA pairs
    float* bBr  = (float*)p; p += SZ_M2 * 4;    // region for wqh/wql
    float* qL   = (float*)p; p += SZ_L * 4;     // 2 MB each
    float* kL   = (float*)p; p += SZ_L * 4;
    float* t1   = (float*)p; p += SZ_L * 4;
    short* t2t  = (short*)p; p += SZ_L * 4;
    float* scal = (float*)p; p += 2 * 4;
    size_t need = (size_t)(p - (char*)d_ws);
    bf16* k  = (bf16*)d_out;                     // first 32 MB of out buffer
    bf16* vT = (bf16*)d_out + SZ_QKV;            // second 32 MB of out buffer
    bf16* oh = (bf16*)x2;                        // 32 MB over dead pinv region

    // split-precision scratch for projections (aliased, dead at use time):
    short* xh  = (short*)x2;                     // 32 MB over x2..bAr
    short* xl  = (short*)vT;                     // vT half of d_out
    short* wqh = (short*)bBr;                    // 1.5 MB
    short* wql = (short*)bBr + (size_t)K3 * DIM;
    short* woh = (short*)q;                      // q dead after attn1_mfma
    short* wol = (short*)q + (size_t)DIM * DIM;
    short* kl16 = (short*)t1;                    // t1 dead after bgemm_t2t

    // pinv pair scratch (after attn3v, k/vT in d_out are dead):
    const size_t U = SZ_M2;                      // 4 MiB per bf16 array
    short* db = (short*)d_out;
    short* bufBTh = db + 0 * U;  short* bufBTl = db + 1 * U;
    short* z2BTh  = db + 2 * U;  short* z2BTl  = db + 3 * U;
    short* zPair[2][4] = {                       // {Ah, Al, BTh, BTl} x 2 buffers
        { db + 4 * U, db + 5 * U, db + 6 * U, db + 7 * U },
        { db + 8 * U, db + 9 * U, db + 10 * U, db + 11 * U } };
    short* x2Ah = (short*)z2r;   short* x2Al = (short*)z2r + U;
    short* bufAh = (short*)bAr;  short* bufAl = (short*)bAr + U;

    if (ws_size < need) {
        zero_out<<<out_size / 256, 256, 0, stream>>>(out);
        return;
    }

    // 1. split inputs, project qkv via MFMA
    split_x<<<(int)(SZ_QKV / (256 * 8)), 256, 0, stream>>>(x, xh, xl);
    split_wT<<<(K3 * DIM) / 256, 256, 0, stream>>>(Wqkv, wqh, wql, K3);
    gemm_qkv_mfma<<<3072, 256, 0, stream>>>(xh, xl, wqh, wql, q, k, v);
    // 2. vT = v^T (overwrites xl -- dead)
    transpose_v<<<(BB * NH * MM) / 4, 256, 0, stream>>>(v, vT);
    // 3. landmark means + attn2 softmax (x2 overwrites xh -- dead)
    landmark_means<<<(BB * NH * MM * DD) / 256, 256, 0, stream>>>(q, k, qL, kL);
    attn2_softmax<<<BB * NH * MM, 256, 0, stream>>>(qL, kL, x2);
    // 4. attn3v FIRST (frees k/vT = all of d_out for pinv scratch)
    //    4 waves/block (j-split pairs), XCD-pinned per bh
    attn3v_mfma<<<256, 256, 0, stream>>>(qL, k, vT, t1);
    // 5. pinv scalars + z0/x2 pairs (rowmax of softmax == 1 analytically)
    init_scal<<<1, 64, 0, stream>>>(scal);
    csum_max<<<BB * NH, 256, 0, stream>>>(x2, scal);
    z_init_split<<<(int)(SZ_M2 / (256 * 8)), 256, 0, stream>>>(
        x2, scal, x2Ah, x2Al,
        zPair[0][0], zPair[0][1], zPair[0][2], zPair[0][3]);
    // 6. Newton-Schulz pinv, split-precision MFMA (eye7 fused into GEMM1)
    int cur = 0;
    for (int it = 0; it < 6; it++) {
        int nxt = cur ^ 1;
        // bufA = x2 @ z  (A-pairs); bufB^T = (7I - bufA)^T  (BT-pairs)
        bgemm_pair<<<dim3(4, 4, BB * NH), 256, 0, stream>>>(
            x2Ah, x2Al, zPair[cur][2], zPair[cur][3],
            bufAh, bufAl, bufBTh, bufBTl, nullptr,
            1.f, 0.f, -1.f, 7.f, 1 | 2);
        // z2 = 15I - bufA @ bufB -> BT-pairs
        bgemm_pair<<<dim3(4, 4, BB * NH), 256, 0, stream>>>(
            bufAh, bufAl, bufBTh, bufBTl,
            nullptr, nullptr, z2BTh, z2BTl, nullptr,
            -1.f, 15.f, 1.f, 0.f, 2);
        // bufB2 = 13I - bufA @ z2 -> BT-pairs (overwrite bufBT)
        bgemm_pair<<<dim3(4, 4, BB * NH), 256, 0, stream>>>(
            bufAh, bufAl, z2BTh, z2BTl,
            nullptr, nullptr, bufBTh, bufBTl, nullptr,
            -1.f, 13.f, 1.f, 0.f, 2);
        // z_next = 0.25 z @ bufB2; last iteration needs only fp32 (zf)
        int fl = (it == 5) ? 4 : (1 | 2);
        bgemm_pair<<<dim3(4, 4, BB * NH), 256, 0, stream>>>(
            zPair[cur][0], zPair[cur][1], bufBTh, bufBTl,
            zPair[nxt][0], zPair[nxt][1], zPair[nxt][2], zPair[nxt][3],
            zf, 0.25f, 0.f, 1.f, 0.f, fl);
        cur = nxt;
    }
    // 7. t2t = (z @ t1)^T in bf16 [bh][64][256]
    bgemm_t2t<<<dim3(1, 4, BB * NH), 256, 0, stream>>>(zf, t1, t2t);
    // 7b. kL -> bf16 (over dead t1) for attn1 B-fragments
    kl_to_bf16<<<(int)(SZ_L / (256 * 4)), 256, 0, stream>>>(kL, kl16);
    // 8. oh = softmax(q kL^T) @ t2 + conv(v)   (conv fused; q dead after)
    attn1_mfma<<<dim3(NN / 64, BB * NH), 256, 0, stream>>>(q, kl16, t2t, v, cw, oh);
    // 9. out = oh @ (WoutH + WoutL) + bout (overwrites d_out; scratch dead)
    split_wT<<<(DIM * DIM) / 256, 256, 0, stream>>>(Wout, woh, wol, DIM);
    gemm_out_mfma<<<1024, 256, 0, stream>>>(oh, woh, wol, bout, out);

    (void)in_sizes; (void)n_in; (void)ws_size;
}

// Round 12
// 1000.629 us; speedup vs baseline: 1.3169x; 1.0045x over previous
//
#include <hip/hip_runtime.h>
#include <hip/hip_bf16.h>
#include <math.h>

// Problem constants
#define BB 4
#define NH 8
#define NN 8192
#define DD 64
#define MM 256
#define LG 32
#define DIM 512
#define K3 1536
#define KER 33

typedef __hip_bfloat16 bf16;
typedef __attribute__((ext_vector_type(8))) short bf16x8;
typedef __attribute__((ext_vector_type(4))) float f32x4;

__device__ __forceinline__ float b2f(bf16 x) { return __bfloat162float(x); }
__device__ __forceinline__ bf16 f2b(float x) { return __float2bfloat16(x); }
__device__ __forceinline__ short f2bs(float x) { bf16 h = __float2bfloat16(x); return *reinterpret_cast<short*>(&h); }
__device__ __forceinline__ float bsf(short s) { return __uint_as_float(((unsigned int)(unsigned short)s) << 16); }
// bf16-pair unpack from a uint32 (lo short = first element)
__device__ __forceinline__ float blo(unsigned int u) { return __uint_as_float(u << 16); }
__device__ __forceinline__ float bhi(unsigned int u) { return __uint_as_float(u & 0xffff0000u); }

// async global->LDS, 16B per lane (dest must be linear: base + lane*16)
__device__ __forceinline__ void g2lds16(const void* g, void* l) {
    __builtin_amdgcn_global_load_lds(
        (const __attribute__((address_space(1))) unsigned int*)g,
        (__attribute__((address_space(3))) unsigned int*)l, 16, 0, 0);
}

// diagnostic fallback: zero the output
__global__ void zero_out(float* __restrict__ o) {
    o[(size_t)blockIdx.x * 256 + threadIdx.x] = 0.f;
}

// ---------------------------------------------------------------------------
// split fp32 -> bf16 hi + bf16 lo (residual), 8 elems/thread, 16B stores
__global__ void split_x(const float* __restrict__ x, short* __restrict__ xh,
                        short* __restrict__ xl) {
    size_t i = ((size_t)blockIdx.x * 256 + threadIdx.x) * 8;
    const float4* xp = (const float4*)(x + i);
    float4 v0 = xp[0], v1 = xp[1];
    float vv[8] = {v0.x, v0.y, v0.z, v0.w, v1.x, v1.y, v1.z, v1.w};
    short hb[8], lb[8];
#pragma unroll
    for (int u = 0; u < 8; u++) {
        bf16 h = f2b(vv[u]);
        hb[u] = *(short*)&h;
        lb[u] = f2bs(vv[u] - b2f(h));
    }
    *(uint4*)(xh + i) = *(uint4*)hb;
    *(uint4*)(xl + i) = *(uint4*)lb;
}

// split + transpose weight: W[k][n] fp32 -> wh/wl [n][K=512] bf16
__global__ void split_wT(const float* __restrict__ W, short* __restrict__ wh,
                         short* __restrict__ wl, int Nn) {
    int idx = blockIdx.x * 256 + threadIdx.x;   // n*512 + k
    int k = idx & 511, n = idx >> 9;
    float v = W[(size_t)k * Nn + n];
    bf16 h = f2b(v);
    wh[idx] = *(short*)&h;
    wl[idx] = f2bs(v - b2f(h));
}

// ---------------------------------------------------------------------------
// qkv projection via MFMA, split-precision (Xh@Wh + Xl@Wh + Xh@Wl).
// LDS tiles chunk-XOR-swizzled (c' = c ^ ((row>>1)&3)): pre-swizzled global
// source + swizzled fragment read -> 2-way banks (free) instead of 8-way.
__global__ __launch_bounds__(256) void gemm_qkv_mfma(
        const short* __restrict__ xh, const short* __restrict__ xl,
        const short* __restrict__ wh, const short* __restrict__ wl,
        bf16* __restrict__ q, bf16* __restrict__ k, bf16* __restrict__ v) {
    __shared__ short Ah[128 * 32];
    __shared__ short Al[128 * 32];
    __shared__ short Bh[128 * 32];
    __shared__ short Bl[128 * 32];
    int orig = blockIdx.x;
    int wg = (orig & 7) * 384 + (orig >> 3);
    int by = wg / 12, bx = wg - by * 12;
    int rowBase = by * 128, colBase = bx * 128;
    int tid = threadIdx.x;
    int rl = tid >> 2;
    int wave = tid >> 6, lane = tid & 63;
    int ln = lane & 15, quad = lane >> 4;
    int wr = (wave >> 1) * 64, wc = (wave & 1) * 64;
    f32x4 acc[4][4];
#pragma unroll
    for (int mt = 0; mt < 4; mt++)
#pragma unroll
        for (int nt = 0; nt < 4; nt++) acc[mt][nt] = (f32x4){0.f, 0.f, 0.f, 0.f};

    for (int k0 = 0; k0 < DIM; k0 += 32) {
        __syncthreads();
#pragma unroll
        for (int p = 0; p < 2; p++) {
            int r = p * 64 + rl;
            int cs = ((tid & 3) ^ ((r >> 1) & 3)) * 8;   // swizzled global chunk
            size_t ga = (size_t)(rowBase + r) * DIM + k0 + cs;
            size_t gb = (size_t)(colBase + r) * DIM + k0 + cs;
            int lo = r * 32 + (tid & 3) * 8;             // linear LDS dest
            g2lds16(xh + ga, &Ah[lo]);
            g2lds16(xl + ga, &Al[lo]);
            g2lds16(wh + gb, &Bh[lo]);
            g2lds16(wl + gb, &Bl[lo]);
        }
        __syncthreads();
        bf16x8 a_h[4], a_l[4], b_h[4], b_l[4];
#pragma unroll
        for (int mt = 0; mt < 4; mt++) {
            int row = wr + mt * 16 + ln;
            int o = row * 32 + ((quad ^ ((row >> 1) & 3)) * 8);
            a_h[mt] = *(const bf16x8*)&Ah[o];
            a_l[mt] = *(const bf16x8*)&Al[o];
        }
#pragma unroll
        for (int nt = 0; nt < 4; nt++) {
            int row = wc + nt * 16 + ln;
            int o = row * 32 + ((quad ^ ((row >> 1) & 3)) * 8);
            b_h[nt] = *(const bf16x8*)&Bh[o];
            b_l[nt] = *(const bf16x8*)&Bl[o];
        }
#pragma unroll
        for (int mt = 0; mt < 4; mt++)
#pragma unroll
            for (int nt = 0; nt < 4; nt++) {
                acc[mt][nt] = __builtin_amdgcn_mfma_f32_16x16x32_bf16(a_h[mt], b_h[nt], acc[mt][nt], 0, 0, 0);
                acc[mt][nt] = __builtin_amdgcn_mfma_f32_16x16x32_bf16(a_l[mt], b_h[nt], acc[mt][nt], 0, 0, 0);
                acc[mt][nt] = __builtin_amdgcn_mfma_f32_16x16x32_bf16(a_h[mt], b_l[nt], acc[mt][nt], 0, 0, 0);
            }
    }
    int part = colBase >> 9;
    bf16* dst = part == 0 ? q : (part == 1 ? k : v);
    float scale = part == 0 ? 0.125f : 1.0f;
#pragma unroll
    for (int mt = 0; mt < 4; mt++)
#pragma unroll
        for (int nt = 0; nt < 4; nt++)
#pragma unroll
            for (int r = 0; r < 4; r++) {
                int row = rowBase + wr + mt * 16 + quad * 4 + r;
                int col = colBase + wc + nt * 16 + ln;
                int h = (col & 511) >> 6, d = col & 63;
                int b_ = row >> 13, n_ = row & 8191;
                size_t di = ((size_t)(b_ * NH + h) * NN + n_) * DD + d;
                dst[di] = f2b(acc[mt][nt][r] * scale);
            }
}

// out projection via MFMA: oh(bf16) @ (Wh+Wl) + bias -> fp32
__global__ __launch_bounds__(256) void gemm_out_mfma(
        const bf16* __restrict__ A, const short* __restrict__ wh,
        const short* __restrict__ wl, const float* __restrict__ bias,
        float* __restrict__ C) {
    __shared__ short As[128 * 32];
    __shared__ short Bh[128 * 32];
    __shared__ short Bl[128 * 32];
    int orig = blockIdx.x;                       // nwg = 1024
    int wg = (orig & 7) * 128 + (orig >> 3);
    int by = wg >> 2, bx = wg & 3;
    int rowBase = by * 128, colBase = bx * 128;
    int tid = threadIdx.x;
    int rl = tid >> 2;
    int wave = tid >> 6, lane = tid & 63;
    int ln = lane & 15, quad = lane >> 4;
    int wr = (wave >> 1) * 64, wc = (wave & 1) * 64;
    const short* Ab = (const short*)A;
    f32x4 acc[4][4];
#pragma unroll
    for (int mt = 0; mt < 4; mt++)
#pragma unroll
        for (int nt = 0; nt < 4; nt++) acc[mt][nt] = (f32x4){0.f, 0.f, 0.f, 0.f};

    for (int k0 = 0; k0 < DIM; k0 += 32) {
        __syncthreads();
#pragma unroll
        for (int p = 0; p < 2; p++) {
            int r = p * 64 + rl;
            int cs = ((tid & 3) ^ ((r >> 1) & 3)) * 8;
            size_t ga = (size_t)(rowBase + r) * DIM + k0 + cs;
            size_t gb = (size_t)(colBase + r) * DIM + k0 + cs;
            int lo = r * 32 + (tid & 3) * 8;
            g2lds16(Ab + ga, &As[lo]);
            g2lds16(wh + gb, &Bh[lo]);
            g2lds16(wl + gb, &Bl[lo]);
        }
        __syncthreads();
        bf16x8 a[4], b_h[4], b_l[4];
#pragma unroll
        for (int mt = 0; mt < 4; mt++) {
            int row = wr + mt * 16 + ln;
            int o = row * 32 + ((quad ^ ((row >> 1) & 3)) * 8);
            a[mt] = *(const bf16x8*)&As[o];
        }
#pragma unroll
        for (int nt = 0; nt < 4; nt++) {
            int row = wc + nt * 16 + ln;
            int o = row * 32 + ((quad ^ ((row >> 1) & 3)) * 8);
            b_h[nt] = *(const bf16x8*)&Bh[o];
            b_l[nt] = *(const bf16x8*)&Bl[o];
        }
#pragma unroll
        for (int mt = 0; mt < 4; mt++)
#pragma unroll
            for (int nt = 0; nt < 4; nt++) {
                acc[mt][nt] = __builtin_amdgcn_mfma_f32_16x16x32_bf16(a[mt], b_h[nt], acc[mt][nt], 0, 0, 0);
                acc[mt][nt] = __builtin_amdgcn_mfma_f32_16x16x32_bf16(a[mt], b_l[nt], acc[mt][nt], 0, 0, 0);
            }
    }
#pragma unroll
    for (int mt = 0; mt < 4; mt++)
#pragma unroll
        for (int nt = 0; nt < 4; nt++)
#pragma unroll
            for (int r = 0; r < 4; r++) {
                int row = rowBase + wr + mt * 16 + quad * 4 + r;
                int col = colBase + wc + nt * 16 + ln;
                C[(size_t)row * DIM + col] = acc[mt][nt][r] + bias[col];
            }
}

// ---------------------------------------------------------------------------
// Batched split-precision MFMA GEMM for the pinv chain.
// val = scale*(A@B) + alpha*I.  A-layout/fp32 outputs get val;
// B^T-layout output gets scaleB*val + alphaB*I (lets eye7 fuse into GEMM1).
// 64x64 tile, 4 waves, grid dim3(4,4,32) = 512 blocks (2 blocks/CU).
// Chunk-XOR LDS swizzle as in gemm_qkv.
__global__ __launch_bounds__(256) void bgemm_pair(
        const short* __restrict__ Ah, const short* __restrict__ Al,
        const short* __restrict__ Bh, const short* __restrict__ Bl,
        short* __restrict__ oAh, short* __restrict__ oAl,
        short* __restrict__ oBh, short* __restrict__ oBl,
        float* __restrict__ oF, float scale, float alpha,
        float scaleB, float alphaB, int flags) {
    __shared__ short sAh[64 * 32];
    __shared__ short sAl[64 * 32];
    __shared__ short sBh[64 * 32];
    __shared__ short sBl[64 * 32];
    int bat = blockIdx.z;
    int rowBase = blockIdx.y * 64;    // 0..192
    int colBase = blockIdx.x * 64;    // 0..192
    const size_t MB = (size_t)bat * (MM * MM);
    int tid = threadIdx.x;
    int rl = tid >> 2;                // rl 0..63
    int wave = tid >> 6, lane = tid & 63;
    int ln = lane & 15, quad = lane >> 4;
    int wr = (wave >> 1) * 32, wc = (wave & 1) * 32;
    f32x4 acc[2][2];
#pragma unroll
    for (int mt = 0; mt < 2; mt++)
#pragma unroll
        for (int nt = 0; nt < 2; nt++) acc[mt][nt] = (f32x4){0.f, 0.f, 0.f, 0.f};

    for (int k0 = 0; k0 < MM; k0 += 32) {
        __syncthreads();
        {
            int cs = ((tid & 3) ^ ((rl >> 1) & 3)) * 8;
            size_t ga = MB + (size_t)(rowBase + rl) * MM + k0 + cs;
            size_t gb = MB + (size_t)(colBase + rl) * MM + k0 + cs;
            int lo = rl * 32 + (tid & 3) * 8;
            g2lds16(Ah + ga, &sAh[lo]);
            g2lds16(Al + ga, &sAl[lo]);
            g2lds16(Bh + gb, &sBh[lo]);
            g2lds16(Bl + gb, &sBl[lo]);
        }
        __syncthreads();
        bf16x8 a_h[2], a_l[2], b_h[2], b_l[2];
#pragma unroll
        for (int mt = 0; mt < 2; mt++) {
            int row = wr + mt * 16 + ln;
            int o = row * 32 + ((quad ^ ((row >> 1) & 3)) * 8);
            a_h[mt] = *(const bf16x8*)&sAh[o];
            a_l[mt] = *(const bf16x8*)&sAl[o];
        }
#pragma unroll
        for (int nt = 0; nt < 2; nt++) {
            int row = wc + nt * 16 + ln;
            int o = row * 32 + ((quad ^ ((row >> 1) & 3)) * 8);
            b_h[nt] = *(const bf16x8*)&sBh[o];
            b_l[nt] = *(const bf16x8*)&sBl[o];
        }
#pragma unroll
        for (int mt = 0; mt < 2; mt++)
#pragma unroll
            for (int nt = 0; nt < 2; nt++) {
                acc[mt][nt] = __builtin_amdgcn_mfma_f32_16x16x32_bf16(a_h[mt], b_h[nt], acc[mt][nt], 0, 0, 0);
                acc[mt][nt] = __builtin_amdgcn_mfma_f32_16x16x32_bf16(a_l[mt], b_h[nt], acc[mt][nt], 0, 0, 0);
                acc[mt][nt] = __builtin_amdgcn_mfma_f32_16x16x32_bf16(a_h[mt], b_l[nt], acc[mt][nt], 0, 0, 0);
            }
    }
#pragma unroll
    for (int mt = 0; mt < 2; mt++)
#pragma unroll
        for (int nt = 0; nt < 2; nt++) {
            short bh4[4], bl4[4];
            int col = colBase + wc + nt * 16 + ln;
            int row0 = rowBase + wr + mt * 16 + quad * 4;
#pragma unroll
            for (int r = 0; r < 4; r++) {
                int row = row0 + r;
                float val = scale * acc[mt][nt][r];
                if (row == col) val += alpha;
                if (flags & 4) oF[MB + (size_t)row * MM + col] = val;
                if (flags & 1) {
                    short vh = f2bs(val);
                    oAh[MB + (size_t)row * MM + col] = vh;
                    oAl[MB + (size_t)row * MM + col] = f2bs(val - bsf(vh));
                }
                float bv = scaleB * val;
                if (row == col) bv += alphaB;
                short bvh = f2bs(bv);
                bh4[r] = bvh; bl4[r] = f2bs(bv - bsf(bvh));
            }
            if (flags & 2) {
                size_t o = MB + (size_t)col * MM + row0;
                *(uint2*)&oBh[o] = *(uint2*)bh4;
                *(uint2*)&oBl[o] = *(uint2*)bl4;
            }
        }
}

// z0 = x2^T / (colmax + 1e-12) -> zA pairs + zBT pairs; also x2 -> A pairs.
// (rowmax of a softmax = 1 analytically, so scal[0] holds only colmax.)
__global__ void z_init_split(const float* __restrict__ x2, const float* __restrict__ scal,
                             short* __restrict__ x2Ah, short* __restrict__ x2Al,
                             short* __restrict__ zAh, short* __restrict__ zAl,
                             short* __restrict__ zBh, short* __restrict__ zBl) {
    size_t base = ((size_t)blockIdx.x * 256 + threadIdx.x) * 8;
    float inv = 1.0f / (scal[0] + 1e-12f);
    int c0 = (int)(base & 255);
    int r = (int)((base >> 8) & 255);
    size_t MB = (base >> 16) << 16;
    const float4* xp = (const float4*)(x2 + base);
    float4 v0 = xp[0], v1 = xp[1];
    float vv[8] = {v0.x, v0.y, v0.z, v0.w, v1.x, v1.y, v1.z, v1.w};
    short ho[8], lo_[8], h2[8], l2[8];
#pragma unroll
    for (int u = 0; u < 8; u++) {
        short xh = f2bs(vv[u]);
        h2[u] = xh; l2[u] = f2bs(vv[u] - bsf(xh));
        float zv = vv[u] * inv;
        short zh = f2bs(zv);
        ho[u] = zh; lo_[u] = f2bs(zv - bsf(zh));
    }
    *(uint4*)&x2Ah[base] = *(uint4*)h2;
    *(uint4*)&x2Al[base] = *(uint4*)l2;
    *(uint4*)&zBh[base] = *(uint4*)ho;
    *(uint4*)&zBl[base] = *(uint4*)lo_;
    // A layout: zA[bat][r][c] = z[r][c] = x2[bat][c][r]*inv  (strided read)
#pragma unroll
    for (int u = 0; u < 8; u++) {
        float v = x2[MB + (size_t)(c0 + u) * MM + r] * inv;
        short vh = f2bs(v);
        ho[u] = vh; lo_[u] = f2bs(v - bsf(vh));
    }
    *(uint4*)&zAh[base] = *(uint4*)ho;
    *(uint4*)&zAl[base] = *(uint4*)lo_;
}

// t2t = (z @ t1)^T per batch, stored bf16 [bh][d=64][landmark=256]
__global__ void bgemm_t2t(const float* __restrict__ A, const float* __restrict__ B,
                          short* __restrict__ T) {
    __shared__ float As[16][64];
    __shared__ float Bs[16][64];
    int bat = blockIdx.z;
    const float* Ab = A + (size_t)bat * MM * MM;   // z [256,256]
    const float* Bb = B + (size_t)bat * MM * DD;   // t1 [256,64]
    short* Tb = T + (size_t)bat * DD * MM;
    int tid = threadIdx.x;
    int rowBase = blockIdx.y * 64;
    int ty = tid >> 4, tx = tid & 15;
    float acc[4][4] = {};
    for (int k0 = 0; k0 < MM; k0 += 16) {
        for (int idx = tid; idx < 64 * 16; idx += 256) {
            int r = idx >> 4, c = idx & 15;
            As[c][r] = Ab[(size_t)(rowBase + r) * MM + k0 + c];
        }
        for (int idx = tid; idx < 16 * 64; idx += 256) {
            int r = idx >> 6, c = idx & 63;
            Bs[r][c] = Bb[(size_t)(k0 + r) * DD + c];
        }
        __syncthreads();
#pragma unroll
        for (int kk = 0; kk < 16; kk++) {
            float a[4], b[4];
#pragma unroll
            for (int i = 0; i < 4; i++) a[i] = As[kk][ty * 4 + i];
#pragma unroll
            for (int j = 0; j < 4; j++) b[j] = Bs[kk][tx * 4 + j];
#pragma unroll
            for (int i = 0; i < 4; i++)
#pragma unroll
                for (int j = 0; j < 4; j++) acc[i][j] += a[i] * b[j];
        }
        __syncthreads();
    }
#pragma unroll
    for (int i = 0; i < 4; i++) {
        int r = rowBase + ty * 4 + i;     // landmark
#pragma unroll
        for (int j = 0; j < 4; j++) {
            int c = tx * 4 + j;           // d
            Tb[(size_t)c * MM + r] = f2bs(acc[i][j]);
        }
    }
}

// ---------------------------------------------------------------------------
// landmark means: qL/kL[bh,mi,d] = mean over 32 tokens (bf16 in, fp32 out)
__global__ void landmark_means(const bf16* __restrict__ q, const bf16* __restrict__ k,
                               float* __restrict__ qL, float* __restrict__ kL) {
    int idx = blockIdx.x * 256 + threadIdx.x;   // (bh*256 + mi)*64 + d
    int d = idx & 63;
    int mi = (idx >> 6) & 255;
    int bh = idx >> 14;
    const bf16* qp = q + ((size_t)bh * NN + mi * LG) * DD + d;
    const bf16* kp = k + ((size_t)bh * NN + mi * LG) * DD + d;
    float sq = 0.f, sk = 0.f;
#pragma unroll
    for (int j = 0; j < LG; j++) { sq += b2f(qp[(size_t)j * DD]); sk += b2f(kp[(size_t)j * DD]); }
    qL[idx] = sq * (1.f / LG);
    kL[idx] = sk * (1.f / LG);
}

// kL fp32 -> bf16 copy (for attn1 B-fragments)
__global__ void kl_to_bf16(const float* __restrict__ kL, short* __restrict__ kl16) {
    size_t i = ((size_t)blockIdx.x * 256 + threadIdx.x) * 4;
    float4 v = *(const float4*)(kL + i);
    short o[4] = {f2bs(v.x), f2bs(v.y), f2bs(v.z), f2bs(v.w)};
    *(uint2*)&kl16[i] = *(uint2*)o;
}

// attn2 = softmax(qL @ kL^T), one block per row (all fp32)
__global__ void attn2_softmax(const float* __restrict__ qL, const float* __restrict__ kL,
                              float* __restrict__ x2) {
    __shared__ float qs[64];
    __shared__ float red[256];
    int bh = blockIdx.x >> 8, i = blockIdx.x & 255;
    int t = threadIdx.x;
    if (t < 64) qs[t] = qL[((size_t)bh * MM + i) * DD + t];
    __syncthreads();
    const float4* kp = (const float4*)(kL + ((size_t)bh * MM + t) * DD);
    float l = 0.f;
#pragma unroll
    for (int u = 0; u < 16; u++) {
        float4 kv = kp[u];
        l += qs[u*4+0]*kv.x + qs[u*4+1]*kv.y + qs[u*4+2]*kv.z + qs[u*4+3]*kv.w;
    }
    red[t] = l; __syncthreads();
    for (int s = 128; s > 0; s >>= 1) { if (t < s) red[t] = fmaxf(red[t], red[t + s]); __syncthreads(); }
    float mx = red[0]; __syncthreads();
    float e = __expf(l - mx);
    red[t] = e; __syncthreads();
    for (int s = 128; s > 0; s >>= 1) { if (t < s) red[t] += red[t + s]; __syncthreads(); }
    x2[((size_t)bh * MM + i) * MM + t] = e / red[0];
}

__global__ void init_scal(float* scal) {
    if (threadIdx.x == 0) { scal[0] = 0.f; scal[1] = 0.f; }
}

// max over (bh,j) of sum_i |x|  -> scal[0]   (rowmax of softmax == 1)
__global__ void csum_max(const float* __restrict__ x2, float* scal) {
    __shared__ float red[256];
    int t = threadIdx.x;
    const float* xp = x2 + (size_t)blockIdx.x * MM * MM;
    float s = 0.f;
    for (int i = 0; i < MM; i++) s += fabsf(xp[(size_t)i * MM + t]);
    red[t] = s; __syncthreads();
    for (int st = 128; st > 0; st >>= 1) { if (t < st) red[t] = fmaxf(red[t], red[t + st]); __syncthreads(); }
    if (t == 0) atomicMax((unsigned int*)&scal[0], __float_as_uint(red[0]));
}

// ---------------------------------------------------------------------------
// v transpose: vT[bh][d][n] <- v[bh][n][d].
__global__ void transpose_v(const bf16* __restrict__ v, bf16* __restrict__ vT) {
    int gw = blockIdx.x * 4 + (threadIdx.x >> 6);   // global wave id
    int lane = threadIdx.x & 63;                     // = d
    int bh = gw >> 8;
    int c  = gw & 255;                               // n-chunk (32 tokens)
    const bf16* vb = v + ((size_t)bh * NN + c * 32) * DD + lane;
    unsigned short buf[32];
#pragma unroll
    for (int i = 0; i < 32; i++) buf[i] = *(const unsigned short*)(vb + (size_t)i * DD);
    bf16* dst = vT + ((size_t)bh * DD + lane) * NN + c * 32;
#pragma unroll
    for (int u = 0; u < 4; u++)
        *(uint4*)(dst + u * 8) = *(uint4*)&buf[u * 8];
}

// ---------------------------------------------------------------------------
// MFMA flash attn3v: t1 = softmax(qL @ k^T over n) @ v
// 4 waves / 32 landmark rows per block; wave-pairs split the j-loop
// (pair 0 = even 128-token chunks, pair 1 = odd), private ks/vs per pair,
// exact flash-combine merge at the end. Grid 256 blocks (8 rb x 32 bh),
// XCD-pinned: all 8 row-blocks of one bh map to the same XCD (g%8).
#define NJ 128
#define KS2 72
#define VS2 136
#define PS2 136
__global__ __launch_bounds__(256) void attn3v_mfma(
        const float* __restrict__ qL, const bf16* __restrict__ k,
        const bf16* __restrict__ vT, float* __restrict__ t1) {
    __shared__ short ks[2][NJ * KS2];       // 36864 B  [pair][j][d]
    __shared__ short vs[2][DD * VS2];       // 34816 B  [pair][d][j]
    __shared__ short ps[4][16 * PS2];       // 17408 B  per-wave P [row][j]
    __shared__ float mb[128 * 25];          // 12800 B  pair-B merge state
    int g = blockIdx.x;
    int c = g & 7, t = g >> 3;
    int bh = c + 8 * (t >> 3);
    int r0 = (t & 7) * 32;
    int tid = threadIdx.x;
    int wave = tid >> 6, lane = tid & 63;
    int pair = wave >> 1, wv = wave & 1;
    int ptid = tid & 127;
    int ln = lane & 15, quad = lane >> 4;
    int m = r0 + wv * 16 + ln;
    const float* qrow = qL + ((size_t)bh * MM + m) * DD;
    bf16x8 a0, a1;
#pragma unroll
    for (int u = 0; u < 8; u++) {
        ((short*)&a0)[u] = f2bs(qrow[quad * 8 + u]);
        ((short*)&a1)[u] = f2bs(qrow[32 + quad * 8 + u]);
    }
    const uint4* kg = (const uint4*)(k + (size_t)bh * NN * DD);
    const uint4* vg = (const uint4*)(vT + (size_t)bh * DD * NN);
    float mrow[4], lrow[4];
    f32x4 o[4];
#pragma unroll
    for (int r = 0; r < 4; r++) { mrow[r] = -1e30f; lrow[r] = 0.f; }
#pragma unroll
    for (int ct = 0; ct < 4; ct++) o[ct] = (f32x4){0.f, 0.f, 0.f, 0.f};
    short* pw = &ps[wave][0];
    short* ksp = &ks[pair][0];
    short* vsp = &vs[pair][0];

    for (int it = 0; it < NN / (2 * NJ); it++) {
        int j0 = (2 * it + pair) * NJ;
        __syncthreads();
#pragma unroll
        for (int s = 0; s < 8; s++) {
            int idx = s * 128 + ptid;
            int row = idx >> 3, c8 = idx & 7;
            uint4 pk = kg[(size_t)(j0 + row) * 8 + c8];
            *(uint4*)&ksp[row * KS2 + c8 * 8] = pk;
        }
#pragma unroll
        for (int s = 0; s < 8; s++) {
            int idx = s * 128 + ptid;
            int row = idx >> 4, c8 = idx & 15;
            uint4 pv = vg[(size_t)row * (NN / 8) + (j0 / 8) + c8];
            *(uint4*)&vsp[row * VS2 + c8 * 8] = pv;
        }
        __syncthreads();
        f32x4 s[8];
#pragma unroll
        for (int ct = 0; ct < 8; ct++) {
            const short* kp = &ksp[(ct * 16 + ln) * KS2 + quad * 8];
            bf16x8 b0 = *(const bf16x8*)kp;
            bf16x8 b1 = *(const bf16x8*)(kp + 32);
            f32x4 cc = {0.f, 0.f, 0.f, 0.f};
            cc = __builtin_amdgcn_mfma_f32_16x16x32_bf16(a0, b0, cc, 0, 0, 0);
            cc = __builtin_amdgcn_mfma_f32_16x16x32_bf16(a1, b1, cc, 0, 0, 0);
            s[ct] = cc;
        }
#pragma unroll
        for (int r = 0; r < 4; r++) {
            float v = -1e30f;
#pragma unroll
            for (int ct = 0; ct < 8; ct++) v = fmaxf(v, s[ct][r]);
            v = fmaxf(v, __shfl_xor(v, 1));
            v = fmaxf(v, __shfl_xor(v, 2));
            v = fmaxf(v, __shfl_xor(v, 4));
            v = fmaxf(v, __shfl_xor(v, 8));
            float mn = fmaxf(mrow[r], v);
            float alpha = __expf(mrow[r] - mn);
            mrow[r] = mn;
            float psum = 0.f;
#pragma unroll
            for (int ct = 0; ct < 8; ct++) { float e = __expf(s[ct][r] - mn); s[ct][r] = e; psum += e; }
            lrow[r] = lrow[r] * alpha + psum;
#pragma unroll
            for (int c2 = 0; c2 < 4; c2++) o[c2][r] *= alpha;
        }
#pragma unroll
        for (int ct = 0; ct < 8; ct++)
#pragma unroll
            for (int r = 0; r < 4; r++)
                pw[(quad * 4 + r) * PS2 + ct * 16 + ln] = f2bs(s[ct][r]);
#pragma unroll
        for (int kstep = 0; kstep < 4; kstep++) {
            bf16x8 pa = *(const bf16x8*)&pw[ln * PS2 + kstep * 32 + quad * 8];
#pragma unroll
            for (int ct = 0; ct < 4; ct++) {
                bf16x8 pb = *(const bf16x8*)&vsp[(ct * 16 + ln) * VS2 + kstep * 32 + quad * 8];
                o[ct] = __builtin_amdgcn_mfma_f32_16x16x32_bf16(pa, pb, o[ct], 0, 0, 0);
            }
        }
    }
    // flash-combine: pair 1 publishes its (m,l,O); pair 0 merges exactly.
    __syncthreads();
    if (wave >= 2) {
        float* mp = &mb[(tid - 128) * 25];
#pragma unroll
        for (int r = 0; r < 4; r++) { mp[r] = mrow[r]; mp[4 + r] = lrow[r]; }
#pragma unroll
        for (int ct = 0; ct < 4; ct++)
#pragma unroll
            for (int r = 0; r < 4; r++) mp[8 + ct * 4 + r] = o[ct][r];
    }
    __syncthreads();
    if (wave < 2) {
        const float* mp = &mb[(wave * 64 + lane) * 25];
#pragma unroll
        for (int r = 0; r < 4; r++) {
            float mB = mp[r], lB = mp[4 + r];
            float mn = fmaxf(mrow[r], mB);
            float eA = __expf(mrow[r] - mn);
            float eB = __expf(mB - mn);
            lrow[r] = lrow[r] * eA + lB * eB;
#pragma unroll
            for (int ct = 0; ct < 4; ct++)
                o[ct][r] = o[ct][r] * eA + mp[8 + ct * 4 + r] * eB;
        }
#pragma unroll
        for (int r = 0; r < 4; r++) {
            float l = lrow[r];
            l += __shfl_xor(l, 1);
            l += __shfl_xor(l, 2);
            l += __shfl_xor(l, 4);
            l += __shfl_xor(l, 8);
            lrow[r] = 1.0f / l;
        }
#pragma unroll
        for (int ct = 0; ct < 4; ct++)
#pragma unroll
            for (int r = 0; r < 4; r++) {
                int row = r0 + wv * 16 + quad * 4 + r;
                t1[((size_t)bh * MM + row) * DD + ct * 16 + ln] = o[ct][r] * lrow[r];
            }
    }
}

// ---------------------------------------------------------------------------
// MFMA fused attn1 + depthwise conv residual:
// oh[b,i,h*64+d] = softmax(q_i kL^T) @ t2 + conv(v)
// kl16/t2t are L2-resident -> B-fragments read directly from global.
// Conv v-window stored TRANSPOSED vt[d][col] so window reads are b64
// (9 per nt-group instead of 36 scalar u16). LDS 47.6 KB -> 3 blocks/CU.
#define T2S 264
#define VTS 108
__global__ __launch_bounds__(256, 3) void attn1_mfma(
        const bf16* __restrict__ q, const short* __restrict__ kl16,
        const short* __restrict__ t2t, const bf16* __restrict__ v,
        const float* __restrict__ cw, bf16* __restrict__ oh) {
    __shared__ short ps1[4][16 * T2S];      // 33792 B
    __shared__ short vt[64 * VTS];          // 13824 B  vt[d][col], col=n-16..n+79
    int bh = blockIdx.y;
    int n0 = blockIdx.x * 64;
    int tid = threadIdx.x;
    int b_ = bh >> 3, h = bh & 7;
    // stage conv v window transposed: read v[gn][d] coalesced, write vt[d][row]
    const bf16* vb = v + (size_t)bh * NN * DD;
    for (int idx = tid; idx < 96 * 8; idx += 256) {
        int row = idx >> 3, c8 = (idx & 7) * 8;
        int gn = n0 - 16 + row;
        uint4 pv;
        pv.x = pv.y = pv.z = pv.w = 0u;
        if (gn >= 0 && gn < NN) pv = *(const uint4*)(vb + (size_t)gn * DD + c8);
        short tmp[8];
        *(uint4*)tmp = pv;
#pragma unroll
        for (int u = 0; u < 8; u++) vt[(c8 + u) * VTS + row] = tmp[u];
    }
    int wave = tid >> 6, lane = tid & 63;
    int ln = lane & 15, quad = lane >> 4;
    int m = n0 + wave * 16 + ln;
    const bf16* qrow = q + ((size_t)bh * NN + m) * DD;
    bf16x8 a0 = *(const bf16x8*)(qrow + quad * 8);
    bf16x8 a1 = *(const bf16x8*)(qrow + 32 + quad * 8);
    // QK^T: B-fragments straight from kl16 (L2-hot, coalesced 2KB/wave-tile)
    const short* klb = kl16 + (size_t)bh * MM * DD;
    f32x4 acc[16];
#pragma unroll
    for (int nt = 0; nt < 16; nt++) {
        const short* kp = klb + (nt * 16 + ln) * DD + quad * 8;
        bf16x8 b0 = *(const bf16x8*)kp;
        bf16x8 b1 = *(const bf16x8*)(kp + 32);
        f32x4 c = {0.f, 0.f, 0.f, 0.f};
        c = __builtin_amdgcn_mfma_f32_16x16x32_bf16(a0, b0, c, 0, 0, 0);
        c = __builtin_amdgcn_mfma_f32_16x16x32_bf16(a1, b1, c, 0, 0, 0);
        acc[nt] = c;
    }
    float inv[4];
#pragma unroll
    for (int r = 0; r < 4; r++) {
        float vx = -1e30f;
#pragma unroll
        for (int nt = 0; nt < 16; nt++) vx = fmaxf(vx, acc[nt][r]);
        vx = fmaxf(vx, __shfl_xor(vx, 1));
        vx = fmaxf(vx, __shfl_xor(vx, 2));
        vx = fmaxf(vx, __shfl_xor(vx, 4));
        vx = fmaxf(vx, __shfl_xor(vx, 8));
        float s = 0.f;
#pragma unroll
        for (int nt = 0; nt < 16; nt++) { float e = __expf(acc[nt][r] - vx); acc[nt][r] = e; s += e; }
        s += __shfl_xor(s, 1);
        s += __shfl_xor(s, 2);
        s += __shfl_xor(s, 4);
        s += __shfl_xor(s, 8);
        inv[r] = 1.0f / s;
    }
    short* pw = &ps1[wave][0];
#pragma unroll
    for (int nt = 0; nt < 16; nt++)
#pragma unroll
        for (int r = 0; r < 4; r++)
            pw[(quad * 4 + r) * T2S + nt * 16 + ln] = f2bs(acc[nt][r]);
    __syncthreads();
    // PV: B-fragments straight from t2t [bh][d][landmark] (L2-hot)
    const short* t2b = t2t + (size_t)bh * DD * MM;
    f32x4 o[4];
#pragma unroll
    for (int nt = 0; nt < 4; nt++) o[nt] = (f32x4){0.f, 0.f, 0.f, 0.f};
#pragma unroll
    for (int ks = 0; ks < 8; ks++) {
        bf16x8 pa = *(const bf16x8*)&pw[ln * T2S + ks * 32 + quad * 8];
#pragma unroll
        for (int nt = 0; nt < 4; nt++) {
            bf16x8 pb = *(const bf16x8*)(t2b + (nt * 16 + ln) * MM + ks * 32 + quad * 8);
            o[nt] = __builtin_amdgcn_mfma_f32_16x16x32_bf16(pa, pb, o[nt], 0, 0, 0);
        }
    }
    // epilogue: add conv residual from vt (b64 window loads), write oh
    const float* wrow = cw + h * KER;
    int lbase = wave * 16 + quad * 4;    // output r=0's window start col
#pragma unroll
    for (int nt = 0; nt < 4; nt++) {
        int d = nt * 16 + ln;
        const short* vrow = &vt[d * VTS + lbase];
        float win[36];
#pragma unroll
        for (int j4 = 0; j4 < 9; j4++) {
            uint2 w4 = *(const uint2*)(vrow + j4 * 4);
            win[j4 * 4 + 0] = blo(w4.x); win[j4 * 4 + 1] = bhi(w4.x);
            win[j4 * 4 + 2] = blo(w4.y); win[j4 * 4 + 3] = bhi(w4.y);
        }
        float res[4] = {0.f, 0.f, 0.f, 0.f};
#pragma unroll
        for (int t = 0; t < KER; t++) {
            float wt = wrow[t];
#pragma unroll
            for (int r = 0; r < 4; r++) res[r] += wt * win[r + t];
        }
#pragma unroll
        for (int r = 0; r < 4; r++) {
            int row = n0 + lbase + r;
            oh[((size_t)(b_ * NN + row)) * DIM + h * 64 + d] = f2b(o[nt][r] * inv[r] + res[r]);
        }
    }
}

// ---------------------------------------------------------------------------

extern "C" void kernel_launch(void* const* d_in, const int* in_sizes, int n_in,
                              void* d_out, int out_size, void* d_ws, size_t ws_size,
                              hipStream_t stream) {
    const float* x    = (const float*)d_in[0];
    const float* Wqkv = (const float*)d_in[1];
    const float* Wout = (const float*)d_in[2];
    const float* bout = (const float*)d_in[3];
    const float* cw   = (const float*)d_in[4];
    float* out = (float*)d_out;

    const size_t SZ_QKV = (size_t)BB * NH * NN * DD;   // 16,777,216 elems
    const size_t SZ_L   = (size_t)BB * NH * MM * DD;   // 524,288
    const size_t SZ_M2  = (size_t)BB * NH * MM * MM;   // 2,097,152

    // --- workspace plumbing (unchanged footprint) ---
    char* p = (char*)d_ws;
    bf16* q    = (bf16*)p;  p += SZ_QKV * 2;    // 32 MB
    bf16* v    = (bf16*)p;  p += SZ_QKV * 2;    // 32 MB
    float* x2   = (float*)p; p += SZ_M2 * 4;    // 8 MB each
    float* zf   = (float*)p; p += SZ_M2 * 4;    // final fp32 z lives here
    float* z2r  = (float*)p; p += SZ_M2 * 4;    // region reused for x2 pairs
    float* bAr  = (float*)p; p += SZ_M2 * 4;    // region reused for bufA pairs
    float* bBr  = (float*)p; p += SZ_M2 * 4;    // region for wqh/wql
    float* qL   = (float*)p; p += SZ_L * 4;     // 2 MB each
    float* kL   = (float*)p; p += SZ_L * 4;
    float* t1   = (float*)p; p += SZ_L * 4;
    short* t2t  = (short*)p; p += SZ_L * 4;
    float* scal = (float*)p; p += 2 * 4;
    size_t need = (size_t)(p - (char*)d_ws);
    bf16* k  = (bf16*)d_out;                     // first 32 MB of out buffer
    bf16* vT = (bf16*)d_out + SZ_QKV;            // second 32 MB of out buffer
    bf16* oh = (bf16*)x2;                        // 32 MB over dead pinv region

    // split-precision scratch for projections (aliased, dead at use time):
    short* xh  = (short*)x2;                     // 32 MB over x2..bAr
    short* xl  = (short*)vT;                     // vT half of d_out
    short* wqh = (short*)bBr;                    // 1.5 MB
    short* wql = (short*)bBr + (size_t)K3 * DIM;
    short* woh = (short*)q;                      // q dead after attn1_mfma
    short* wol = (short*)q + (size_t)DIM * DIM;
    short* kl16 = (short*)t1;                    // t1 dead after bgemm_t2t

    // pinv pair scratch (after attn3v, k/vT in d_out are dead):
    const size_t U = SZ_M2;                      // 4 MiB per bf16 array
    short* db = (short*)d_out;
    short* bufBTh = db + 0 * U;  short* bufBTl = db + 1 * U;
    short* z2BTh  = db + 2 * U;  short* z2BTl  = db + 3 * U;
    short* zPair[2][4] = {                       // {Ah, Al, BTh, BTl} x 2 buffers
        { db + 4 * U, db + 5 * U, db + 6 * U, db + 7 * U },
        { db + 8 * U, db + 9 * U, db + 10 * U, db + 11 * U } };
    short* x2Ah = (short*)z2r;   short* x2Al = (short*)z2r + U;
    short* bufAh = (short*)bAr;  short* bufAl = (short*)bAr + U;

    if (ws_size < need) {
        zero_out<<<out_size / 256, 256, 0, stream>>>(out);
        return;
    }

    // 1. split inputs, project qkv via MFMA
    split_x<<<(int)(SZ_QKV / (256 * 8)), 256, 0, stream>>>(x, xh, xl);
    split_wT<<<(K3 * DIM) / 256, 256, 0, stream>>>(Wqkv, wqh, wql, K3);
    gemm_qkv_mfma<<<3072, 256, 0, stream>>>(xh, xl, wqh, wql, q, k, v);
    // 2. vT = v^T (overwrites xl -- dead)
    transpose_v<<<(BB * NH * MM) / 4, 256, 0, stream>>>(v, vT);
    // 3. landmark means + attn2 softmax (x2 overwrites xh -- dead)
    landmark_means<<<(BB * NH * MM * DD) / 256, 256, 0, stream>>>(q, k, qL, kL);
    attn2_softmax<<<BB * NH * MM, 256, 0, stream>>>(qL, kL, x2);
    // 4. attn3v FIRST (frees k/vT = all of d_out for pinv scratch)
    //    4 waves/block (j-split pairs), XCD-pinned per bh
    attn3v_mfma<<<256, 256, 0, stream>>>(qL, k, vT, t1);
    // 5. pinv scalars + z0/x2 pairs (rowmax of softmax == 1 analytically)
    init_scal<<<1, 64, 0, stream>>>(scal);
    csum_max<<<BB * NH, 256, 0, stream>>>(x2, scal);
    z_init_split<<<(int)(SZ_M2 / (256 * 8)), 256, 0, stream>>>(
        x2, scal, x2Ah, x2Al,
        zPair[0][0], zPair[0][1], zPair[0][2], zPair[0][3]);
    // 6. Newton-Schulz pinv, split-precision MFMA (eye7 fused into GEMM1)
    int cur = 0;
    for (int it = 0; it < 6; it++) {
        int nxt = cur ^ 1;
        // bufA = x2 @ z  (A-pairs); bufB^T = (7I - bufA)^T  (BT-pairs)
        bgemm_pair<<<dim3(4, 4, BB * NH), 256, 0, stream>>>(
            x2Ah, x2Al, zPair[cur][2], zPair[cur][3],
            bufAh, bufAl, bufBTh, bufBTl, nullptr,
            1.f, 0.f, -1.f, 7.f, 1 | 2);
        // z2 = 15I - bufA @ bufB -> BT-pairs
        bgemm_pair<<<dim3(4, 4, BB * NH), 256, 0, stream>>>(
            bufAh, bufAl, bufBTh, bufBTl,
            nullptr, nullptr, z2BTh, z2BTl, nullptr,
            -1.f, 15.f, 1.f, 0.f, 2);
        // bufB2 = 13I - bufA @ z2 -> BT-pairs (overwrite bufBT)
        bgemm_pair<<<dim3(4, 4, BB * NH), 256, 0, stream>>>(
            bufAh, bufAl, z2BTh, z2BTl,
            nullptr, nullptr, bufBTh, bufBTl, nullptr,
            -1.f, 13.f, 1.f, 0.f, 2);
        // z_next = 0.25 z @ bufB2; last iteration needs only fp32 (zf)
        int fl = (it == 5) ? 4 : (1 | 2);
        bgemm_pair<<<dim3(4, 4, BB * NH), 256, 0, stream>>>(
            zPair[cur][0], zPair[cur][1], bufBTh, bufBTl,
            zPair[nxt][0], zPair[nxt][1], zPair[nxt][2], zPair[nxt][3],
            zf, 0.25f, 0.f, 1.f, 0.f, fl);
        cur = nxt;
    }
    // 7. t2t = (z @ t1)^T in bf16 [bh][64][256]
    bgemm_t2t<<<dim3(1, 4, BB * NH), 256, 0, stream>>>(zf, t1, t2t);
    // 7b. kL -> bf16 (over dead t1) for attn1 B-fragments
    kl_to_bf16<<<(int)(SZ_L / (256 * 4)), 256, 0, stream>>>(kL, kl16);
    // 8. oh = softmax(q kL^T) @ t2 + conv(v)   (conv fused; q dead after)
    attn1_mfma<<<dim3(NN / 64, BB * NH), 256, 0, stream>>>(q, kl16, t2t, v, cw, oh);
    // 9. out = oh @ (WoutH + WoutL) + bout (overwrites d_out; scratch dead)
    split_wT<<<(DIM * DIM) / 256, 256, 0, stream>>>(Wout, woh, wol, DIM);
    gemm_out_mfma<<<1024, 256, 0, stream>>>(oh, woh, wol, bout, out);

    (void)in_sizes; (void)n_in; (void)ws_size;
}